// Round 2
// baseline (4069.815 us; speedup 1.0000x reference)
//
#include <hip/hip_runtime.h>
#include <math.h>

typedef float  f32x4  __attribute__((ext_vector_type(4)));
typedef __bf16 bf16x8 __attribute__((ext_vector_type(8)));
typedef __bf16 bf16x4 __attribute__((ext_vector_type(4)));

#define DEV __device__ __forceinline__

DEV f32x4 mfma16(bf16x8 a, bf16x8 b, f32x4 c) {
    return __builtin_amdgcn_mfma_f32_16x16x32_bf16(a, b, c, 0, 0, 0);
}

DEV void async16(const void* g, void* l) {
    __builtin_amdgcn_global_load_lds((const __attribute__((address_space(1))) void*)g,
                                     (__attribute__((address_space(3))) void*)l, 16, 0, 0);
}

// ---------------------------------------------------------------- constants
constexpr int B_  = 8;
constexpr int S_  = 512;
constexpr int D_  = 1024;
constexpr int H_  = 16;
constexpr int FF_ = 4096;
constexpr int ROWS = B_ * S_;   // 4096

// ---------------------------------------------------------------- embed + LN
__global__ __launch_bounds__(256)
void embed_ln_kernel(const int* __restrict__ ids, const int* __restrict__ lgs,
                     const float* __restrict__ fmask,
                     const float* __restrict__ wemb, const float* __restrict__ pemb,
                     const float* __restrict__ lemb,
                     const float* __restrict__ g, const float* __restrict__ bb,
                     float* __restrict__ xf, __bf16* __restrict__ xb)
{
    __shared__ float2 red[4];
    const int row = blockIdx.x;
    const int s   = row & (S_ - 1);
    const int t   = threadIdx.x;
    const int lane = t & 63, w = t >> 6;
    const int id = ids[row], lg = lgs[row];

    float4 wv = *(const float4*)(wemb + ((size_t)id << 10) + t * 4);
    float4 pv = *(const float4*)(pemb + ((size_t)s  << 10) + t * 4);
    float4 lv = *(const float4*)(lemb + ((size_t)lg << 10) + t * 4);
    float a[4] = { wv.x + pv.x + lv.x, wv.y + pv.y + lv.y,
                   wv.z + pv.z + lv.z, wv.w + pv.w + lv.w };

    float sm = a[0] + a[1] + a[2] + a[3];
    float sq = a[0]*a[0] + a[1]*a[1] + a[2]*a[2] + a[3]*a[3];
#pragma unroll
    for (int o = 32; o > 0; o >>= 1) { sm += __shfl_down(sm, o); sq += __shfl_down(sq, o); }
    if (lane == 0) red[w] = make_float2(sm, sq);
    __syncthreads();
    float ts = red[0].x + red[1].x + red[2].x + red[3].x;
    float tq = red[0].y + red[1].y + red[2].y + red[3].y;
    float mean = ts * (1.0f / D_);
    float var  = tq * (1.0f / D_) - mean * mean;
    float rs   = rsqrtf(var + 1e-12f);
    float fm   = fmask[row];

    float4 gv = *(const float4*)(g  + t * 4);
    float4 bv = *(const float4*)(bb + t * 4);
    float o0 = ((a[0]-mean)*rs*gv.x + bv.x) * fm;
    float o1 = ((a[1]-mean)*rs*gv.y + bv.y) * fm;
    float o2 = ((a[2]-mean)*rs*gv.z + bv.z) * fm;
    float o3 = ((a[3]-mean)*rs*gv.w + bv.w) * fm;
    *(float4*)(xf + ((size_t)row << 10) + t * 4) = make_float4(o0, o1, o2, o3);
    bf16x4 ob; ob[0] = (__bf16)o0; ob[1] = (__bf16)o1; ob[2] = (__bf16)o2; ob[3] = (__bf16)o3;
    *(bf16x4*)(xb + ((size_t)row << 10) + t * 4) = ob;
}

// ------------------------------------------------------- residual + LN (+mask)
__global__ __launch_bounds__(256)
void ln_res_kernel(const float* __restrict__ xin, const float* __restrict__ yin,
                   const float* __restrict__ g, const float* __restrict__ bb,
                   const float* __restrict__ fmask,
                   float* __restrict__ xf_out, __bf16* __restrict__ xb_out)
{
    __shared__ float2 red[4];
    const int row = blockIdx.x;
    const int t   = threadIdx.x;
    const int lane = t & 63, w = t >> 6;
    const size_t base = (size_t)row << 10;

    float4 xv = *(const float4*)(xin + base + t * 4);
    float4 yv = *(const float4*)(yin + base + t * 4);
    float a[4] = { xv.x + yv.x, xv.y + yv.y, xv.z + yv.z, xv.w + yv.w };

    float sm = a[0] + a[1] + a[2] + a[3];
    float sq = a[0]*a[0] + a[1]*a[1] + a[2]*a[2] + a[3]*a[3];
#pragma unroll
    for (int o = 32; o > 0; o >>= 1) { sm += __shfl_down(sm, o); sq += __shfl_down(sq, o); }
    if (lane == 0) red[w] = make_float2(sm, sq);
    __syncthreads();
    float ts = red[0].x + red[1].x + red[2].x + red[3].x;
    float tq = red[0].y + red[1].y + red[2].y + red[3].y;
    float mean = ts * (1.0f / D_);
    float var  = tq * (1.0f / D_) - mean * mean;
    float rs   = rsqrtf(var + 1e-12f);
    float fm   = fmask ? fmask[row] : 1.0f;

    float4 gv = *(const float4*)(g  + t * 4);
    float4 bv = *(const float4*)(bb + t * 4);
    float o0 = ((a[0]-mean)*rs*gv.x + bv.x) * fm;
    float o1 = ((a[1]-mean)*rs*gv.y + bv.y) * fm;
    float o2 = ((a[2]-mean)*rs*gv.z + bv.z) * fm;
    float o3 = ((a[3]-mean)*rs*gv.w + bv.w) * fm;
    *(float4*)(xf_out + base + t * 4) = make_float4(o0, o1, o2, o3);
    bf16x4 ob; ob[0] = (__bf16)o0; ob[1] = (__bf16)o1; ob[2] = (__bf16)o2; ob[3] = (__bf16)o3;
    *(bf16x4*)(xb_out + base + t * 4) = ob;
}

// -------------------------------------- weight convert fp32[K][N] -> bf16[N][K]
__global__ __launch_bounds__(256)
void convT_kernel(const float* __restrict__ s0, __bf16* __restrict__ d0,
                  const float* __restrict__ s1, __bf16* __restrict__ d1,
                  const float* __restrict__ s2, __bf16* __restrict__ d2,
                  const float* __restrict__ s3, __bf16* __restrict__ d3,
                  int K, int N)
{
    __shared__ __bf16 tile[64][66];
    const int m = blockIdx.y;
    const float* src = (m == 0) ? s0 : (m == 1) ? s1 : (m == 2) ? s2 : s3;
    __bf16*      dst = (m == 0) ? d0 : (m == 1) ? d1 : (m == 2) ? d2 : d3;
    const int ktiles = K >> 6;
    const int tk = blockIdx.x % ktiles, tn = blockIdx.x / ktiles;
    const int k0 = tk << 6, n0 = tn << 6;
    const int t = threadIdx.x;
#pragma unroll
    for (int i = 0; i < 16; ++i) {
        int idx = i * 256 + t;
        int r = idx >> 6, c = idx & 63;
        tile[c][r] = (__bf16)src[(size_t)(k0 + r) * N + n0 + c];
    }
    __syncthreads();
#pragma unroll
    for (int i = 0; i < 16; ++i) {
        int idx = i * 256 + t;
        int r = idx >> 6, c = idx & 63;
        dst[(size_t)(n0 + r) * K + k0 + c] = tile[r][c];
    }
}

// ---------------------------------------------------------------- GEMM (m97-ish)
// C[M,N] = A[M,K](bf16) @ Bt[N,K](bf16)^T + bias
// EPI 0: Cb = bf16((acc+bias)*scale)   EPI 1: Cf = acc+bias   EPI 2: Cb = bf16(gelu(acc+bias))
template<int EPI>
__global__ __launch_bounds__(256, 2)
void gemm_kernel(const __bf16* __restrict__ A, const __bf16* __restrict__ Bt,
                 const float* __restrict__ bias, float* __restrict__ Cf,
                 __bf16* __restrict__ Cb, int M, int N, int K, float scale)
{
    __shared__ __bf16 As[128 * 64];
    __shared__ __bf16 Bs[128 * 64];
    const int tid = threadIdx.x;
    const int lane = tid & 63;
    const int w = tid >> 6, wr = w >> 1, wc = w & 1;
    const int nT = N >> 7;
    const int nwg = gridDim.x;
    const int bid = blockIdx.x;
    const int cpx = nwg >> 3;                       // grid always %8==0 here
    const int bswz = (bid & 7) * cpx + (bid >> 3);  // XCD-contiguous
    const int bm = bswz / nT, bn = bswz % nT;
    const int m0 = bm << 7, n0 = bn << 7;

    f32x4 acc[4][4] = {};

    const int chr = tid >> 3, chc = tid & 7;
    const __bf16* ga = A  + (size_t)(m0 + chr) * K + chc * 8;
    const __bf16* gb = Bt + (size_t)(n0 + chr) * K + chc * 8;
    char* la = (char*)As + (tid & ~63) * 16;
    char* lb = (char*)Bs + (tid & ~63) * 16;

    const __bf16* arow = As + (wr * 64 + (lane & 15)) * 64 + (lane >> 4) * 8;
    const __bf16* brow = Bs + (wc * 64 + (lane & 15)) * 64 + (lane >> 4) * 8;

    for (int k0 = 0; k0 < K; k0 += 64) {
#pragma unroll
        for (int i = 0; i < 4; ++i) {
            async16(ga + (size_t)(i * 32) * K + k0, la + i * 4096);
            async16(gb + (size_t)(i * 32) * K + k0, lb + i * 4096);
        }
        __syncthreads();
#pragma unroll
        for (int kk = 0; kk < 2; ++kk) {
            bf16x8 af[4], bf[4];
#pragma unroll
            for (int i = 0; i < 4; ++i) af[i] = *(const bf16x8*)(arow + i * 16 * 64 + kk * 32);
#pragma unroll
            for (int i = 0; i < 4; ++i) bf[i] = *(const bf16x8*)(brow + i * 16 * 64 + kk * 32);
#pragma unroll
            for (int mi = 0; mi < 4; ++mi)
#pragma unroll
                for (int ni = 0; ni < 4; ++ni)
                    acc[mi][ni] = mfma16(af[mi], bf[ni], acc[mi][ni]);
        }
        __syncthreads();
    }

    const int mb = m0 + wr * 64 + ((lane >> 4) * 4);
    const int nb = n0 + wc * 64 + (lane & 15);
#pragma unroll
    for (int ni = 0; ni < 4; ++ni) {
        const float bvv = bias[nb + ni * 16];
#pragma unroll
        for (int mi = 0; mi < 4; ++mi) {
#pragma unroll
            for (int r = 0; r < 4; ++r) {
                const int gm = mb + mi * 16 + r;
                const int gn = nb + ni * 16;
                float v = acc[mi][ni][r] + bvv;
                if (EPI == 0) {
                    Cb[(size_t)gm * N + gn] = (__bf16)(v * scale);
                } else if (EPI == 1) {
                    Cf[(size_t)gm * N + gn] = v;
                } else {
                    float ge = 0.5f * v * (1.0f + erff(v * 0.70710678118654752f));
                    Cb[(size_t)gm * N + gn] = (__bf16)ge;
                }
            }
        }
    }
}

// ---------------------------------------------------------------- attention
// grid: qt(8) x h(16) x b(8); block = 4 waves, each wave owns 16 q-rows.
__global__ __launch_bounds__(256, 1)
void attn_kernel(const __bf16* __restrict__ q, const __bf16* __restrict__ k,
                 const __bf16* __restrict__ v, const float* __restrict__ fmask,
                 __bf16* __restrict__ ctx)
{
    __shared__ __bf16 Ks[S_ * 64];        // 64 KB, overlaid by P after QK^T
    __shared__ __bf16 Vt[64 * 528];       // V transposed, padded (66 KB)
    __shared__ float  negm[S_];
    const int bid = blockIdx.x;
    const int qt = bid & 7, h = (bid >> 3) & 15, b = bid >> 7;
    const int tid = threadIdx.x, lane = tid & 63, w = tid >> 6;

    // stage K[s][d] rows for this (b,h) via global_load_lds
    const __bf16* kbase = k + ((size_t)b * S_) * D_ + h * 64;
    char* kl = (char*)Ks + (tid & ~63) * 16;
#pragma unroll
    for (int i = 0; i < 16; ++i) {
        const int s = i * 32 + (tid >> 3);
        async16(kbase + (size_t)s * D_ + (tid & 7) * 8, kl + i * 4096);
    }
    for (int i = tid; i < S_; i += 256) negm[i] = (fmask[b * S_ + i] - 1.0f) * 1e30f;

    // stage V transposed: Vt[d][s]
    const __bf16* vbase = v + ((size_t)b * S_) * D_ + h * 64;
#pragma unroll
    for (int i = 0; i < 16; ++i) {
        const int s = i * 32 + (tid >> 3), d0 = (tid & 7) * 8;
        bf16x8 vv = *(const bf16x8*)(vbase + (size_t)s * D_ + d0);
#pragma unroll
        for (int j = 0; j < 8; ++j) Vt[(d0 + j) * 528 + s] = vv[j];
    }

    // Q fragments (pre-scaled by 0.125 in the projection epilogue)
    const __bf16* qbase = q + ((size_t)b * S_ + qt * 64 + w * 16) * D_ + h * 64;
    const bf16x8 qf0 = *(const bf16x8*)(qbase + (size_t)(lane & 15) * D_ + (lane >> 4) * 8);
    const bf16x8 qf1 = *(const bf16x8*)(qbase + (size_t)(lane & 15) * D_ + 32 + (lane >> 4) * 8);
    __syncthreads();

    // QK^T : per-wave 16 q-rows x 512 key-cols
    f32x4 sc[32];
#pragma unroll
    for (int nf = 0; nf < 32; ++nf) { sc[nf][0] = 0.f; sc[nf][1] = 0.f; sc[nf][2] = 0.f; sc[nf][3] = 0.f; }
#pragma unroll
    for (int nf = 0; nf < 32; ++nf) {
        const __bf16* kr = Ks + (nf * 16 + (lane & 15)) * 64 + (lane >> 4) * 8;
        sc[nf] = mfma16(qf0, *(const bf16x8*)(kr), sc[nf]);
        sc[nf] = mfma16(qf1, *(const bf16x8*)(kr + 32), sc[nf]);
    }

    // mask + softmax (rows live in 16-lane groups; reg r = q-row (lane>>4)*4+r)
    float mx[4] = { -3e38f, -3e38f, -3e38f, -3e38f };
#pragma unroll
    for (int nf = 0; nf < 32; ++nf) {
        const float nm = negm[nf * 16 + (lane & 15)];
#pragma unroll
        for (int r = 0; r < 4; ++r) { sc[nf][r] += nm; mx[r] = fmaxf(mx[r], sc[nf][r]); }
    }
#pragma unroll
    for (int o = 8; o > 0; o >>= 1)
#pragma unroll
        for (int r = 0; r < 4; ++r) mx[r] = fmaxf(mx[r], __shfl_xor(mx[r], o));
    float smr[4] = { 0.f, 0.f, 0.f, 0.f };
#pragma unroll
    for (int nf = 0; nf < 32; ++nf)
#pragma unroll
        for (int r = 0; r < 4; ++r) { float p = __expf(sc[nf][r] - mx[r]); sc[nf][r] = p; smr[r] += p; }
#pragma unroll
    for (int o = 8; o > 0; o >>= 1)
#pragma unroll
        for (int r = 0; r < 4; ++r) smr[r] += __shfl_xor(smr[r], o);
    float inv[4];
#pragma unroll
    for (int r = 0; r < 4; ++r) inv[r] = 1.0f / smr[r];

    __syncthreads();                     // everyone done reading Ks
    __bf16* P = Ks + w * (16 * S_);      // per-wave P[16][512] overlays Ks
#pragma unroll
    for (int nf = 0; nf < 32; ++nf)
#pragma unroll
        for (int r = 0; r < 4; ++r)
            P[((lane >> 4) * 4 + r) * S_ + nf * 16 + (lane & 15)] = (__bf16)sc[nf][r];

    // PV : ctx[16 x 64]
    f32x4 co[4] = {};
#pragma unroll
    for (int kk2 = 0; kk2 < 16; ++kk2) {
        bf16x8 pa = *(const bf16x8*)(P + (lane & 15) * S_ + kk2 * 32 + (lane >> 4) * 8);
#pragma unroll
        for (int nf = 0; nf < 4; ++nf) {
            bf16x8 vf = *(const bf16x8*)(Vt + (nf * 16 + (lane & 15)) * 528 + kk2 * 32 + (lane >> 4) * 8);
            co[nf] = mfma16(pa, vf, co[nf]);
        }
    }
    __bf16* cb = ctx + ((size_t)b * S_ + qt * 64 + w * 16) * D_ + h * 64;
#pragma unroll
    for (int nf = 0; nf < 4; ++nf)
#pragma unroll
        for (int r = 0; r < 4; ++r)
            cb[((lane >> 4) * 4 + r) * D_ + nf * 16 + (lane & 15)] = (__bf16)(co[nf][r] * inv[r]);
}

// ---------------------------------------------------------------- launcher
extern "C" void kernel_launch(void* const* d_in, const int* in_sizes, int n_in,
                              void* d_out, int out_size, void* d_ws, size_t ws_size,
                              hipStream_t stream)
{
    (void)in_sizes; (void)n_in; (void)out_size; (void)ws_size;
    const int*   ids   = (const int*)d_in[0];
    const int*   lgs   = (const int*)d_in[1];
    const float* amask = (const float*)d_in[2];
    const float* wemb  = (const float*)d_in[3];
    const float* pemb  = (const float*)d_in[4];
    const float* lemb  = (const float*)d_in[5];
    const float* lng   = (const float*)d_in[6];
    const float* lnbv  = (const float*)d_in[7];
    const float* Wq = (const float*)d_in[8];  const float* bq = (const float*)d_in[9];
    const float* Wk = (const float*)d_in[10]; const float* bk = (const float*)d_in[11];
    const float* Wv = (const float*)d_in[12]; const float* bv = (const float*)d_in[13];
    const float* Wo = (const float*)d_in[14]; const float* bo = (const float*)d_in[15];
    const float* g1 = (const float*)d_in[16]; const float* be1 = (const float*)d_in[17];
    const float* W1 = (const float*)d_in[18]; const float* b1 = (const float*)d_in[19];
    const float* W2 = (const float*)d_in[20]; const float* b2 = (const float*)d_in[21];
    const float* g2 = (const float*)d_in[22]; const float* be2 = (const float*)d_in[23];

    char* p = (char*)d_ws;
    auto take = [&](size_t n) { char* r = p; p += (n + 255) & ~(size_t)255; return r; };
    float*  xf   = (float*) take((size_t)ROWS * D_ * 4);
    __bf16* xb   = (__bf16*)take((size_t)ROWS * D_ * 2);
    __bf16* qb   = (__bf16*)take((size_t)ROWS * D_ * 2);
    __bf16* kb   = (__bf16*)take((size_t)ROWS * D_ * 2);
    __bf16* vbuf = (__bf16*)take((size_t)ROWS * D_ * 2);
    __bf16* cxb  = (__bf16*)take((size_t)ROWS * D_ * 2);
    __bf16* hb   = (__bf16*)take((size_t)ROWS * FF_ * 2);
    float*  yf   = (float*) take((size_t)ROWS * D_ * 4);
    __bf16* wqT  = (__bf16*)take((size_t)D_ * D_ * 2);
    __bf16* wkT  = (__bf16*)take((size_t)D_ * D_ * 2);
    __bf16* wvT  = (__bf16*)take((size_t)D_ * D_ * 2);
    __bf16* woT  = (__bf16*)take((size_t)D_ * D_ * 2);
    __bf16* w1T  = (__bf16*)take((size_t)D_ * FF_ * 2);
    __bf16* w2T  = (__bf16*)take((size_t)FF_ * D_ * 2);

    // tile-derived grids (the round-1 NaN was a hard-coded wrong grid here)
    const int gDD   = (ROWS / 128) * (D_  / 128);   // 256  : [4096x1024] out
    const int gDF   = (ROWS / 128) * (FF_ / 128);   // 1024 : [4096x4096] out

    embed_ln_kernel<<<ROWS, 256, 0, stream>>>(ids, lgs, amask, wemb, pemb, lemb, lng, lnbv, xf, xb);

    for (int l = 0; l < 12; ++l) {
        const size_t woff = (size_t)l * D_ * D_;
        const size_t foff = (size_t)l * D_ * FF_;
        convT_kernel<<<dim3(256, 4), 256, 0, stream>>>(Wq + woff, wqT, Wk + woff, wkT,
                                                       Wv + woff, wvT, Wo + woff, woT, D_, D_);
        convT_kernel<<<dim3(1024, 1), 256, 0, stream>>>(W1 + foff, w1T, W1 + foff, w1T,
                                                        W1 + foff, w1T, W1 + foff, w1T, D_, FF_);
        convT_kernel<<<dim3(1024, 1), 256, 0, stream>>>(W2 + foff, w2T, W2 + foff, w2T,
                                                        W2 + foff, w2T, W2 + foff, w2T, FF_, D_);

        gemm_kernel<0><<<gDD, 256, 0, stream>>>(xb, wqT, bq + l * D_, nullptr, qb,  ROWS, D_, D_, 0.125f);
        gemm_kernel<0><<<gDD, 256, 0, stream>>>(xb, wkT, bk + l * D_, nullptr, kb,  ROWS, D_, D_, 1.0f);
        gemm_kernel<0><<<gDD, 256, 0, stream>>>(xb, wvT, bv + l * D_, nullptr, vbuf, ROWS, D_, D_, 1.0f);

        attn_kernel<<<B_ * H_ * (S_ / 64), 256, 0, stream>>>(qb, kb, vbuf, amask, cxb);

        gemm_kernel<1><<<gDD, 256, 0, stream>>>(cxb, woT, bo + l * D_, yf, nullptr, ROWS, D_, D_, 1.0f);
        ln_res_kernel<<<ROWS, 256, 0, stream>>>(xf, yf, g1 + l * D_, be1 + l * D_, nullptr, xf, xb);

        gemm_kernel<2><<<gDF, 256, 0, stream>>>(xb, w1T, b1 + l * FF_, nullptr, hb, ROWS, FF_, D_, 1.0f);
        gemm_kernel<1><<<gDD, 256, 0, stream>>>(hb, w2T, b2 + l * D_, yf, nullptr, ROWS, D_, FF_, 1.0f);

        float* dst = (l == 11) ? (float*)d_out : xf;
        ln_res_kernel<<<ROWS, 256, 0, stream>>>(xf, yf, g2 + l * D_, be2 + l * D_, amask, dst, xb);
    }
}

// Round 3
// 3142.040 us; speedup vs baseline: 1.2953x; 1.2953x over previous
//
#include <hip/hip_runtime.h>
#include <math.h>

typedef float  f32x4  __attribute__((ext_vector_type(4)));
typedef __bf16 bf16x8 __attribute__((ext_vector_type(8)));
typedef __bf16 bf16x4 __attribute__((ext_vector_type(4)));

#define DEV __device__ __forceinline__

DEV f32x4 mfma16(bf16x8 a, bf16x8 b, f32x4 c) {
    return __builtin_amdgcn_mfma_f32_16x16x32_bf16(a, b, c, 0, 0, 0);
}

DEV void async16(const void* g, void* l) {
    __builtin_amdgcn_global_load_lds((const __attribute__((address_space(1))) void*)g,
                                     (__attribute__((address_space(3))) void*)l, 16, 0, 0);
}

// ---------------------------------------------------------------- constants
constexpr int B_  = 8;
constexpr int S_  = 512;
constexpr int D_  = 1024;
constexpr int H_  = 16;
constexpr int FF_ = 4096;
constexpr int ROWS = B_ * S_;   // 4096

// ---------------------------------------------------------------- embed + LN
__global__ __launch_bounds__(256)
void embed_ln_kernel(const int* __restrict__ ids, const int* __restrict__ lgs,
                     const float* __restrict__ fmask,
                     const float* __restrict__ wemb, const float* __restrict__ pemb,
                     const float* __restrict__ lemb,
                     const float* __restrict__ g, const float* __restrict__ bb,
                     float* __restrict__ xf, __bf16* __restrict__ xb)
{
    __shared__ float2 red[4];
    const int row = blockIdx.x;
    const int s   = row & (S_ - 1);
    const int t   = threadIdx.x;
    const int lane = t & 63, w = t >> 6;
    const int id = ids[row], lg = lgs[row];

    float4 wv = *(const float4*)(wemb + ((size_t)id << 10) + t * 4);
    float4 pv = *(const float4*)(pemb + ((size_t)s  << 10) + t * 4);
    float4 lv = *(const float4*)(lemb + ((size_t)lg << 10) + t * 4);
    float a[4] = { wv.x + pv.x + lv.x, wv.y + pv.y + lv.y,
                   wv.z + pv.z + lv.z, wv.w + pv.w + lv.w };

    float sm = a[0] + a[1] + a[2] + a[3];
    float sq = a[0]*a[0] + a[1]*a[1] + a[2]*a[2] + a[3]*a[3];
#pragma unroll
    for (int o = 32; o > 0; o >>= 1) { sm += __shfl_down(sm, o); sq += __shfl_down(sq, o); }
    if (lane == 0) red[w] = make_float2(sm, sq);
    __syncthreads();
    float ts = red[0].x + red[1].x + red[2].x + red[3].x;
    float tq = red[0].y + red[1].y + red[2].y + red[3].y;
    float mean = ts * (1.0f / D_);
    float var  = tq * (1.0f / D_) - mean * mean;
    float rs   = rsqrtf(var + 1e-12f);
    float fm   = fmask[row];

    float4 gv = *(const float4*)(g  + t * 4);
    float4 bv = *(const float4*)(bb + t * 4);
    float o0 = ((a[0]-mean)*rs*gv.x + bv.x) * fm;
    float o1 = ((a[1]-mean)*rs*gv.y + bv.y) * fm;
    float o2 = ((a[2]-mean)*rs*gv.z + bv.z) * fm;
    float o3 = ((a[3]-mean)*rs*gv.w + bv.w) * fm;
    *(float4*)(xf + ((size_t)row << 10) + t * 4) = make_float4(o0, o1, o2, o3);
    bf16x4 ob; ob[0] = (__bf16)o0; ob[1] = (__bf16)o1; ob[2] = (__bf16)o2; ob[3] = (__bf16)o3;
    *(bf16x4*)(xb + ((size_t)row << 10) + t * 4) = ob;
}

// ---------------------------------------- residual + two split-K partials + LN
__global__ __launch_bounds__(256)
void ln_res2_kernel(const float* __restrict__ xin, const float* __restrict__ y0,
                    const float* __restrict__ y1,
                    const float* __restrict__ g, const float* __restrict__ bb,
                    const float* __restrict__ fmask,
                    float* __restrict__ xf_out, __bf16* __restrict__ xb_out)
{
    __shared__ float2 red[4];
    const int row = blockIdx.x;
    const int t   = threadIdx.x;
    const int lane = t & 63, w = t >> 6;
    const size_t base = (size_t)row << 10;

    float4 xv = *(const float4*)(xin + base + t * 4);
    float4 y0v = *(const float4*)(y0 + base + t * 4);
    float4 y1v = *(const float4*)(y1 + base + t * 4);
    float a[4] = { xv.x + y0v.x + y1v.x, xv.y + y0v.y + y1v.y,
                   xv.z + y0v.z + y1v.z, xv.w + y0v.w + y1v.w };

    float sm = a[0] + a[1] + a[2] + a[3];
    float sq = a[0]*a[0] + a[1]*a[1] + a[2]*a[2] + a[3]*a[3];
#pragma unroll
    for (int o = 32; o > 0; o >>= 1) { sm += __shfl_down(sm, o); sq += __shfl_down(sq, o); }
    if (lane == 0) red[w] = make_float2(sm, sq);
    __syncthreads();
    float ts = red[0].x + red[1].x + red[2].x + red[3].x;
    float tq = red[0].y + red[1].y + red[2].y + red[3].y;
    float mean = ts * (1.0f / D_);
    float var  = tq * (1.0f / D_) - mean * mean;
    float rs   = rsqrtf(var + 1e-12f);
    float fm   = fmask ? fmask[row] : 1.0f;

    float4 gv = *(const float4*)(g  + t * 4);
    float4 bv = *(const float4*)(bb + t * 4);
    float o0 = ((a[0]-mean)*rs*gv.x + bv.x) * fm;
    float o1 = ((a[1]-mean)*rs*gv.y + bv.y) * fm;
    float o2 = ((a[2]-mean)*rs*gv.z + bv.z) * fm;
    float o3 = ((a[3]-mean)*rs*gv.w + bv.w) * fm;
    *(float4*)(xf_out + base + t * 4) = make_float4(o0, o1, o2, o3);
    bf16x4 ob; ob[0] = (__bf16)o0; ob[1] = (__bf16)o1; ob[2] = (__bf16)o2; ob[3] = (__bf16)o3;
    *(bf16x4*)(xb_out + base + t * 4) = ob;
}

// -------------------------------------- weight convert fp32[K][N] -> bf16[N][K]
__global__ __launch_bounds__(256)
void convT_kernel(const float* __restrict__ s0, __bf16* __restrict__ d0,
                  const float* __restrict__ s1, __bf16* __restrict__ d1,
                  const float* __restrict__ s2, __bf16* __restrict__ d2,
                  const float* __restrict__ s3, __bf16* __restrict__ d3,
                  int K, int N)
{
    __shared__ __bf16 tile[64][66];
    const int m = blockIdx.y;
    const float* src = (m == 0) ? s0 : (m == 1) ? s1 : (m == 2) ? s2 : s3;
    __bf16*      dst = (m == 0) ? d0 : (m == 1) ? d1 : (m == 2) ? d2 : d3;
    const int ktiles = K >> 6;
    const int tk = blockIdx.x % ktiles, tn = blockIdx.x / ktiles;
    const int k0 = tk << 6, n0 = tn << 6;
    const int t = threadIdx.x;
#pragma unroll
    for (int i = 0; i < 16; ++i) {
        int idx = i * 256 + t;
        int r = idx >> 6, c = idx & 63;
        tile[c][r] = (__bf16)src[(size_t)(k0 + r) * N + n0 + c];
    }
    __syncthreads();
#pragma unroll
    for (int i = 0; i < 16; ++i) {
        int idx = i * 256 + t;
        int r = idx >> 6, c = idx & 63;
        dst[(size_t)(n0 + r) * K + k0 + c] = tile[r][c];
    }
}

// ---------------------------------------------------------------- fused QKV GEMM
// A[4096,1024](bf16) @ wqkvT[3072,1024]^T ; per-128-tile output routed to q/k/v.
__global__ __launch_bounds__(256, 2)
void gemm_qkv_kernel(const __bf16* __restrict__ A, const __bf16* __restrict__ Bt,
                     const float* __restrict__ bq, const float* __restrict__ bk,
                     const float* __restrict__ bv,
                     __bf16* __restrict__ qb, __bf16* __restrict__ kb,
                     __bf16* __restrict__ vb)
{
    constexpr int K = D_;
    constexpr int nT = 3 * D_ / 128;    // 24
    __shared__ __bf16 As[128 * 64];
    __shared__ __bf16 Bs[128 * 64];
    const int tid = threadIdx.x;
    const int lane = tid & 63;
    const int w = tid >> 6, wr = w >> 1, wc = w & 1;
    const int nwg = gridDim.x;
    const int bid = blockIdx.x;
    const int cpx = nwg >> 3;
    const int bswz = (bid & 7) * cpx + (bid >> 3);
    const int bm = bswz / nT, bn = bswz % nT;
    const int m0 = bm << 7, n0 = bn << 7;

    f32x4 acc[4][4] = {};

    const int chr = tid >> 3, chc = tid & 7;
    const __bf16* ga = A  + (size_t)(m0 + chr) * K + chc * 8;
    const __bf16* gb = Bt + (size_t)(n0 + chr) * K + chc * 8;
    char* la = (char*)As + (tid & ~63) * 16;
    char* lb = (char*)Bs + (tid & ~63) * 16;

    const __bf16* arow = As + (wr * 64 + (lane & 15)) * 64 + (lane >> 4) * 8;
    const __bf16* brow = Bs + (wc * 64 + (lane & 15)) * 64 + (lane >> 4) * 8;

    for (int k0 = 0; k0 < K; k0 += 64) {
#pragma unroll
        for (int i = 0; i < 4; ++i) {
            async16(ga + (size_t)(i * 32) * K + k0, la + i * 4096);
            async16(gb + (size_t)(i * 32) * K + k0, lb + i * 4096);
        }
        __syncthreads();
#pragma unroll
        for (int kk = 0; kk < 2; ++kk) {
            bf16x8 af[4], bf[4];
#pragma unroll
            for (int i = 0; i < 4; ++i) af[i] = *(const bf16x8*)(arow + i * 16 * 64 + kk * 32);
#pragma unroll
            for (int i = 0; i < 4; ++i) bf[i] = *(const bf16x8*)(brow + i * 16 * 64 + kk * 32);
#pragma unroll
            for (int mi = 0; mi < 4; ++mi)
#pragma unroll
                for (int ni = 0; ni < 4; ++ni)
                    acc[mi][ni] = mfma16(af[mi], bf[ni], acc[mi][ni]);
        }
        __syncthreads();
    }

    const int sel = n0 >> 10;                    // 0:q 1:k 2:v (tile never straddles)
    __bf16* out = (sel == 0) ? qb : (sel == 1) ? kb : vb;
    const float* bptr = (sel == 0) ? bq : (sel == 1) ? bk : bv;
    const float scale = (sel == 0) ? 0.125f : 1.0f;
    const int mb = m0 + wr * 64 + ((lane >> 4) * 4);
    const int nb = (n0 & 1023) + wc * 64 + (lane & 15);
#pragma unroll
    for (int ni = 0; ni < 4; ++ni) {
        const float bvv = bptr[nb + ni * 16];
#pragma unroll
        for (int mi = 0; mi < 4; ++mi)
#pragma unroll
            for (int r = 0; r < 4; ++r)
                out[(size_t)(mb + mi * 16 + r) * D_ + nb + ni * 16] =
                    (__bf16)((acc[mi][ni][r] + bvv) * scale);
    }
}

// ---------------------------------------------------------------- GEMM (full-K)
// EPI 2: Cb = bf16(gelu(acc+bias))
template<int EPI>
__global__ __launch_bounds__(256, 2)
void gemm_kernel(const __bf16* __restrict__ A, const __bf16* __restrict__ Bt,
                 const float* __restrict__ bias, float* __restrict__ Cf,
                 __bf16* __restrict__ Cb, int M, int N, int K, float scale)
{
    __shared__ __bf16 As[128 * 64];
    __shared__ __bf16 Bs[128 * 64];
    const int tid = threadIdx.x;
    const int lane = tid & 63;
    const int w = tid >> 6, wr = w >> 1, wc = w & 1;
    const int nT = N >> 7;
    const int nwg = gridDim.x;
    const int bid = blockIdx.x;
    const int cpx = nwg >> 3;
    const int bswz = (bid & 7) * cpx + (bid >> 3);
    const int bm = bswz / nT, bn = bswz % nT;
    const int m0 = bm << 7, n0 = bn << 7;

    f32x4 acc[4][4] = {};

    const int chr = tid >> 3, chc = tid & 7;
    const __bf16* ga = A  + (size_t)(m0 + chr) * K + chc * 8;
    const __bf16* gb = Bt + (size_t)(n0 + chr) * K + chc * 8;
    char* la = (char*)As + (tid & ~63) * 16;
    char* lb = (char*)Bs + (tid & ~63) * 16;

    const __bf16* arow = As + (wr * 64 + (lane & 15)) * 64 + (lane >> 4) * 8;
    const __bf16* brow = Bs + (wc * 64 + (lane & 15)) * 64 + (lane >> 4) * 8;

    for (int k0 = 0; k0 < K; k0 += 64) {
#pragma unroll
        for (int i = 0; i < 4; ++i) {
            async16(ga + (size_t)(i * 32) * K + k0, la + i * 4096);
            async16(gb + (size_t)(i * 32) * K + k0, lb + i * 4096);
        }
        __syncthreads();
#pragma unroll
        for (int kk = 0; kk < 2; ++kk) {
            bf16x8 af[4], bf[4];
#pragma unroll
            for (int i = 0; i < 4; ++i) af[i] = *(const bf16x8*)(arow + i * 16 * 64 + kk * 32);
#pragma unroll
            for (int i = 0; i < 4; ++i) bf[i] = *(const bf16x8*)(brow + i * 16 * 64 + kk * 32);
#pragma unroll
            for (int mi = 0; mi < 4; ++mi)
#pragma unroll
                for (int ni = 0; ni < 4; ++ni)
                    acc[mi][ni] = mfma16(af[mi], bf[ni], acc[mi][ni]);
        }
        __syncthreads();
    }

    const int mb = m0 + wr * 64 + ((lane >> 4) * 4);
    const int nb = n0 + wc * 64 + (lane & 15);
#pragma unroll
    for (int ni = 0; ni < 4; ++ni) {
        const float bvv = bias[nb + ni * 16];
#pragma unroll
        for (int mi = 0; mi < 4; ++mi) {
#pragma unroll
            for (int r = 0; r < 4; ++r) {
                const int gm = mb + mi * 16 + r;
                const int gn = nb + ni * 16;
                float v = acc[mi][ni][r] + bvv;
                if (EPI == 2) {
                    float ge = 0.5f * v * (1.0f + erff(v * 0.70710678118654752f));
                    Cb[(size_t)gm * N + gn] = (__bf16)ge;
                } else {
                    Cf[(size_t)gm * N + gn] = v * scale;
                }
            }
        }
    }
}

// ------------------------------------------------------------- split-K=2 GEMM
// grid = 2*(M/128)*(N/128); partial fp32 outputs Yp[slice][M][N]; slice0 adds bias.
__global__ __launch_bounds__(256, 2)
void gemm_splitk_kernel(const __bf16* __restrict__ A, const __bf16* __restrict__ Bt,
                        const float* __restrict__ bias, float* __restrict__ Yp,
                        int M, int N, int K)
{
    __shared__ __bf16 As[128 * 64];
    __shared__ __bf16 Bs[128 * 64];
    const int tid = threadIdx.x;
    const int lane = tid & 63;
    const int w = tid >> 6, wr = w >> 1, wc = w & 1;
    const int nT = N >> 7;
    const int nwg = gridDim.x;
    const int bid = blockIdx.x;
    const int cpx = nwg >> 3;
    const int bswz = (bid & 7) * cpx + (bid >> 3);
    const int tiles = nwg >> 1;
    const int slice = bswz / tiles;
    const int tile  = bswz % tiles;
    const int bm = tile / nT, bn = tile % nT;
    const int m0 = bm << 7, n0 = bn << 7;
    const int Kh = K >> 1, ks = slice * Kh;

    f32x4 acc[4][4] = {};

    const int chr = tid >> 3, chc = tid & 7;
    const __bf16* ga = A  + (size_t)(m0 + chr) * K + chc * 8;
    const __bf16* gb = Bt + (size_t)(n0 + chr) * K + chc * 8;
    char* la = (char*)As + (tid & ~63) * 16;
    char* lb = (char*)Bs + (tid & ~63) * 16;

    const __bf16* arow = As + (wr * 64 + (lane & 15)) * 64 + (lane >> 4) * 8;
    const __bf16* brow = Bs + (wc * 64 + (lane & 15)) * 64 + (lane >> 4) * 8;

    for (int k0 = ks; k0 < ks + Kh; k0 += 64) {
#pragma unroll
        for (int i = 0; i < 4; ++i) {
            async16(ga + (size_t)(i * 32) * K + k0, la + i * 4096);
            async16(gb + (size_t)(i * 32) * K + k0, lb + i * 4096);
        }
        __syncthreads();
#pragma unroll
        for (int kk = 0; kk < 2; ++kk) {
            bf16x8 af[4], bf[4];
#pragma unroll
            for (int i = 0; i < 4; ++i) af[i] = *(const bf16x8*)(arow + i * 16 * 64 + kk * 32);
#pragma unroll
            for (int i = 0; i < 4; ++i) bf[i] = *(const bf16x8*)(brow + i * 16 * 64 + kk * 32);
#pragma unroll
            for (int mi = 0; mi < 4; ++mi)
#pragma unroll
                for (int ni = 0; ni < 4; ++ni)
                    acc[mi][ni] = mfma16(af[mi], bf[ni], acc[mi][ni]);
        }
        __syncthreads();
    }

    float* Y = Yp + (size_t)slice * M * N;
    const int mb = m0 + wr * 64 + ((lane >> 4) * 4);
    const int nb = n0 + wc * 64 + (lane & 15);
#pragma unroll
    for (int ni = 0; ni < 4; ++ni) {
        const float bvv = (slice == 0) ? bias[nb + ni * 16] : 0.0f;
#pragma unroll
        for (int mi = 0; mi < 4; ++mi)
#pragma unroll
            for (int r = 0; r < 4; ++r)
                Y[(size_t)(mb + mi * 16 + r) * N + nb + ni * 16] = acc[mi][ni][r] + bvv;
    }
}

// ---------------------------------------------------------------- attention
// 2 x 256-key chunks; 67 KB LDS -> 2 blocks/CU. 4 waves x 16 q-rows.
__global__ __launch_bounds__(256, 2)
void attn_kernel(const __bf16* __restrict__ q, const __bf16* __restrict__ k,
                 const __bf16* __restrict__ v, const float* __restrict__ fmask,
                 __bf16* __restrict__ ctx)
{
    __shared__ __bf16 Ks[256 * 64];       // 32 KB; re-used as P in PV phase
    __shared__ __bf16 Vt[64 * 264];       // 33 KB, padded stride
    __shared__ float  negm[S_];
    const int bid = blockIdx.x;
    const int qt = bid & 7, h = (bid >> 3) & 15, b = bid >> 7;
    const int tid = threadIdx.x, lane = tid & 63, w = tid >> 6;

    const __bf16* kbase = k + ((size_t)b * S_) * D_ + h * 64;
    const __bf16* vbase = v + ((size_t)b * S_) * D_ + h * 64;
    char* kl = (char*)Ks + (tid & ~63) * 16;

    for (int i = tid; i < S_; i += 256) negm[i] = (fmask[b * S_ + i] - 1.0f) * 1e30f;

    const __bf16* qbase = q + ((size_t)b * S_ + qt * 64 + w * 16) * D_ + h * 64;
    const bf16x8 qf0 = *(const bf16x8*)(qbase + (size_t)(lane & 15) * D_ + (lane >> 4) * 8);
    const bf16x8 qf1 = *(const bf16x8*)(qbase + (size_t)(lane & 15) * D_ + 32 + (lane >> 4) * 8);

    f32x4 sc[32];
#pragma unroll
    for (int i = 0; i < 32; ++i) { sc[i][0] = 0.f; sc[i][1] = 0.f; sc[i][2] = 0.f; sc[i][3] = 0.f; }

    // ---- QK^T in two 256-key chunks through one 32 KB buffer
#pragma unroll
    for (int c = 0; c < 2; ++c) {
        if (c) __syncthreads();           // chunk-0 reads done before overwrite
#pragma unroll
        for (int i = 0; i < 8; ++i) {
            const int s = c * 256 + i * 32 + (tid >> 3);
            async16(kbase + (size_t)s * D_ + (tid & 7) * 8, kl + i * 4096);
        }
        __syncthreads();
#pragma unroll
        for (int nf = 0; nf < 16; ++nf) {
            const __bf16* kr = Ks + (nf * 16 + (lane & 15)) * 64 + (lane >> 4) * 8;
            sc[c * 16 + nf] = mfma16(qf0, *(const bf16x8*)(kr), sc[c * 16 + nf]);
            sc[c * 16 + nf] = mfma16(qf1, *(const bf16x8*)(kr + 32), sc[c * 16 + nf]);
        }
    }

    // ---- mask + softmax fully in registers (rows in 16-lane groups)
    float mx[4] = { -3e38f, -3e38f, -3e38f, -3e38f };
#pragma unroll
    for (int i = 0; i < 32; ++i) {
        const int key = (i >> 4) * 256 + (i & 15) * 16 + (lane & 15);
        const float nm = negm[key];
#pragma unroll
        for (int r = 0; r < 4; ++r) { sc[i][r] += nm; mx[r] = fmaxf(mx[r], sc[i][r]); }
    }
#pragma unroll
    for (int o = 8; o > 0; o >>= 1)
#pragma unroll
        for (int r = 0; r < 4; ++r) mx[r] = fmaxf(mx[r], __shfl_xor(mx[r], o));
    float smr[4] = { 0.f, 0.f, 0.f, 0.f };
#pragma unroll
    for (int i = 0; i < 32; ++i)
#pragma unroll
        for (int r = 0; r < 4; ++r) { float pp = __expf(sc[i][r] - mx[r]); sc[i][r] = pp; smr[r] += pp; }
#pragma unroll
    for (int o = 8; o > 0; o >>= 1)
#pragma unroll
        for (int r = 0; r < 4; ++r) smr[r] += __shfl_xor(smr[r], o);
    float inv[4];
#pragma unroll
    for (int r = 0; r < 4; ++r) inv[r] = 1.0f / smr[r];

    // ---- PV in two chunks: P overlays Ks, Vt staged per chunk
    f32x4 co[4] = {};
#pragma unroll
    for (int c = 0; c < 2; ++c) {
        __syncthreads();                  // previous readers of Ks/Vt done
        __bf16* P = Ks + w * (16 * 256);
#pragma unroll
        for (int nf = 0; nf < 16; ++nf)
#pragma unroll
            for (int r = 0; r < 4; ++r)
                P[((lane >> 4) * 4 + r) * 256 + nf * 16 + (lane & 15)] = (__bf16)sc[c * 16 + nf][r];
#pragma unroll
        for (int i = 0; i < 8; ++i) {
            const int s = i * 32 + (tid >> 3), d0 = (tid & 7) * 8;
            bf16x8 vv = *(const bf16x8*)(vbase + (size_t)(c * 256 + s) * D_ + d0);
#pragma unroll
            for (int j = 0; j < 8; ++j) Vt[(d0 + j) * 264 + s] = vv[j];
        }
        __syncthreads();
#pragma unroll
        for (int kk2 = 0; kk2 < 8; ++kk2) {
            bf16x8 pa = *(const bf16x8*)(P + (lane & 15) * 256 + kk2 * 32 + (lane >> 4) * 8);
#pragma unroll
            for (int nf = 0; nf < 4; ++nf) {
                bf16x8 vf = *(const bf16x8*)(Vt + (nf * 16 + (lane & 15)) * 264 + kk2 * 32 + (lane >> 4) * 8);
                co[nf] = mfma16(pa, vf, co[nf]);
            }
        }
    }

    __bf16* cb = ctx + ((size_t)b * S_ + qt * 64 + w * 16) * D_ + h * 64;
#pragma unroll
    for (int nf = 0; nf < 4; ++nf)
#pragma unroll
        for (int r = 0; r < 4; ++r)
            cb[((lane >> 4) * 4 + r) * D_ + nf * 16 + (lane & 15)] = (__bf16)(co[nf][r] * inv[r]);
}

// ---------------------------------------------------------------- launcher
extern "C" void kernel_launch(void* const* d_in, const int* in_sizes, int n_in,
                              void* d_out, int out_size, void* d_ws, size_t ws_size,
                              hipStream_t stream)
{
    (void)in_sizes; (void)n_in; (void)out_size; (void)ws_size;
    const int*   ids   = (const int*)d_in[0];
    const int*   lgs   = (const int*)d_in[1];
    const float* amask = (const float*)d_in[2];
    const float* wemb  = (const float*)d_in[3];
    const float* pemb  = (const float*)d_in[4];
    const float* lemb  = (const float*)d_in[5];
    const float* lng   = (const float*)d_in[6];
    const float* lnbv  = (const float*)d_in[7];
    const float* Wq = (const float*)d_in[8];  const float* bq = (const float*)d_in[9];
    const float* Wk = (const float*)d_in[10]; const float* bk = (const float*)d_in[11];
    const float* Wv = (const float*)d_in[12]; const float* bv = (const float*)d_in[13];
    const float* Wo = (const float*)d_in[14]; const float* bo = (const float*)d_in[15];
    const float* g1 = (const float*)d_in[16]; const float* be1 = (const float*)d_in[17];
    const float* W1 = (const float*)d_in[18]; const float* b1 = (const float*)d_in[19];
    const float* W2 = (const float*)d_in[20]; const float* b2 = (const float*)d_in[21];
    const float* g2 = (const float*)d_in[22]; const float* be2 = (const float*)d_in[23];

    char* p = (char*)d_ws;
    auto take = [&](size_t n) { char* r = p; p += (n + 255) & ~(size_t)255; return r; };
    float*  xf    = (float*) take((size_t)ROWS * D_ * 4);
    __bf16* xb    = (__bf16*)take((size_t)ROWS * D_ * 2);
    __bf16* qb    = (__bf16*)take((size_t)ROWS * D_ * 2);
    __bf16* kb    = (__bf16*)take((size_t)ROWS * D_ * 2);
    __bf16* vbuf  = (__bf16*)take((size_t)ROWS * D_ * 2);
    __bf16* cxb   = (__bf16*)take((size_t)ROWS * D_ * 2);
    __bf16* hb    = (__bf16*)take((size_t)ROWS * FF_ * 2);
    float*  yfp   = (float*) take((size_t)2 * ROWS * D_ * 4);   // split-K partials
    __bf16* wqkvT = (__bf16*)take((size_t)3 * D_ * D_ * 2);
    __bf16* woT   = (__bf16*)take((size_t)D_ * D_ * 2);
    __bf16* w1T   = (__bf16*)take((size_t)D_ * FF_ * 2);
    __bf16* w2T   = (__bf16*)take((size_t)FF_ * D_ * 2);

    const int gQKV = (ROWS / 128) * (3 * D_ / 128);   // 768
    const int gDD2 = 2 * (ROWS / 128) * (D_ / 128);   // 512 (split-K=2)
    const int gDF  = (ROWS / 128) * (FF_ / 128);      // 1024

    embed_ln_kernel<<<ROWS, 256, 0, stream>>>(ids, lgs, amask, wemb, pemb, lemb, lng, lnbv, xf, xb);

    for (int l = 0; l < 12; ++l) {
        const size_t woff = (size_t)l * D_ * D_;
        const size_t foff = (size_t)l * D_ * FF_;
        convT_kernel<<<dim3(256, 4), 256, 0, stream>>>(
            Wq + woff, wqkvT, Wk + woff, wqkvT + (size_t)D_ * D_,
            Wv + woff, wqkvT + (size_t)2 * D_ * D_, Wo + woff, woT, D_, D_);
        convT_kernel<<<dim3(1024, 1), 256, 0, stream>>>(W1 + foff, w1T, W1 + foff, w1T,
                                                        W1 + foff, w1T, W1 + foff, w1T, D_, FF_);
        convT_kernel<<<dim3(1024, 1), 256, 0, stream>>>(W2 + foff, w2T, W2 + foff, w2T,
                                                        W2 + foff, w2T, W2 + foff, w2T, FF_, D_);

        gemm_qkv_kernel<<<gQKV, 256, 0, stream>>>(xb, wqkvT, bq + l * D_, bk + l * D_, bv + l * D_,
                                                  qb, kb, vbuf);

        attn_kernel<<<B_ * H_ * (S_ / 64), 256, 0, stream>>>(qb, kb, vbuf, amask, cxb);

        gemm_splitk_kernel<<<gDD2, 256, 0, stream>>>(cxb, woT, bo + l * D_, yfp, ROWS, D_, D_);
        ln_res2_kernel<<<ROWS, 256, 0, stream>>>(xf, yfp, yfp + (size_t)ROWS * D_,
                                                 g1 + l * D_, be1 + l * D_, nullptr, xf, xb);

        gemm_kernel<2><<<gDF, 256, 0, stream>>>(xb, w1T, b1 + l * FF_, nullptr, hb, ROWS, FF_, D_, 1.0f);
        gemm_splitk_kernel<<<gDD2, 256, 0, stream>>>(hb, w2T, b2 + l * D_, yfp, ROWS, D_, FF_);

        float* dst = (l == 11) ? (float*)d_out : xf;
        ln_res2_kernel<<<ROWS, 256, 0, stream>>>(xf, yfp, yfp + (size_t)ROWS * D_,
                                                 g2 + l * D_, be2 + l * D_, amask, dst, xb);
    }
}

// Round 4
// 2828.859 us; speedup vs baseline: 1.4387x; 1.1107x over previous
//
#include <hip/hip_runtime.h>
#include <math.h>

typedef float  f32x4  __attribute__((ext_vector_type(4)));
typedef __bf16 bf16x8 __attribute__((ext_vector_type(8)));
typedef __bf16 bf16x4 __attribute__((ext_vector_type(4)));

#define DEV __device__ __forceinline__

DEV f32x4 mfma16(bf16x8 a, bf16x8 b, f32x4 c) {
    return __builtin_amdgcn_mfma_f32_16x16x32_bf16(a, b, c, 0, 0, 0);
}

DEV void async16(const void* g, void* l) {
    __builtin_amdgcn_global_load_lds((const __attribute__((address_space(1))) void*)g,
                                     (__attribute__((address_space(3))) void*)l, 16, 0, 0);
}

// ---------------------------------------------------------------- constants
constexpr int B_  = 8;
constexpr int S_  = 512;
constexpr int D_  = 1024;
constexpr int H_  = 16;
constexpr int FF_ = 4096;
constexpr int ROWS = B_ * S_;   // 4096

// ---------------------------------------------------------------- embed + LN
__global__ __launch_bounds__(256)
void embed_ln_kernel(const int* __restrict__ ids, const int* __restrict__ lgs,
                     const float* __restrict__ fmask,
                     const float* __restrict__ wemb, const float* __restrict__ pemb,
                     const float* __restrict__ lemb,
                     const float* __restrict__ g, const float* __restrict__ bb,
                     float* __restrict__ xf, __bf16* __restrict__ xb)
{
    __shared__ float2 red[4];
    const int row = blockIdx.x;
    const int s   = row & (S_ - 1);
    const int t   = threadIdx.x;
    const int lane = t & 63, w = t >> 6;
    const int id = ids[row], lg = lgs[row];

    float4 wv = *(const float4*)(wemb + ((size_t)id << 10) + t * 4);
    float4 pv = *(const float4*)(pemb + ((size_t)s  << 10) + t * 4);
    float4 lv = *(const float4*)(lemb + ((size_t)lg << 10) + t * 4);
    float a[4] = { wv.x + pv.x + lv.x, wv.y + pv.y + lv.y,
                   wv.z + pv.z + lv.z, wv.w + pv.w + lv.w };

    float sm = a[0] + a[1] + a[2] + a[3];
    float sq = a[0]*a[0] + a[1]*a[1] + a[2]*a[2] + a[3]*a[3];
#pragma unroll
    for (int o = 32; o > 0; o >>= 1) { sm += __shfl_down(sm, o); sq += __shfl_down(sq, o); }
    if (lane == 0) red[w] = make_float2(sm, sq);
    __syncthreads();
    float ts = red[0].x + red[1].x + red[2].x + red[3].x;
    float tq = red[0].y + red[1].y + red[2].y + red[3].y;
    float mean = ts * (1.0f / D_);
    float var  = tq * (1.0f / D_) - mean * mean;
    float rs   = rsqrtf(var + 1e-12f);
    float fm   = fmask[row];

    float4 gv = *(const float4*)(g  + t * 4);
    float4 bv = *(const float4*)(bb + t * 4);
    float o0 = ((a[0]-mean)*rs*gv.x + bv.x) * fm;
    float o1 = ((a[1]-mean)*rs*gv.y + bv.y) * fm;
    float o2 = ((a[2]-mean)*rs*gv.z + bv.z) * fm;
    float o3 = ((a[3]-mean)*rs*gv.w + bv.w) * fm;
    *(float4*)(xf + ((size_t)row << 10) + t * 4) = make_float4(o0, o1, o2, o3);
    bf16x4 ob; ob[0] = (__bf16)o0; ob[1] = (__bf16)o1; ob[2] = (__bf16)o2; ob[3] = (__bf16)o3;
    *(bf16x4*)(xb + ((size_t)row << 10) + t * 4) = ob;
}

// ---------------------------- residual + NP split-K partials + LN (+mask)
// NP==1: y = y0[base].  NP==4: y = y0[base] + y0[base+MN] + y1[base] + y1[base+MN]
template<int NP>
__global__ __launch_bounds__(256)
void ln_resN_kernel(const float* __restrict__ xin, const float* __restrict__ y0,
                    const float* __restrict__ y1,
                    const float* __restrict__ g, const float* __restrict__ bb,
                    const float* __restrict__ fmask,
                    float* __restrict__ xf_out, __bf16* __restrict__ xb_out)
{
    constexpr size_t MN = (size_t)ROWS * D_;
    __shared__ float2 red[4];
    const int row = blockIdx.x;
    const int t   = threadIdx.x;
    const int lane = t & 63, w = t >> 6;
    const size_t base = ((size_t)row << 10) + t * 4;

    float4 xv = *(const float4*)(xin + base);
    float4 yv = *(const float4*)(y0 + base);
    float a[4] = { xv.x + yv.x, xv.y + yv.y, xv.z + yv.z, xv.w + yv.w };
    if (NP == 4) {
        float4 p1 = *(const float4*)(y0 + base + MN);
        float4 p2 = *(const float4*)(y1 + base);
        float4 p3 = *(const float4*)(y1 + base + MN);
        a[0] += p1.x + p2.x + p3.x; a[1] += p1.y + p2.y + p3.y;
        a[2] += p1.z + p2.z + p3.z; a[3] += p1.w + p2.w + p3.w;
    }

    float sm = a[0] + a[1] + a[2] + a[3];
    float sq = a[0]*a[0] + a[1]*a[1] + a[2]*a[2] + a[3]*a[3];
#pragma unroll
    for (int o = 32; o > 0; o >>= 1) { sm += __shfl_down(sm, o); sq += __shfl_down(sq, o); }
    if (lane == 0) red[w] = make_float2(sm, sq);
    __syncthreads();
    float ts = red[0].x + red[1].x + red[2].x + red[3].x;
    float tq = red[0].y + red[1].y + red[2].y + red[3].y;
    float mean = ts * (1.0f / D_);
    float var  = tq * (1.0f / D_) - mean * mean;
    float rs   = rsqrtf(var + 1e-12f);
    float fm   = fmask ? fmask[row] : 1.0f;

    float4 gv = *(const float4*)(g  + t * 4);
    float4 bv = *(const float4*)(bb + t * 4);
    float o0 = ((a[0]-mean)*rs*gv.x + bv.x) * fm;
    float o1 = ((a[1]-mean)*rs*gv.y + bv.y) * fm;
    float o2 = ((a[2]-mean)*rs*gv.z + bv.z) * fm;
    float o3 = ((a[3]-mean)*rs*gv.w + bv.w) * fm;
    *(float4*)(xf_out + base) = make_float4(o0, o1, o2, o3);
    bf16x4 ob; ob[0] = (__bf16)o0; ob[1] = (__bf16)o1; ob[2] = (__bf16)o2; ob[3] = (__bf16)o3;
    *(bf16x4*)(xb_out + base) = ob;
}

// -------------------------------------- weight convert fp32[K][N] -> bf16[N][K]
__global__ __launch_bounds__(256)
void convT_kernel(const float* __restrict__ s0, __bf16* __restrict__ d0,
                  const float* __restrict__ s1, __bf16* __restrict__ d1,
                  const float* __restrict__ s2, __bf16* __restrict__ d2,
                  const float* __restrict__ s3, __bf16* __restrict__ d3,
                  int K, int N)
{
    __shared__ __bf16 tile[64][66];
    const int m = blockIdx.y;
    const float* src = (m == 0) ? s0 : (m == 1) ? s1 : (m == 2) ? s2 : s3;
    __bf16*      dst = (m == 0) ? d0 : (m == 1) ? d1 : (m == 2) ? d2 : d3;
    const int ktiles = K >> 6;
    const int tk = blockIdx.x % ktiles, tn = blockIdx.x / ktiles;
    const int k0 = tk << 6, n0 = tn << 6;
    const int t = threadIdx.x;
#pragma unroll
    for (int i = 0; i < 16; ++i) {
        int idx = i * 256 + t;
        int r = idx >> 6, c = idx & 63;
        tile[c][r] = (__bf16)src[(size_t)(k0 + r) * N + n0 + c];
    }
    __syncthreads();
#pragma unroll
    for (int i = 0; i < 16; ++i) {
        int idx = i * 256 + t;
        int r = idx >> 6, c = idx & 63;
        dst[(size_t)(n0 + r) * K + k0 + c] = tile[r][c];
    }
}

// ================================================================ 256x256 8-phase GEMM
// C[M,N] = A[M,K] @ Bt[N,K]^T.  8 waves (2M x 4N), BK=64, 2 K-tiles/iter,
// double-buffered LDS (128 KiB), counted vmcnt(6), st-swizzle via pre-swizzled
// global source + swizzled ds_read (involution cb ^= (row&7)<<4).
// Half-tiles are M/N-interleaved: A-ht h = M rows {h*64..h*64+63} of each 128-row
// wave strip; B-ht h = N rows {h*32..h*32+31} of each 64-row wave strip.
// EPI 0: QKV route (+bias, q*0.125, bf16).  EPI 2: GELU->bf16.  EPI 3: split-K fp32 partial.
template<int EPI>
__global__ __launch_bounds__(512, 2)
void gemm256_kernel(const __bf16* __restrict__ A, const __bf16* __restrict__ Bt,
                    const float* __restrict__ b0, const float* __restrict__ b1,
                    const float* __restrict__ b2,
                    __bf16* __restrict__ o0, __bf16* __restrict__ o1,
                    __bf16* __restrict__ o2,
                    float* __restrict__ oF0, float* __restrict__ oF1,
                    int M, int N, int K, int Kloc, int nTn, int tiles)
{
    __shared__ __bf16 lds[65536];            // 128 KiB: [A|B][buf][half] x 8192 elems
    const int tid  = threadIdx.x;
    const int lane = tid & 63;
    const int w    = tid >> 6;
    const int wr   = w >> 2, wc = w & 3;     // 2 x 4 waves

    // ---- block tile (XCD-swizzled; grid always % 8 == 0)
    const int nwg = gridDim.x, bid = blockIdx.x;
    const int cpx = nwg >> 3;
    const int bswz = (bid & 7) * cpx + (bid >> 3);
    const int slice = bswz / tiles;
    const int tile  = bswz % tiles;
    const int bm = tile / nTn, bn = tile % nTn;
    const int m0 = bm << 8, n0 = bn << 8;
    const int ks = slice * Kloc;

    // ---- stage-side per-thread constants (pre-swizzled global column)
    const int rrT = tid >> 3;                                  // 0..63
    const size_t swzK  = (size_t)(((tid & 7) ^ (rrT & 7)) * 8);
    const size_t aoff0 = (size_t)rrT * K + swzK;
    const size_t boff0 = (size_t)((rrT >> 5) * 64 + (rrT & 31)) * K + swzK;
    const size_t boff1 = (size_t)(((rrT >> 5) + 2) * 64 + (rrT & 31)) * K + swzK;
    const int wub = w * 512;                                   // elems (wave-uniform LDS chunk)

    // ---- read-side per-thread constants (swizzled ds_read offsets, elems)
    const int aread = (wr * 64 + (lane & 15)) * 64;
    const int bread = (wc * 32 + (lane & 15)) * 64;
    const int csw0 = ((      (lane >> 4) * 16) ^ ((lane & 7) << 4)) >> 1;
    const int csw1 = ((64 +  (lane >> 4) * 16) ^ ((lane & 7) << 4)) >> 1;

    f32x4 acc[8][4] = {};
    bf16x8 a_[4][2], b_[2][2];

#define ST_A(p,h,kt) do {                                                     \
    const size_t gb = (size_t)(m0 + (h) * 64) * K + (kt);                     \
    async16(A + gb + aoff0,                  lds + ((p)*2+(h))*8192 + wub);   \
    async16(A + gb + (size_t)128*K + aoff0,  lds + ((p)*2+(h))*8192 + 4096 + wub); \
} while (0)
#define ST_B(p,h,kt) do {                                                     \
    const size_t gb = (size_t)(n0 + (h) * 32) * K + (kt);                     \
    async16(Bt + gb + boff0, lds + 32768 + ((p)*2+(h))*8192 + wub);           \
    async16(Bt + gb + boff1, lds + 32768 + ((p)*2+(h))*8192 + 4096 + wub);    \
} while (0)
#define DS_A(p,h) do {                                                        \
    const __bf16* base_ = lds + ((p)*2+(h))*8192 + aread;                     \
    _Pragma("unroll") for (int m_ = 0; m_ < 4; ++m_) {                        \
        a_[m_][0] = *(const bf16x8*)(base_ + m_*1024 + csw0);                 \
        a_[m_][1] = *(const bf16x8*)(base_ + m_*1024 + csw1);                 \
    }                                                                         \
} while (0)
#define DS_B(p,h) do {                                                        \
    const __bf16* base_ = lds + 32768 + ((p)*2+(h))*8192 + bread;             \
    _Pragma("unroll") for (int n_ = 0; n_ < 2; ++n_) {                        \
        b_[n_][0] = *(const bf16x8*)(base_ + n_*1024 + csw0);                 \
        b_[n_][1] = *(const bf16x8*)(base_ + n_*1024 + csw1);                 \
    }                                                                         \
} while (0)
#define MM(mb,nb) do {                                                        \
    _Pragma("unroll") for (int m_ = 0; m_ < 4; ++m_)                          \
    _Pragma("unroll") for (int n_ = 0; n_ < 2; ++n_)                          \
    _Pragma("unroll") for (int k_ = 0; k_ < 2; ++k_)                          \
        acc[(mb)+m_][(nb)+n_] = mfma16(a_[m_][k_], b_[n_][k_], acc[(mb)+m_][(nb)+n_]); \
} while (0)
#define SYNC do { __builtin_amdgcn_s_barrier();                               \
    asm volatile("s_waitcnt lgkmcnt(0)" ::: "memory");                        \
    __builtin_amdgcn_s_setprio(1); } while (0)
#define PEND do { __builtin_amdgcn_s_setprio(0);                              \
    __builtin_amdgcn_s_barrier(); } while (0)

    // ---- prologue: 7 half-tile stages (tile0 complete first), 3 left in flight
    ST_A(0,0, ks);      ST_B(0,1, ks);      ST_A(0,1, ks);      ST_B(0,0, ks);
    ST_A(1,0, ks + 64); ST_B(1,1, ks + 64); ST_A(1,1, ks + 64);
    asm volatile("s_waitcnt vmcnt(6)" ::: "memory");
    __builtin_amdgcn_s_barrier();

    const int nIter = Kloc >> 7;             // 2 K-tiles per iteration
    for (int i = 0; i < nIter; ++i) {
        const bool nl = (i != nIter - 1);
        const int kt1 = ks + (2*i+1) * 64;
        const int kt2 = ks + (2*i+2) * 64;
        const int kt3 = kt2 + 64;
        // P1 (Q00, buf0): 12 ds_reads
        DS_A(0,0); DS_B(0,0); ST_B(1,0,kt1);
        SYNC; MM(0,0); PEND;
        // P2 (Q01)
        DS_B(0,1); if (nl) ST_A(0,0,kt2);
        SYNC; MM(0,2); PEND;
        // P3 (Q11)
        DS_A(0,1); if (nl) ST_B(0,1,kt2);
        SYNC; MM(4,2); PEND;
        // P4 (Q10) + counted vmcnt
        DS_B(0,0); if (nl) ST_A(0,1,kt2);
        SYNC; MM(4,0);
        __builtin_amdgcn_s_setprio(0);
        if (nl) asm volatile("s_waitcnt vmcnt(6)" ::: "memory");
        else    asm volatile("s_waitcnt vmcnt(0)" ::: "memory");
        __builtin_amdgcn_s_barrier();
        // P5 (Q00, buf1)
        DS_A(1,0); DS_B(1,0); if (nl) ST_B(0,0,kt2);
        SYNC; MM(0,0); PEND;
        // P6 (Q01)
        DS_B(1,1); if (nl) ST_A(1,0,kt3);
        SYNC; MM(0,2); PEND;
        // P7 (Q11)
        DS_A(1,1); if (nl) ST_B(1,1,kt3);
        SYNC; MM(4,2); PEND;
        // P8 (Q10) + counted vmcnt
        DS_B(1,0); if (nl) ST_A(1,1,kt3);
        SYNC; MM(4,0);
        __builtin_amdgcn_s_setprio(0);
        if (nl) asm volatile("s_waitcnt vmcnt(6)" ::: "memory");
        __builtin_amdgcn_s_barrier();
    }
#undef ST_A
#undef ST_B
#undef DS_A
#undef DS_B
#undef MM
#undef SYNC
#undef PEND

    // ---- epilogue
    const int mrow = m0 + wr * 128 + (lane >> 4) * 4;
    const int ncol = n0 + wc * 64 + (lane & 15);
    if (EPI == 0) {
        const int sel = n0 >> 10;
        __bf16* out = (sel == 0) ? o0 : (sel == 1) ? o1 : o2;
        const float* bp = (sel == 0) ? b0 : (sel == 1) ? b1 : b2;
        const float scl = (sel == 0) ? 0.125f : 1.0f;
        const int nc = ncol & 1023;
#pragma unroll
        for (int ni = 0; ni < 4; ++ni) {
            const float bvv = bp[nc + ni * 16];
#pragma unroll
            for (int mi = 0; mi < 8; ++mi)
#pragma unroll
                for (int r = 0; r < 4; ++r)
                    out[(size_t)(mrow + mi * 16 + r) * D_ + nc + ni * 16] =
                        (__bf16)((acc[mi][ni][r] + bvv) * scl);
        }
    } else if (EPI == 2) {
#pragma unroll
        for (int ni = 0; ni < 4; ++ni) {
            const float bvv = b0[ncol + ni * 16];
#pragma unroll
            for (int mi = 0; mi < 8; ++mi)
#pragma unroll
                for (int r = 0; r < 4; ++r) {
                    float v = acc[mi][ni][r] + bvv;
                    float ge = 0.5f * v * (1.0f + erff(v * 0.70710678118654752f));
                    o0[(size_t)(mrow + mi * 16 + r) * N + ncol + ni * 16] = (__bf16)ge;
                }
        }
    } else {
        const size_t MN = (size_t)M * N;
        float* Y = (slice < 2) ? (oF0 + (size_t)slice * MN) : (oF1 + (size_t)(slice - 2) * MN);
#pragma unroll
        for (int ni = 0; ni < 4; ++ni) {
            const float bvv = (slice == 0) ? b0[ncol + ni * 16] : 0.0f;
#pragma unroll
            for (int mi = 0; mi < 8; ++mi)
#pragma unroll
                for (int r = 0; r < 4; ++r)
                    Y[(size_t)(mrow + mi * 16 + r) * N + ncol + ni * 16] = acc[mi][ni][r] + bvv;
        }
    }
}

// ---------------------------------------------------------------- 128x128 GEMM (Wo)
// EPI 1: Cf = acc + bias (fp32)
template<int EPI>
__global__ __launch_bounds__(256, 2)
void gemm_kernel(const __bf16* __restrict__ A, const __bf16* __restrict__ Bt,
                 const float* __restrict__ bias, float* __restrict__ Cf,
                 __bf16* __restrict__ Cb, int M, int N, int K, float scale)
{
    __shared__ __bf16 As[128 * 64];
    __shared__ __bf16 Bs[128 * 64];
    const int tid = threadIdx.x;
    const int lane = tid & 63;
    const int w = tid >> 6, wr = w >> 1, wc = w & 1;
    const int nT = N >> 7;
    const int nwg = gridDim.x;
    const int bid = blockIdx.x;
    const int cpx = nwg >> 3;
    const int bswz = (bid & 7) * cpx + (bid >> 3);
    const int bm = bswz / nT, bn = bswz % nT;
    const int m0 = bm << 7, n0 = bn << 7;

    f32x4 acc[4][4] = {};

    const int chr = tid >> 3, chc = tid & 7;
    const __bf16* ga = A  + (size_t)(m0 + chr) * K + chc * 8;
    const __bf16* gb = Bt + (size_t)(n0 + chr) * K + chc * 8;
    char* la = (char*)As + (tid & ~63) * 16;
    char* lb = (char*)Bs + (tid & ~63) * 16;

    const __bf16* arow = As + (wr * 64 + (lane & 15)) * 64 + (lane >> 4) * 8;
    const __bf16* brow = Bs + (wc * 64 + (lane & 15)) * 64 + (lane >> 4) * 8;

    for (int k0 = 0; k0 < K; k0 += 64) {
#pragma unroll
        for (int i = 0; i < 4; ++i) {
            async16(ga + (size_t)(i * 32) * K + k0, la + i * 4096);
            async16(gb + (size_t)(i * 32) * K + k0, lb + i * 4096);
        }
        __syncthreads();
#pragma unroll
        for (int kk = 0; kk < 2; ++kk) {
            bf16x8 af[4], bf[4];
#pragma unroll
            for (int i = 0; i < 4; ++i) af[i] = *(const bf16x8*)(arow + i * 16 * 64 + kk * 32);
#pragma unroll
            for (int i = 0; i < 4; ++i) bf[i] = *(const bf16x8*)(brow + i * 16 * 64 + kk * 32);
#pragma unroll
            for (int mi = 0; mi < 4; ++mi)
#pragma unroll
                for (int ni = 0; ni < 4; ++ni)
                    acc[mi][ni] = mfma16(af[mi], bf[ni], acc[mi][ni]);
        }
        __syncthreads();
    }

    const int mb = m0 + wr * 64 + ((lane >> 4) * 4);
    const int nb = n0 + wc * 64 + (lane & 15);
#pragma unroll
    for (int ni = 0; ni < 4; ++ni) {
        const float bvv = bias[nb + ni * 16];
#pragma unroll
        for (int mi = 0; mi < 4; ++mi)
#pragma unroll
            for (int r = 0; r < 4; ++r)
                Cf[(size_t)(mb + mi * 16 + r) * N + nb + ni * 16] =
                    (acc[mi][ni][r] + bvv) * scale;
    }
}

// ---------------------------------------------------------------- attention
// 2 x 256-key chunks; 67 KB LDS -> 2 blocks/CU. 4 waves x 16 q-rows.
__global__ __launch_bounds__(256, 2)
void attn_kernel(const __bf16* __restrict__ q, const __bf16* __restrict__ k,
                 const __bf16* __restrict__ v, const float* __restrict__ fmask,
                 __bf16* __restrict__ ctx)
{
    __shared__ __bf16 Ks[256 * 64];       // 32 KB; re-used as P in PV phase
    __shared__ __bf16 Vt[64 * 264];       // 33 KB, padded stride
    __shared__ float  negm[S_];
    const int bid = blockIdx.x;
    const int qt = bid & 7, h = (bid >> 3) & 15, b = bid >> 7;
    const int tid = threadIdx.x, lane = tid & 63, w = tid >> 6;

    const __bf16* kbase = k + ((size_t)b * S_) * D_ + h * 64;
    const __bf16* vbase = v + ((size_t)b * S_) * D_ + h * 64;
    char* kl = (char*)Ks + (tid & ~63) * 16;

    for (int i = tid; i < S_; i += 256) negm[i] = (fmask[b * S_ + i] - 1.0f) * 1e30f;

    const __bf16* qbase = q + ((size_t)b * S_ + qt * 64 + w * 16) * D_ + h * 64;
    const bf16x8 qf0 = *(const bf16x8*)(qbase + (size_t)(lane & 15) * D_ + (lane >> 4) * 8);
    const bf16x8 qf1 = *(const bf16x8*)(qbase + (size_t)(lane & 15) * D_ + 32 + (lane >> 4) * 8);

    f32x4 sc[32];
#pragma unroll
    for (int i = 0; i < 32; ++i) { sc[i][0] = 0.f; sc[i][1] = 0.f; sc[i][2] = 0.f; sc[i][3] = 0.f; }

#pragma unroll
    for (int c = 0; c < 2; ++c) {
        if (c) __syncthreads();
#pragma unroll
        for (int i = 0; i < 8; ++i) {
            const int s = c * 256 + i * 32 + (tid >> 3);
            async16(kbase + (size_t)s * D_ + (tid & 7) * 8, kl + i * 4096);
        }
        __syncthreads();
#pragma unroll
        for (int nf = 0; nf < 16; ++nf) {
            const __bf16* kr = Ks + (nf * 16 + (lane & 15)) * 64 + (lane >> 4) * 8;
            sc[c * 16 + nf] = mfma16(qf0, *(const bf16x8*)(kr), sc[c * 16 + nf]);
            sc[c * 16 + nf] = mfma16(qf1, *(const bf16x8*)(kr + 32), sc[c * 16 + nf]);
        }
    }

    float mx[4] = { -3e38f, -3e38f, -3e38f, -3e38f };
#pragma unroll
    for (int i = 0; i < 32; ++i) {
        const int key = (i >> 4) * 256 + (i & 15) * 16 + (lane & 15);
        const float nm = negm[key];
#pragma unroll
        for (int r = 0; r < 4; ++r) { sc[i][r] += nm; mx[r] = fmaxf(mx[r], sc[i][r]); }
    }
#pragma unroll
    for (int o = 8; o > 0; o >>= 1)
#pragma unroll
        for (int r = 0; r < 4; ++r) mx[r] = fmaxf(mx[r], __shfl_xor(mx[r], o));
    float smr[4] = { 0.f, 0.f, 0.f, 0.f };
#pragma unroll
    for (int i = 0; i < 32; ++i)
#pragma unroll
        for (int r = 0; r < 4; ++r) { float pp = __expf(sc[i][r] - mx[r]); sc[i][r] = pp; smr[r] += pp; }
#pragma unroll
    for (int o = 8; o > 0; o >>= 1)
#pragma unroll
        for (int r = 0; r < 4; ++r) smr[r] += __shfl_xor(smr[r], o);
    float inv[4];
#pragma unroll
    for (int r = 0; r < 4; ++r) inv[r] = 1.0f / smr[r];

    f32x4 co[4] = {};
#pragma unroll
    for (int c = 0; c < 2; ++c) {
        __syncthreads();
        __bf16* P = Ks + w * (16 * 256);
#pragma unroll
        for (int nf = 0; nf < 16; ++nf)
#pragma unroll
            for (int r = 0; r < 4; ++r)
                P[((lane >> 4) * 4 + r) * 256 + nf * 16 + (lane & 15)] = (__bf16)sc[c * 16 + nf][r];
#pragma unroll
        for (int i = 0; i < 8; ++i) {
            const int s = i * 32 + (tid >> 3), d0 = (tid & 7) * 8;
            bf16x8 vv = *(const bf16x8*)(vbase + (size_t)(c * 256 + s) * D_ + d0);
#pragma unroll
            for (int j = 0; j < 8; ++j) Vt[(d0 + j) * 264 + s] = vv[j];
        }
        __syncthreads();
#pragma unroll
        for (int kk2 = 0; kk2 < 8; ++kk2) {
            bf16x8 pa = *(const bf16x8*)(P + (lane & 15) * 256 + kk2 * 32 + (lane >> 4) * 8);
#pragma unroll
            for (int nf = 0; nf < 4; ++nf) {
                bf16x8 vf = *(const bf16x8*)(Vt + (nf * 16 + (lane & 15)) * 264 + kk2 * 32 + (lane >> 4) * 8);
                co[nf] = mfma16(pa, vf, co[nf]);
            }
        }
    }

    __bf16* cb = ctx + ((size_t)b * S_ + qt * 64 + w * 16) * D_ + h * 64;
#pragma unroll
    for (int nf = 0; nf < 4; ++nf)
#pragma unroll
        for (int r = 0; r < 4; ++r)
            cb[((lane >> 4) * 4 + r) * D_ + nf * 16 + (lane & 15)] = (__bf16)(co[nf][r] * inv[r]);
}

// ---------------------------------------------------------------- launcher
extern "C" void kernel_launch(void* const* d_in, const int* in_sizes, int n_in,
                              void* d_out, int out_size, void* d_ws, size_t ws_size,
                              hipStream_t stream)
{
    (void)in_sizes; (void)n_in; (void)out_size; (void)ws_size;
    const int*   ids   = (const int*)d_in[0];
    const int*   lgs   = (const int*)d_in[1];
    const float* amask = (const float*)d_in[2];
    const float* wemb  = (const float*)d_in[3];
    const float* pemb  = (const float*)d_in[4];
    const float* lemb  = (const float*)d_in[5];
    const float* lng   = (const float*)d_in[6];
    const float* lnbv  = (const float*)d_in[7];
    const float* Wq = (const float*)d_in[8];  const float* bq = (const float*)d_in[9];
    const float* Wk = (const float*)d_in[10]; const float* bk = (const float*)d_in[11];
    const float* Wv = (const float*)d_in[12]; const float* bv = (const float*)d_in[13];
    const float* Wo = (const float*)d_in[14]; const float* bo = (const float*)d_in[15];
    const float* g1 = (const float*)d_in[16]; const float* be1 = (const float*)d_in[17];
    const float* W1 = (const float*)d_in[18]; const float* b1 = (const float*)d_in[19];
    const float* W2 = (const float*)d_in[20]; const float* b2 = (const float*)d_in[21];
    const float* g2 = (const float*)d_in[22]; const float* be2 = (const float*)d_in[23];

    char* p = (char*)d_ws;
    auto take = [&](size_t n) { char* r = p; p += (n + 255) & ~(size_t)255; return r; };
    float*  xf    = (float*) take((size_t)ROWS * D_ * 4);
    __bf16* xb    = (__bf16*)take((size_t)ROWS * D_ * 2);
    __bf16* qb    = (__bf16*)take((size_t)ROWS * D_ * 2);   // also FFN2 partial slice 2
    __bf16* kb    = (__bf16*)take((size_t)ROWS * D_ * 2);
    __bf16* vbuf  = (__bf16*)take((size_t)ROWS * D_ * 2);   // also FFN2 partial slice 3
    __bf16* cxb   = (__bf16*)take((size_t)ROWS * D_ * 2);
    __bf16* hb    = (__bf16*)take((size_t)ROWS * FF_ * 2);
    float*  yfp   = (float*) take((size_t)2 * ROWS * D_ * 4);  // Wo out / FFN2 slices 0,1
    __bf16* wqkvT = (__bf16*)take((size_t)3 * D_ * D_ * 2);
    __bf16* woT   = (__bf16*)take((size_t)D_ * D_ * 2);
    __bf16* w1T   = (__bf16*)take((size_t)D_ * FF_ * 2);
    __bf16* w2T   = (__bf16*)take((size_t)FF_ * D_ * 2);
    float*  y23   = (float*)qb;   // 32 MB spanning qb..cxb (dead during FFN2)

    const int gQKV = (ROWS / 256) * (3 * D_ / 256);   // 192
    const int gF1  = (ROWS / 256) * (FF_ / 256);      // 256
    const int gF2  = 4 * (ROWS / 256) * (D_ / 256);   // 256 (split-K=4)
    const int gWo  = (ROWS / 128) * (D_ / 128);       // 256

    embed_ln_kernel<<<ROWS, 256, 0, stream>>>(ids, lgs, amask, wemb, pemb, lemb, lng, lnbv, xf, xb);

    for (int l = 0; l < 12; ++l) {
        const size_t woff = (size_t)l * D_ * D_;
        const size_t foff = (size_t)l * D_ * FF_;
        convT_kernel<<<dim3(256, 4), 256, 0, stream>>>(
            Wq + woff, wqkvT, Wk + woff, wqkvT + (size_t)D_ * D_,
            Wv + woff, wqkvT + (size_t)2 * D_ * D_, Wo + woff, woT, D_, D_);
        convT_kernel<<<dim3(1024, 1), 256, 0, stream>>>(W1 + foff, w1T, W1 + foff, w1T,
                                                        W1 + foff, w1T, W1 + foff, w1T, D_, FF_);
        convT_kernel<<<dim3(1024, 1), 256, 0, stream>>>(W2 + foff, w2T, W2 + foff, w2T,
                                                        W2 + foff, w2T, W2 + foff, w2T, FF_, D_);

        gemm256_kernel<0><<<gQKV, 512, 0, stream>>>(xb, wqkvT, bq + l * D_, bk + l * D_, bv + l * D_,
                                                    qb, kb, vbuf, nullptr, nullptr,
                                                    ROWS, 3 * D_, D_, D_, 12, gQKV);

        attn_kernel<<<B_ * H_ * (S_ / 64), 256, 0, stream>>>(qb, kb, vbuf, amask, cxb);

        gemm_kernel<1><<<gWo, 256, 0, stream>>>(cxb, woT, bo + l * D_, yfp, nullptr, ROWS, D_, D_, 1.0f);
        ln_resN_kernel<1><<<ROWS, 256, 0, stream>>>(xf, yfp, nullptr,
                                                    g1 + l * D_, be1 + l * D_, nullptr, xf, xb);

        gemm256_kernel<2><<<gF1, 512, 0, stream>>>(xb, w1T, b1 + l * FF_, nullptr, nullptr,
                                                   hb, nullptr, nullptr, nullptr, nullptr,
                                                   ROWS, FF_, D_, D_, 16, gF1);
        gemm256_kernel<3><<<gF2, 512, 0, stream>>>(hb, w2T, b2 + l * D_, nullptr, nullptr,
                                                   nullptr, nullptr, nullptr, yfp, y23,
                                                   ROWS, D_, FF_, D_, 4, 64);

        float* dst = (l == 11) ? (float*)d_out : xf;
        ln_resN_kernel<4><<<ROWS, 256, 0, stream>>>(xf, yfp, y23,
                                                    g2 + l * D_, be2 + l * D_, amask, dst, xb);
    }
}

// Round 5
// 2723.564 us; speedup vs baseline: 1.4943x; 1.0387x over previous
//
#include <hip/hip_runtime.h>
#include <math.h>

typedef float  f32x4  __attribute__((ext_vector_type(4)));
typedef __bf16 bf16x8 __attribute__((ext_vector_type(8)));
typedef __bf16 bf16x4 __attribute__((ext_vector_type(4)));

#define DEV __device__ __forceinline__

DEV f32x4 mfma16(bf16x8 a, bf16x8 b, f32x4 c) {
    return __builtin_amdgcn_mfma_f32_16x16x32_bf16(a, b, c, 0, 0, 0);
}

DEV void async16(const void* g, void* l) {
    __builtin_amdgcn_global_load_lds((const __attribute__((address_space(1))) void*)g,
                                     (__attribute__((address_space(3))) void*)l, 16, 0, 0);
}

// ---------------------------------------------------------------- constants
constexpr int B_  = 8;
constexpr int S_  = 512;
constexpr int D_  = 1024;
constexpr int H_  = 16;
constexpr int FF_ = 4096;
constexpr int ROWS = B_ * S_;   // 4096

// ---------------------------------------------------------------- embed + LN
__global__ __launch_bounds__(256)
void embed_ln_kernel(const int* __restrict__ ids, const int* __restrict__ lgs,
                     const float* __restrict__ fmask,
                     const float* __restrict__ wemb, const float* __restrict__ pemb,
                     const float* __restrict__ lemb,
                     const float* __restrict__ g, const float* __restrict__ bb,
                     float* __restrict__ xf, __bf16* __restrict__ xb)
{
    __shared__ float2 red[4];
    const int row = blockIdx.x;
    const int s   = row & (S_ - 1);
    const int t   = threadIdx.x;
    const int lane = t & 63, w = t >> 6;
    const int id = ids[row], lg = lgs[row];

    float4 wv = *(const float4*)(wemb + ((size_t)id << 10) + t * 4);
    float4 pv = *(const float4*)(pemb + ((size_t)s  << 10) + t * 4);
    float4 lv = *(const float4*)(lemb + ((size_t)lg << 10) + t * 4);
    float a[4] = { wv.x + pv.x + lv.x, wv.y + pv.y + lv.y,
                   wv.z + pv.z + lv.z, wv.w + pv.w + lv.w };

    float sm = a[0] + a[1] + a[2] + a[3];
    float sq = a[0]*a[0] + a[1]*a[1] + a[2]*a[2] + a[3]*a[3];
#pragma unroll
    for (int o = 32; o > 0; o >>= 1) { sm += __shfl_down(sm, o); sq += __shfl_down(sq, o); }
    if (lane == 0) red[w] = make_float2(sm, sq);
    __syncthreads();
    float ts = red[0].x + red[1].x + red[2].x + red[3].x;
    float tq = red[0].y + red[1].y + red[2].y + red[3].y;
    float mean = ts * (1.0f / D_);
    float var  = tq * (1.0f / D_) - mean * mean;
    float rs   = rsqrtf(var + 1e-12f);
    float fm   = fmask[row];

    float4 gv = *(const float4*)(g  + t * 4);
    float4 bv = *(const float4*)(bb + t * 4);
    float o0 = ((a[0]-mean)*rs*gv.x + bv.x) * fm;
    float o1 = ((a[1]-mean)*rs*gv.y + bv.y) * fm;
    float o2 = ((a[2]-mean)*rs*gv.z + bv.z) * fm;
    float o3 = ((a[3]-mean)*rs*gv.w + bv.w) * fm;
    *(float4*)(xf + ((size_t)row << 10) + t * 4) = make_float4(o0, o1, o2, o3);
    bf16x4 ob; ob[0] = (__bf16)o0; ob[1] = (__bf16)o1; ob[2] = (__bf16)o2; ob[3] = (__bf16)o3;
    *(bf16x4*)(xb + ((size_t)row << 10) + t * 4) = ob;
}

// ---------------------------- residual + NP split-K partials + LN (+mask)
template<int NP>
__global__ __launch_bounds__(256)
void ln_resN_kernel(const float* __restrict__ xin, const float* __restrict__ y0,
                    const float* __restrict__ y1,
                    const float* __restrict__ g, const float* __restrict__ bb,
                    const float* __restrict__ fmask,
                    float* __restrict__ xf_out, __bf16* __restrict__ xb_out)
{
    constexpr size_t MN = (size_t)ROWS * D_;
    __shared__ float2 red[4];
    const int row = blockIdx.x;
    const int t   = threadIdx.x;
    const int lane = t & 63, w = t >> 6;
    const size_t base = ((size_t)row << 10) + t * 4;

    float4 xv = *(const float4*)(xin + base);
    float4 yv = *(const float4*)(y0 + base);
    float a[4] = { xv.x + yv.x, xv.y + yv.y, xv.z + yv.z, xv.w + yv.w };
    if (NP == 4) {
        float4 p1 = *(const float4*)(y0 + base + MN);
        float4 p2 = *(const float4*)(y1 + base);
        float4 p3 = *(const float4*)(y1 + base + MN);
        a[0] += p1.x + p2.x + p3.x; a[1] += p1.y + p2.y + p3.y;
        a[2] += p1.z + p2.z + p3.z; a[3] += p1.w + p2.w + p3.w;
    }

    float sm = a[0] + a[1] + a[2] + a[3];
    float sq = a[0]*a[0] + a[1]*a[1] + a[2]*a[2] + a[3]*a[3];
#pragma unroll
    for (int o = 32; o > 0; o >>= 1) { sm += __shfl_down(sm, o); sq += __shfl_down(sq, o); }
    if (lane == 0) red[w] = make_float2(sm, sq);
    __syncthreads();
    float ts = red[0].x + red[1].x + red[2].x + red[3].x;
    float tq = red[0].y + red[1].y + red[2].y + red[3].y;
    float mean = ts * (1.0f / D_);
    float var  = tq * (1.0f / D_) - mean * mean;
    float rs   = rsqrtf(var + 1e-12f);
    float fm   = fmask ? fmask[row] : 1.0f;

    float4 gv = *(const float4*)(g  + t * 4);
    float4 bv = *(const float4*)(bb + t * 4);
    float o0 = ((a[0]-mean)*rs*gv.x + bv.x) * fm;
    float o1 = ((a[1]-mean)*rs*gv.y + bv.y) * fm;
    float o2 = ((a[2]-mean)*rs*gv.z + bv.z) * fm;
    float o3 = ((a[3]-mean)*rs*gv.w + bv.w) * fm;
    *(float4*)(xf_out + base) = make_float4(o0, o1, o2, o3);
    bf16x4 ob; ob[0] = (__bf16)o0; ob[1] = (__bf16)o1; ob[2] = (__bf16)o2; ob[3] = (__bf16)o3;
    *(bf16x4*)(xb_out + base) = ob;
}

// --------------------- fused weight convert fp32[K][N] -> bf16[N][K], all 6 mats
// grid 3072: [0,1024) Wq/Wk/Wv/Wo (256 tiles each), [1024,2048) W1, [2048,3072) W2
__global__ __launch_bounds__(256)
void conv_all_kernel(const float* __restrict__ Wq, const float* __restrict__ Wk,
                     const float* __restrict__ Wv, const float* __restrict__ Wo,
                     const float* __restrict__ W1, const float* __restrict__ W2,
                     __bf16* __restrict__ qkvT, __bf16* __restrict__ woT,
                     __bf16* __restrict__ w1T, __bf16* __restrict__ w2T)
{
    __shared__ __bf16 tile[64][66];
    const int id = blockIdx.x;
    const float* src; __bf16* dst; int K, N, t;
    if (id < 1024) {
        const int m = id >> 8; t = id & 255; K = 1024; N = 1024;
        src = (m == 0) ? Wq : (m == 1) ? Wk : (m == 2) ? Wv : Wo;
        dst = (m == 3) ? woT : qkvT + (size_t)m * 1024 * 1024;
    } else if (id < 2048) {
        t = id - 1024; K = 1024; N = 4096; src = W1; dst = w1T;
    } else {
        t = id - 2048; K = 4096; N = 1024; src = W2; dst = w2T;
    }
    const int ktiles = K >> 6;
    const int tk = t % ktiles, tn = t / ktiles;
    const int k0 = tk << 6, n0 = tn << 6;
    const int tt = threadIdx.x;
#pragma unroll
    for (int i = 0; i < 16; ++i) {
        int idx = i * 256 + tt;
        int r = idx >> 6, c = idx & 63;
        tile[c][r] = (__bf16)src[(size_t)(k0 + r) * N + n0 + c];
    }
    __syncthreads();
#pragma unroll
    for (int i = 0; i < 16; ++i) {
        int idx = i * 256 + tt;
        int r = idx >> 6, c = idx & 63;
        dst[(size_t)(n0 + r) * K + k0 + c] = tile[r][c];
    }
}

// ================================================================ 256x256 8-phase GEMM
// (unchanged from round 4 — verified schedule)
template<int EPI>
__global__ __launch_bounds__(512, 2)
void gemm256_kernel(const __bf16* __restrict__ A, const __bf16* __restrict__ Bt,
                    const float* __restrict__ b0, const float* __restrict__ b1,
                    const float* __restrict__ b2,
                    __bf16* __restrict__ o0, __bf16* __restrict__ o1,
                    __bf16* __restrict__ o2,
                    float* __restrict__ oF0, float* __restrict__ oF1,
                    int M, int N, int K, int Kloc, int nTn, int tiles)
{
    __shared__ __bf16 lds[65536];
    const int tid  = threadIdx.x;
    const int lane = tid & 63;
    const int w    = tid >> 6;
    const int wr   = w >> 2, wc = w & 3;

    const int nwg = gridDim.x, bid = blockIdx.x;
    const int cpx = nwg >> 3;
    const int bswz = (bid & 7) * cpx + (bid >> 3);
    const int slice = bswz / tiles;
    const int tile  = bswz % tiles;
    const int bm = tile / nTn, bn = tile % nTn;
    const int m0 = bm << 8, n0 = bn << 8;
    const int ks = slice * Kloc;

    const int rrT = tid >> 3;
    const size_t swzK  = (size_t)(((tid & 7) ^ (rrT & 7)) * 8);
    const size_t aoff0 = (size_t)rrT * K + swzK;
    const size_t boff0 = (size_t)((rrT >> 5) * 64 + (rrT & 31)) * K + swzK;
    const size_t boff1 = (size_t)(((rrT >> 5) + 2) * 64 + (rrT & 31)) * K + swzK;
    const int wub = w * 512;

    const int aread = (wr * 64 + (lane & 15)) * 64;
    const int bread = (wc * 32 + (lane & 15)) * 64;
    const int csw0 = ((      (lane >> 4) * 16) ^ ((lane & 7) << 4)) >> 1;
    const int csw1 = ((64 +  (lane >> 4) * 16) ^ ((lane & 7) << 4)) >> 1;

    f32x4 acc[8][4] = {};
    bf16x8 a_[4][2], b_[2][2];

#define ST_A(p,h,kt) do {                                                     \
    const size_t gb = (size_t)(m0 + (h) * 64) * K + (kt);                     \
    async16(A + gb + aoff0,                  lds + ((p)*2+(h))*8192 + wub);   \
    async16(A + gb + (size_t)128*K + aoff0,  lds + ((p)*2+(h))*8192 + 4096 + wub); \
} while (0)
#define ST_B(p,h,kt) do {                                                     \
    const size_t gb = (size_t)(n0 + (h) * 32) * K + (kt);                     \
    async16(Bt + gb + boff0, lds + 32768 + ((p)*2+(h))*8192 + wub);           \
    async16(Bt + gb + boff1, lds + 32768 + ((p)*2+(h))*8192 + 4096 + wub);    \
} while (0)
#define DS_A(p,h) do {                                                        \
    const __bf16* base_ = lds + ((p)*2+(h))*8192 + aread;                     \
    _Pragma("unroll") for (int m_ = 0; m_ < 4; ++m_) {                        \
        a_[m_][0] = *(const bf16x8*)(base_ + m_*1024 + csw0);                 \
        a_[m_][1] = *(const bf16x8*)(base_ + m_*1024 + csw1);                 \
    }                                                                         \
} while (0)
#define DS_B(p,h) do {                                                        \
    const __bf16* base_ = lds + 32768 + ((p)*2+(h))*8192 + bread;             \
    _Pragma("unroll") for (int n_ = 0; n_ < 2; ++n_) {                        \
        b_[n_][0] = *(const bf16x8*)(base_ + n_*1024 + csw0);                 \
        b_[n_][1] = *(const bf16x8*)(base_ + n_*1024 + csw1);                 \
    }                                                                         \
} while (0)
#define MM(mb,nb) do {                                                        \
    _Pragma("unroll") for (int m_ = 0; m_ < 4; ++m_)                          \
    _Pragma("unroll") for (int n_ = 0; n_ < 2; ++n_)                          \
    _Pragma("unroll") for (int k_ = 0; k_ < 2; ++k_)                          \
        acc[(mb)+m_][(nb)+n_] = mfma16(a_[m_][k_], b_[n_][k_], acc[(mb)+m_][(nb)+n_]); \
} while (0)
#define SYNC do { __builtin_amdgcn_s_barrier();                               \
    asm volatile("s_waitcnt lgkmcnt(0)" ::: "memory");                        \
    __builtin_amdgcn_s_setprio(1); } while (0)
#define PEND do { __builtin_amdgcn_s_setprio(0);                              \
    __builtin_amdgcn_s_barrier(); } while (0)

    ST_A(0,0, ks);      ST_B(0,1, ks);      ST_A(0,1, ks);      ST_B(0,0, ks);
    ST_A(1,0, ks + 64); ST_B(1,1, ks + 64); ST_A(1,1, ks + 64);
    asm volatile("s_waitcnt vmcnt(6)" ::: "memory");
    __builtin_amdgcn_s_barrier();

    const int nIter = Kloc >> 7;
    for (int i = 0; i < nIter; ++i) {
        const bool nl = (i != nIter - 1);
        const int kt1 = ks + (2*i+1) * 64;
        const int kt2 = ks + (2*i+2) * 64;
        const int kt3 = kt2 + 64;
        DS_A(0,0); DS_B(0,0); ST_B(1,0,kt1);
        SYNC; MM(0,0); PEND;
        DS_B(0,1); if (nl) ST_A(0,0,kt2);
        SYNC; MM(0,2); PEND;
        DS_A(0,1); if (nl) ST_B(0,1,kt2);
        SYNC; MM(4,2); PEND;
        DS_B(0,0); if (nl) ST_A(0,1,kt2);
        SYNC; MM(4,0);
        __builtin_amdgcn_s_setprio(0);
        if (nl) asm volatile("s_waitcnt vmcnt(6)" ::: "memory");
        else    asm volatile("s_waitcnt vmcnt(0)" ::: "memory");
        __builtin_amdgcn_s_barrier();
        DS_A(1,0); DS_B(1,0); if (nl) ST_B(0,0,kt2);
        SYNC; MM(0,0); PEND;
        DS_B(1,1); if (nl) ST_A(1,0,kt3);
        SYNC; MM(0,2); PEND;
        DS_A(1,1); if (nl) ST_B(1,1,kt3);
        SYNC; MM(4,2); PEND;
        DS_B(1,0); if (nl) ST_A(1,1,kt3);
        SYNC; MM(4,0);
        __builtin_amdgcn_s_setprio(0);
        if (nl) asm volatile("s_waitcnt vmcnt(6)" ::: "memory");
        __builtin_amdgcn_s_barrier();
    }
#undef ST_A
#undef ST_B
#undef DS_A
#undef DS_B
#undef MM
#undef SYNC
#undef PEND

    const int mrow = m0 + wr * 128 + (lane >> 4) * 4;
    const int ncol = n0 + wc * 64 + (lane & 15);
    if (EPI == 0) {
        const int sel = n0 >> 10;
        __bf16* out = (sel == 0) ? o0 : (sel == 1) ? o1 : o2;
        const float* bp = (sel == 0) ? b0 : (sel == 1) ? b1 : b2;
        const float scl = (sel == 0) ? 0.125f : 1.0f;
        const int nc = ncol & 1023;
#pragma unroll
        for (int ni = 0; ni < 4; ++ni) {
            const float bvv = bp[nc + ni * 16];
#pragma unroll
            for (int mi = 0; mi < 8; ++mi)
#pragma unroll
                for (int r = 0; r < 4; ++r)
                    out[(size_t)(mrow + mi * 16 + r) * D_ + nc + ni * 16] =
                        (__bf16)((acc[mi][ni][r] + bvv) * scl);
        }
    } else if (EPI == 2) {
#pragma unroll
        for (int ni = 0; ni < 4; ++ni) {
            const float bvv = b0[ncol + ni * 16];
#pragma unroll
            for (int mi = 0; mi < 8; ++mi)
#pragma unroll
                for (int r = 0; r < 4; ++r) {
                    float v = acc[mi][ni][r] + bvv;
                    float ge = 0.5f * v * (1.0f + erff(v * 0.70710678118654752f));
                    o0[(size_t)(mrow + mi * 16 + r) * N + ncol + ni * 16] = (__bf16)ge;
                }
        }
    } else {
        const size_t MN = (size_t)M * N;
        float* Y = (slice < 2) ? (oF0 + (size_t)slice * MN) : (oF1 + (size_t)(slice - 2) * MN);
#pragma unroll
        for (int ni = 0; ni < 4; ++ni) {
            const float bvv = (slice == 0) ? b0[ncol + ni * 16] : 0.0f;
#pragma unroll
            for (int mi = 0; mi < 8; ++mi)
#pragma unroll
                for (int r = 0; r < 4; ++r)
                    Y[(size_t)(mrow + mi * 16 + r) * N + ncol + ni * 16] = acc[mi][ni][r] + bvv;
        }
    }
}

// ---------------------------------------------------------------- 128x128 GEMM (Wo)
template<int EPI>
__global__ __launch_bounds__(256, 2)
void gemm_kernel(const __bf16* __restrict__ A, const __bf16* __restrict__ Bt,
                 const float* __restrict__ bias, float* __restrict__ Cf,
                 __bf16* __restrict__ Cb, int M, int N, int K, float scale)
{
    __shared__ __bf16 As[128 * 64];
    __shared__ __bf16 Bs[128 * 64];
    const int tid = threadIdx.x;
    const int lane = tid & 63;
    const int w = tid >> 6, wr = w >> 1, wc = w & 1;
    const int nT = N >> 7;
    const int nwg = gridDim.x;
    const int bid = blockIdx.x;
    const int cpx = nwg >> 3;
    const int bswz = (bid & 7) * cpx + (bid >> 3);
    const int bm = bswz / nT, bn = bswz % nT;
    const int m0 = bm << 7, n0 = bn << 7;

    f32x4 acc[4][4] = {};

    const int chr = tid >> 3, chc = tid & 7;
    const __bf16* ga = A  + (size_t)(m0 + chr) * K + chc * 8;
    const __bf16* gb = Bt + (size_t)(n0 + chr) * K + chc * 8;
    char* la = (char*)As + (tid & ~63) * 16;
    char* lb = (char*)Bs + (tid & ~63) * 16;

    const __bf16* arow = As + (wr * 64 + (lane & 15)) * 64 + (lane >> 4) * 8;
    const __bf16* brow = Bs + (wc * 64 + (lane & 15)) * 64 + (lane >> 4) * 8;

    for (int k0 = 0; k0 < K; k0 += 64) {
#pragma unroll
        for (int i = 0; i < 4; ++i) {
            async16(ga + (size_t)(i * 32) * K + k0, la + i * 4096);
            async16(gb + (size_t)(i * 32) * K + k0, lb + i * 4096);
        }
        __syncthreads();
#pragma unroll
        for (int kk = 0; kk < 2; ++kk) {
            bf16x8 af[4], bf[4];
#pragma unroll
            for (int i = 0; i < 4; ++i) af[i] = *(const bf16x8*)(arow + i * 16 * 64 + kk * 32);
#pragma unroll
            for (int i = 0; i < 4; ++i) bf[i] = *(const bf16x8*)(brow + i * 16 * 64 + kk * 32);
#pragma unroll
            for (int mi = 0; mi < 4; ++mi)
#pragma unroll
                for (int ni = 0; ni < 4; ++ni)
                    acc[mi][ni] = mfma16(af[mi], bf[ni], acc[mi][ni]);
        }
        __syncthreads();
    }

    const int mb = m0 + wr * 64 + ((lane >> 4) * 4);
    const int nb = n0 + wc * 64 + (lane & 15);
#pragma unroll
    for (int ni = 0; ni < 4; ++ni) {
        const float bvv = bias[nb + ni * 16];
#pragma unroll
        for (int mi = 0; mi < 4; ++mi)
#pragma unroll
            for (int r = 0; r < 4; ++r)
                Cf[(size_t)(mb + mi * 16 + r) * N + nb + ni * 16] =
                    (acc[mi][ni][r] + bvv) * scale;
    }
}

// ---------------------------------------------------------------- attention
// 2 x 256-key chunks; 67 KB LDS -> 2 blocks/CU. 4 waves x 16 q-rows.
// Ks XOR-swizzled (pre-swizzled global source + swizzled ds_read);
// P XOR-swizzled (swizzled scalar write + swizzled ds_read).
__global__ __launch_bounds__(256, 2)
void attn_kernel(const __bf16* __restrict__ q, const __bf16* __restrict__ k,
                 const __bf16* __restrict__ v, const float* __restrict__ fmask,
                 __bf16* __restrict__ ctx)
{
    __shared__ __bf16 Ks[256 * 64];       // 32 KB; re-used as P in PV phase
    __shared__ __bf16 Vt[64 * 264];       // 33 KB, padded stride
    __shared__ float  negm[S_];
    const int bid = blockIdx.x;
    const int qt = bid & 7, h = (bid >> 3) & 15, b = bid >> 7;
    const int tid = threadIdx.x, lane = tid & 63, w = tid >> 6;
    const int r7 = lane & 7;

    const __bf16* kbase = k + ((size_t)b * S_) * D_ + h * 64;
    const __bf16* vbase = v + ((size_t)b * S_) * D_ + h * 64;
    char* kl = (char*)Ks + (tid & ~63) * 16;
    const int srow  = tid >> 3;                         // K-stage row within 32-group
    const int sslot = (tid & 7) ^ (srow & 7);           // pre-swizzled global slot

    for (int i = tid; i < S_; i += 256) negm[i] = (fmask[b * S_ + i] - 1.0f) * 1e30f;

    const __bf16* qbase = q + ((size_t)b * S_ + qt * 64 + w * 16) * D_ + h * 64;
    const bf16x8 qf0 = *(const bf16x8*)(qbase + (size_t)(lane & 15) * D_ + (lane >> 4) * 8);
    const bf16x8 qf1 = *(const bf16x8*)(qbase + (size_t)(lane & 15) * D_ + 32 + (lane >> 4) * 8);

    f32x4 sc[32];
#pragma unroll
    for (int i = 0; i < 32; ++i) { sc[i][0] = 0.f; sc[i][1] = 0.f; sc[i][2] = 0.f; sc[i][3] = 0.f; }

    // ---- QK^T in two 256-key chunks (swizzled Ks)
#pragma unroll
    for (int c = 0; c < 2; ++c) {
        if (c) __syncthreads();
#pragma unroll
        for (int i = 0; i < 8; ++i) {
            const int s = c * 256 + i * 32 + srow;
            async16(kbase + (size_t)s * D_ + sslot * 8, kl + i * 4096);
        }
        __syncthreads();
#pragma unroll
        for (int nf = 0; nf < 16; ++nf) {
            const __bf16* kr = Ks + (nf * 16 + (lane & 15)) * 64;
            const bf16x8 k0 = *(const bf16x8*)(kr + ((((lane >> 4))     ^ r7) << 3));
            const bf16x8 k1 = *(const bf16x8*)(kr + ((((lane >> 4) + 4) ^ r7) << 3));
            sc[c * 16 + nf] = mfma16(qf0, k0, sc[c * 16 + nf]);
            sc[c * 16 + nf] = mfma16(qf1, k1, sc[c * 16 + nf]);
        }
    }

    // ---- mask + softmax fully in registers
    float mx[4] = { -3e38f, -3e38f, -3e38f, -3e38f };
#pragma unroll
    for (int i = 0; i < 32; ++i) {
        const int key = (i >> 4) * 256 + (i & 15) * 16 + (lane & 15);
        const float nm = negm[key];
#pragma unroll
        for (int r = 0; r < 4; ++r) { sc[i][r] += nm; mx[r] = fmaxf(mx[r], sc[i][r]); }
    }
#pragma unroll
    for (int o = 8; o > 0; o >>= 1)
#pragma unroll
        for (int r = 0; r < 4; ++r) mx[r] = fmaxf(mx[r], __shfl_xor(mx[r], o));
    float smr[4] = { 0.f, 0.f, 0.f, 0.f };
#pragma unroll
    for (int i = 0; i < 32; ++i)
#pragma unroll
        for (int r = 0; r < 4; ++r) { float pp = __expf(sc[i][r] - mx[r]); sc[i][r] = pp; smr[r] += pp; }
#pragma unroll
    for (int o = 8; o > 0; o >>= 1)
#pragma unroll
        for (int r = 0; r < 4; ++r) smr[r] += __shfl_xor(smr[r], o);
    float inv[4];
#pragma unroll
    for (int r = 0; r < 4; ++r) inv[r] = 1.0f / smr[r];

    // ---- PV in two chunks: swizzled P overlays Ks, Vt staged per chunk
    f32x4 co[4] = {};
#pragma unroll
    for (int c = 0; c < 2; ++c) {
        __syncthreads();
        __bf16* P = Ks + w * (16 * 256);
#pragma unroll
        for (int nf = 0; nf < 16; ++nf)
#pragma unroll
            for (int r = 0; r < 4; ++r) {
                const int row = (lane >> 4) * 4 + r;
                const int col = nf * 16 + (lane & 15);
                P[row * 256 + (((col >> 3) ^ (row & 7)) << 3) + (col & 7)] =
                    (__bf16)sc[c * 16 + nf][r];
            }
#pragma unroll
        for (int i = 0; i < 8; ++i) {
            const int s = i * 32 + (tid >> 3), d0 = (tid & 7) * 8;
            bf16x8 vv = *(const bf16x8*)(vbase + (size_t)(c * 256 + s) * D_ + d0);
#pragma unroll
            for (int j = 0; j < 8; ++j) Vt[(d0 + j) * 264 + s] = vv[j];
        }
        __syncthreads();
#pragma unroll
        for (int kk2 = 0; kk2 < 8; ++kk2) {
            const int row = lane & 15;
            const int slot = kk2 * 4 + (lane >> 4);
            bf16x8 pa = *(const bf16x8*)(P + row * 256 + ((slot ^ r7) << 3));
#pragma unroll
            for (int nf = 0; nf < 4; ++nf) {
                bf16x8 vf = *(const bf16x8*)(Vt + (nf * 16 + (lane & 15)) * 264 + kk2 * 32 + (lane >> 4) * 8);
                co[nf] = mfma16(pa, vf, co[nf]);
            }
        }
    }

    __bf16* cb = ctx + ((size_t)b * S_ + qt * 64 + w * 16) * D_ + h * 64;
#pragma unroll
    for (int nf = 0; nf < 4; ++nf)
#pragma unroll
        for (int r = 0; r < 4; ++r)
            cb[((lane >> 4) * 4 + r) * D_ + nf * 16 + (lane & 15)] = (__bf16)(co[nf][r] * inv[r]);
}

// ---------------------------------------------------------------- launcher
extern "C" void kernel_launch(void* const* d_in, const int* in_sizes, int n_in,
                              void* d_out, int out_size, void* d_ws, size_t ws_size,
                              hipStream_t stream)
{
    (void)in_sizes; (void)n_in; (void)out_size; (void)ws_size;
    const int*   ids   = (const int*)d_in[0];
    const int*   lgs   = (const int*)d_in[1];
    const float* amask = (const float*)d_in[2];
    const float* wemb  = (const float*)d_in[3];
    const float* pemb  = (const float*)d_in[4];
    const float* lemb  = (const float*)d_in[5];
    const float* lng   = (const float*)d_in[6];
    const float* lnbv  = (const float*)d_in[7];
    const float* Wq = (const float*)d_in[8];  const float* bq = (const float*)d_in[9];
    const float* Wk = (const float*)d_in[10]; const float* bk = (const float*)d_in[11];
    const float* Wv = (const float*)d_in[12]; const float* bv = (const float*)d_in[13];
    const float* Wo = (const float*)d_in[14]; const float* bo = (const float*)d_in[15];
    const float* g1 = (const float*)d_in[16]; const float* be1 = (const float*)d_in[17];
    const float* W1 = (const float*)d_in[18]; const float* b1 = (const float*)d_in[19];
    const float* W2 = (const float*)d_in[20]; const float* b2 = (const float*)d_in[21];
    const float* g2 = (const float*)d_in[22]; const float* be2 = (const float*)d_in[23];

    char* p = (char*)d_ws;
    auto take = [&](size_t n) { char* r = p; p += (n + 255) & ~(size_t)255; return r; };
    float*  xf    = (float*) take((size_t)ROWS * D_ * 4);
    __bf16* xb    = (__bf16*)take((size_t)ROWS * D_ * 2);
    __bf16* qb    = (__bf16*)take((size_t)ROWS * D_ * 2);   // FFN2 partial slice 2 overlay
    __bf16* kb    = (__bf16*)take((size_t)ROWS * D_ * 2);
    __bf16* vbuf  = (__bf16*)take((size_t)ROWS * D_ * 2);
    __bf16* cxb   = (__bf16*)take((size_t)ROWS * D_ * 2);
    __bf16* hb    = (__bf16*)take((size_t)ROWS * FF_ * 2);
    float*  yfp   = (float*) take((size_t)2 * ROWS * D_ * 4);  // Wo out / FFN2 slices 0,1
    __bf16* wqkvT = (__bf16*)take((size_t)3 * D_ * D_ * 2);
    __bf16* woT   = (__bf16*)take((size_t)D_ * D_ * 2);
    __bf16* w1T   = (__bf16*)take((size_t)D_ * FF_ * 2);
    __bf16* w2T   = (__bf16*)take((size_t)FF_ * D_ * 2);
    float*  y23   = (float*)qb;   // 33.6 MB spanning qb..cxb (dead during FFN2)

    const int gQKV = (ROWS / 256) * (3 * D_ / 256);   // 192
    const int gF1  = (ROWS / 256) * (FF_ / 256);      // 256
    const int gF2  = 4 * (ROWS / 256) * (D_ / 256);   // 256 (split-K=4)
    const int gWo  = (ROWS / 128) * (D_ / 128);       // 256

    embed_ln_kernel<<<ROWS, 256, 0, stream>>>(ids, lgs, amask, wemb, pemb, lemb, lng, lnbv, xf, xb);

    for (int l = 0; l < 12; ++l) {
        const size_t woff = (size_t)l * D_ * D_;
        const size_t foff = (size_t)l * D_ * FF_;
        conv_all_kernel<<<3072, 256, 0, stream>>>(Wq + woff, Wk + woff, Wv + woff, Wo + woff,
                                                  W1 + foff, W2 + foff,
                                                  wqkvT, woT, w1T, w2T);

        gemm256_kernel<0><<<gQKV, 512, 0, stream>>>(xb, wqkvT, bq + l * D_, bk + l * D_, bv + l * D_,
                                                    qb, kb, vbuf, nullptr, nullptr,
                                                    ROWS, 3 * D_, D_, D_, 12, gQKV);

        attn_kernel<<<B_ * H_ * (S_ / 64), 256, 0, stream>>>(qb, kb, vbuf, amask, cxb);

        gemm_kernel<1><<<gWo, 256, 0, stream>>>(cxb, woT, bo + l * D_, yfp, nullptr, ROWS, D_, D_, 1.0f);
        ln_resN_kernel<1><<<ROWS, 256, 0, stream>>>(xf, yfp, nullptr,
                                                    g1 + l * D_, be1 + l * D_, nullptr, xf, xb);

        gemm256_kernel<2><<<gF1, 512, 0, stream>>>(xb, w1T, b1 + l * FF_, nullptr, nullptr,
                                                   hb, nullptr, nullptr, nullptr, nullptr,
                                                   ROWS, FF_, D_, D_, 16, gF1);
        gemm256_kernel<3><<<gF2, 512, 0, stream>>>(hb, w2T, b2 + l * D_, nullptr, nullptr,
                                                   nullptr, nullptr, nullptr, yfp, y23,
                                                   ROWS, D_, FF_, D_, 4, 64);

        float* dst = (l == 11) ? (float*)d_out : xf;
        ln_resN_kernel<4><<<ROWS, 256, 0, stream>>>(xf, yfp, y23,
                                                    g2 + l * D_, be2 + l * D_, amask, dst, xb);
    }
}

// Round 6
// 2591.880 us; speedup vs baseline: 1.5702x; 1.0508x over previous
//
#include <hip/hip_runtime.h>
#include <math.h>

typedef float  f32x4  __attribute__((ext_vector_type(4)));
typedef __bf16 bf16x8 __attribute__((ext_vector_type(8)));
typedef __bf16 bf16x4 __attribute__((ext_vector_type(4)));

#define DEV __device__ __forceinline__

DEV f32x4 mfma16(bf16x8 a, bf16x8 b, f32x4 c) {
    return __builtin_amdgcn_mfma_f32_16x16x32_bf16(a, b, c, 0, 0, 0);
}

DEV void async16(const void* g, void* l) {
    __builtin_amdgcn_global_load_lds((const __attribute__((address_space(1))) void*)g,
                                     (__attribute__((address_space(3))) void*)l, 16, 0, 0);
}

// ---------------------------------------------------------------- constants
constexpr int B_  = 8;
constexpr int S_  = 512;
constexpr int D_  = 1024;
constexpr int H_  = 16;
constexpr int FF_ = 4096;
constexpr int ROWS = B_ * S_;   // 4096

// ---------------------------------------------------------------- embed + LN
__global__ __launch_bounds__(256)
void embed_ln_kernel(const int* __restrict__ ids, const int* __restrict__ lgs,
                     const float* __restrict__ fmask,
                     const float* __restrict__ wemb, const float* __restrict__ pemb,
                     const float* __restrict__ lemb,
                     const float* __restrict__ g, const float* __restrict__ bb,
                     float* __restrict__ xf, __bf16* __restrict__ xb)
{
    __shared__ float2 red[4];
    const int row = blockIdx.x;
    const int s   = row & (S_ - 1);
    const int t   = threadIdx.x;
    const int lane = t & 63, w = t >> 6;
    const int id = ids[row], lg = lgs[row];

    float4 wv = *(const float4*)(wemb + ((size_t)id << 10) + t * 4);
    float4 pv = *(const float4*)(pemb + ((size_t)s  << 10) + t * 4);
    float4 lv = *(const float4*)(lemb + ((size_t)lg << 10) + t * 4);
    float a[4] = { wv.x + pv.x + lv.x, wv.y + pv.y + lv.y,
                   wv.z + pv.z + lv.z, wv.w + pv.w + lv.w };

    float sm = a[0] + a[1] + a[2] + a[3];
    float sq = a[0]*a[0] + a[1]*a[1] + a[2]*a[2] + a[3]*a[3];
#pragma unroll
    for (int o = 32; o > 0; o >>= 1) { sm += __shfl_down(sm, o); sq += __shfl_down(sq, o); }
    if (lane == 0) red[w] = make_float2(sm, sq);
    __syncthreads();
    float ts = red[0].x + red[1].x + red[2].x + red[3].x;
    float tq = red[0].y + red[1].y + red[2].y + red[3].y;
    float mean = ts * (1.0f / D_);
    float var  = tq * (1.0f / D_) - mean * mean;
    float rs   = rsqrtf(var + 1e-12f);
    float fm   = fmask[row];

    float4 gv = *(const float4*)(g  + t * 4);
    float4 bv = *(const float4*)(bb + t * 4);
    float o0 = ((a[0]-mean)*rs*gv.x + bv.x) * fm;
    float o1 = ((a[1]-mean)*rs*gv.y + bv.y) * fm;
    float o2 = ((a[2]-mean)*rs*gv.z + bv.z) * fm;
    float o3 = ((a[3]-mean)*rs*gv.w + bv.w) * fm;
    *(float4*)(xf + ((size_t)row << 10) + t * 4) = make_float4(o0, o1, o2, o3);
    bf16x4 ob; ob[0] = (__bf16)o0; ob[1] = (__bf16)o1; ob[2] = (__bf16)o2; ob[3] = (__bf16)o3;
    *(bf16x4*)(xb + ((size_t)row << 10) + t * 4) = ob;
}

// ---------------------------- residual + NP bf16 partials + LN (+mask)
template<int NP>
__global__ __launch_bounds__(256)
void ln_resN_kernel(const float* __restrict__ xin, const __bf16* __restrict__ yp,
                    const float* __restrict__ g, const float* __restrict__ bb,
                    const float* __restrict__ fmask,
                    float* __restrict__ xf_out, __bf16* __restrict__ xb_out)
{
    constexpr size_t MN = (size_t)ROWS * D_;
    __shared__ float2 red[4];
    const int row = blockIdx.x;
    const int t   = threadIdx.x;
    const int lane = t & 63, w = t >> 6;
    const size_t base = ((size_t)row << 10) + t * 4;

    float4 xv = *(const float4*)(xin + base);
    float a[4] = { xv.x, xv.y, xv.z, xv.w };
#pragma unroll
    for (int pslice = 0; pslice < NP; ++pslice) {
        bf16x4 yv = *(const bf16x4*)(yp + base + (size_t)pslice * MN);
#pragma unroll
        for (int j = 0; j < 4; ++j) a[j] += (float)yv[j];
    }

    float sm = a[0] + a[1] + a[2] + a[3];
    float sq = a[0]*a[0] + a[1]*a[1] + a[2]*a[2] + a[3]*a[3];
#pragma unroll
    for (int o = 32; o > 0; o >>= 1) { sm += __shfl_down(sm, o); sq += __shfl_down(sq, o); }
    if (lane == 0) red[w] = make_float2(sm, sq);
    __syncthreads();
    float ts = red[0].x + red[1].x + red[2].x + red[3].x;
    float tq = red[0].y + red[1].y + red[2].y + red[3].y;
    float mean = ts * (1.0f / D_);
    float var  = tq * (1.0f / D_) - mean * mean;
    float rs   = rsqrtf(var + 1e-12f);
    float fm   = fmask ? fmask[row] : 1.0f;

    float4 gv = *(const float4*)(g  + t * 4);
    float4 bv = *(const float4*)(bb + t * 4);
    float o0 = ((a[0]-mean)*rs*gv.x + bv.x) * fm;
    float o1 = ((a[1]-mean)*rs*gv.y + bv.y) * fm;
    float o2 = ((a[2]-mean)*rs*gv.z + bv.z) * fm;
    float o3 = ((a[3]-mean)*rs*gv.w + bv.w) * fm;
    *(float4*)(xf_out + base) = make_float4(o0, o1, o2, o3);
    bf16x4 ob; ob[0] = (__bf16)o0; ob[1] = (__bf16)o1; ob[2] = (__bf16)o2; ob[3] = (__bf16)o3;
    *(bf16x4*)(xb_out + base) = ob;
}

// --------------------- fused weight convert fp32[K][N] -> bf16[N][K], all 6 mats
__global__ __launch_bounds__(256)
void conv_all_kernel(const float* __restrict__ Wq, const float* __restrict__ Wk,
                     const float* __restrict__ Wv, const float* __restrict__ Wo,
                     const float* __restrict__ W1, const float* __restrict__ W2,
                     __bf16* __restrict__ qkvT, __bf16* __restrict__ woT,
                     __bf16* __restrict__ w1T, __bf16* __restrict__ w2T)
{
    __shared__ __bf16 tile[64][66];
    const int id = blockIdx.x;
    const float* src; __bf16* dst; int K, N, t;
    if (id < 1024) {
        const int m = id >> 8; t = id & 255; K = 1024; N = 1024;
        src = (m == 0) ? Wq : (m == 1) ? Wk : (m == 2) ? Wv : Wo;
        dst = (m == 3) ? woT : qkvT + (size_t)m * 1024 * 1024;
    } else if (id < 2048) {
        t = id - 1024; K = 1024; N = 4096; src = W1; dst = w1T;
    } else {
        t = id - 2048; K = 4096; N = 1024; src = W2; dst = w2T;
    }
    const int ktiles = K >> 6;
    const int tk = t % ktiles, tn = t / ktiles;
    const int k0 = tk << 6, n0 = tn << 6;
    const int tt = threadIdx.x;
#pragma unroll
    for (int i = 0; i < 16; ++i) {
        int idx = i * 256 + tt;
        int r = idx >> 6, c = idx & 63;
        tile[c][r] = (__bf16)src[(size_t)(k0 + r) * N + n0 + c];
    }
    __syncthreads();
#pragma unroll
    for (int i = 0; i < 16; ++i) {
        int idx = i * 256 + tt;
        int r = idx >> 6, c = idx & 63;
        dst[(size_t)(n0 + r) * K + k0 + c] = tile[r][c];
    }
}

// ================================================================ 256x256 8-phase GEMM
// EPI 0: QKV (q*0.125 bf16 row-major; k bf16 row-major; V -> TRANSPOSED vT[b][h][64][512])
// EPI 2: GELU->bf16.  EPI 3: split-K bf16 partials at oP + slice*M*N.
template<int EPI>
__global__ __launch_bounds__(512, 2)
void gemm256_kernel(const __bf16* __restrict__ A, const __bf16* __restrict__ Bt,
                    const float* __restrict__ b0, const float* __restrict__ b1,
                    const float* __restrict__ b2,
                    __bf16* __restrict__ o0, __bf16* __restrict__ o1,
                    __bf16* __restrict__ o2, __bf16* __restrict__ oP,
                    int M, int N, int K, int Kloc, int nTn, int tiles)
{
    __shared__ __bf16 lds[65536];
    const int tid  = threadIdx.x;
    const int lane = tid & 63;
    const int w    = tid >> 6;
    const int wr   = w >> 2, wc = w & 3;

    const int nwg = gridDim.x, bid = blockIdx.x;
    const int cpx = nwg >> 3;
    const int bswz = (bid & 7) * cpx + (bid >> 3);
    const int slice = bswz / tiles;
    const int tile  = bswz % tiles;
    const int bm = tile / nTn, bn = tile % nTn;
    const int m0 = bm << 8, n0 = bn << 8;
    const int ks = slice * Kloc;

    const int rrT = tid >> 3;
    const size_t swzK  = (size_t)(((tid & 7) ^ (rrT & 7)) * 8);
    const size_t aoff0 = (size_t)rrT * K + swzK;
    const size_t boff0 = (size_t)((rrT >> 5) * 64 + (rrT & 31)) * K + swzK;
    const size_t boff1 = (size_t)(((rrT >> 5) + 2) * 64 + (rrT & 31)) * K + swzK;
    const int wub = w * 512;

    const int aread = (wr * 64 + (lane & 15)) * 64;
    const int bread = (wc * 32 + (lane & 15)) * 64;
    const int csw0 = ((      (lane >> 4) * 16) ^ ((lane & 7) << 4)) >> 1;
    const int csw1 = ((64 +  (lane >> 4) * 16) ^ ((lane & 7) << 4)) >> 1;

    f32x4 acc[8][4] = {};
    bf16x8 a_[4][2], b_[2][2];

#define ST_A(p,h,kt) do {                                                     \
    const size_t gb = (size_t)(m0 + (h) * 64) * K + (kt);                     \
    async16(A + gb + aoff0,                  lds + ((p)*2+(h))*8192 + wub);   \
    async16(A + gb + (size_t)128*K + aoff0,  lds + ((p)*2+(h))*8192 + 4096 + wub); \
} while (0)
#define ST_B(p,h,kt) do {                                                     \
    const size_t gb = (size_t)(n0 + (h) * 32) * K + (kt);                     \
    async16(Bt + gb + boff0, lds + 32768 + ((p)*2+(h))*8192 + wub);           \
    async16(Bt + gb + boff1, lds + 32768 + ((p)*2+(h))*8192 + 4096 + wub);    \
} while (0)
#define DS_A(p,h) do {                                                        \
    const __bf16* base_ = lds + ((p)*2+(h))*8192 + aread;                     \
    _Pragma("unroll") for (int m_ = 0; m_ < 4; ++m_) {                        \
        a_[m_][0] = *(const bf16x8*)(base_ + m_*1024 + csw0);                 \
        a_[m_][1] = *(const bf16x8*)(base_ + m_*1024 + csw1);                 \
    }                                                                         \
} while (0)
#define DS_B(p,h) do {                                                        \
    const __bf16* base_ = lds + 32768 + ((p)*2+(h))*8192 + bread;             \
    _Pragma("unroll") for (int n_ = 0; n_ < 2; ++n_) {                        \
        b_[n_][0] = *(const bf16x8*)(base_ + n_*1024 + csw0);                 \
        b_[n_][1] = *(const bf16x8*)(base_ + n_*1024 + csw1);                 \
    }                                                                         \
} while (0)
#define MM(mb,nb) do {                                                        \
    _Pragma("unroll") for (int m_ = 0; m_ < 4; ++m_)                          \
    _Pragma("unroll") for (int n_ = 0; n_ < 2; ++n_)                          \
    _Pragma("unroll") for (int k_ = 0; k_ < 2; ++k_)                          \
        acc[(mb)+m_][(nb)+n_] = mfma16(a_[m_][k_], b_[n_][k_], acc[(mb)+m_][(nb)+n_]); \
} while (0)
#define SYNC do { __builtin_amdgcn_s_barrier();                               \
    asm volatile("s_waitcnt lgkmcnt(0)" ::: "memory");                        \
    __builtin_amdgcn_s_setprio(1); } while (0)
#define PEND do { __builtin_amdgcn_s_setprio(0);                              \
    __builtin_amdgcn_s_barrier(); } while (0)

    ST_A(0,0, ks);      ST_B(0,1, ks);      ST_A(0,1, ks);      ST_B(0,0, ks);
    ST_A(1,0, ks + 64); ST_B(1,1, ks + 64); ST_A(1,1, ks + 64);
    asm volatile("s_waitcnt vmcnt(6)" ::: "memory");
    __builtin_amdgcn_s_barrier();

    const int nIter = Kloc >> 7;
    for (int i = 0; i < nIter; ++i) {
        const bool nl = (i != nIter - 1);
        const int kt1 = ks + (2*i+1) * 64;
        const int kt2 = ks + (2*i+2) * 64;
        const int kt3 = kt2 + 64;
        DS_A(0,0); DS_B(0,0); ST_B(1,0,kt1);
        SYNC; MM(0,0); PEND;
        DS_B(0,1); if (nl) ST_A(0,0,kt2);
        SYNC; MM(0,2); PEND;
        DS_A(0,1); if (nl) ST_B(0,1,kt2);
        SYNC; MM(4,2); PEND;
        DS_B(0,0); if (nl) ST_A(0,1,kt2);
        SYNC; MM(4,0);
        __builtin_amdgcn_s_setprio(0);
        if (nl) asm volatile("s_waitcnt vmcnt(6)" ::: "memory");
        else    asm volatile("s_waitcnt vmcnt(0)" ::: "memory");
        __builtin_amdgcn_s_barrier();
        DS_A(1,0); DS_B(1,0); if (nl) ST_B(0,0,kt2);
        SYNC; MM(0,0); PEND;
        DS_B(1,1); if (nl) ST_A(1,0,kt3);
        SYNC; MM(0,2); PEND;
        DS_A(1,1); if (nl) ST_B(1,1,kt3);
        SYNC; MM(4,2); PEND;
        DS_B(1,0); if (nl) ST_A(1,1,kt3);
        SYNC; MM(4,0);
        __builtin_amdgcn_s_setprio(0);
        if (nl) asm volatile("s_waitcnt vmcnt(6)" ::: "memory");
        __builtin_amdgcn_s_barrier();
    }
#undef ST_A
#undef ST_B
#undef DS_A
#undef DS_B
#undef MM
#undef SYNC
#undef PEND

    const int mrow = m0 + wr * 128 + (lane >> 4) * 4;
    const int ncol = n0 + wc * 64 + (lane & 15);
    if (EPI == 0) {
        const int sel = n0 >> 10;
        const int nc = ncol & 1023;
        if (sel < 2) {
            __bf16* out = (sel == 0) ? o0 : o1;
            const float* bp = (sel == 0) ? b0 : b1;
            const float scl = (sel == 0) ? 0.125f : 1.0f;
#pragma unroll
            for (int ni = 0; ni < 4; ++ni) {
                const float bvv = bp[nc + ni * 16];
#pragma unroll
                for (int mi = 0; mi < 8; ++mi)
#pragma unroll
                    for (int r = 0; r < 4; ++r)
                        out[(size_t)(mrow + mi * 16 + r) * D_ + nc + ni * 16] =
                            (__bf16)((acc[mi][ni][r] + bvv) * scl);
            }
        } else {
            // V -> vT[((b*16+h)*64 + dh)][s], packed 4 consecutive s per store
#pragma unroll
            for (int ni = 0; ni < 4; ++ni) {
                const int dhf = nc + ni * 16;
                const float bvv = b2[dhf];
                const int hh = dhf >> 6, dh = dhf & 63;
#pragma unroll
                for (int mi = 0; mi < 8; ++mi) {
                    const int gm0 = mrow + mi * 16;
                    const int bb_ = gm0 >> 9, s0 = gm0 & 511;
                    bf16x4 pk;
#pragma unroll
                    for (int r = 0; r < 4; ++r) pk[r] = (__bf16)(acc[mi][ni][r] + bvv);
                    *(bf16x4*)(o2 + ((size_t)((bb_ * 16 + hh) * 64 + dh) << 9) + s0) = pk;
                }
            }
        }
    } else if (EPI == 2) {
#pragma unroll
        for (int ni = 0; ni < 4; ++ni) {
            const float bvv = b0[ncol + ni * 16];
#pragma unroll
            for (int mi = 0; mi < 8; ++mi)
#pragma unroll
                for (int r = 0; r < 4; ++r) {
                    float v = acc[mi][ni][r] + bvv;
                    float ge = 0.5f * v * (1.0f + erff(v * 0.70710678118654752f));
                    o0[(size_t)(mrow + mi * 16 + r) * N + ncol + ni * 16] = (__bf16)ge;
                }
        }
    } else {
        __bf16* Y = oP + (size_t)slice * M * N;
#pragma unroll
        for (int ni = 0; ni < 4; ++ni) {
            const float bvv = (slice == 0) ? b0[ncol + ni * 16] : 0.0f;
#pragma unroll
            for (int mi = 0; mi < 8; ++mi)
#pragma unroll
                for (int r = 0; r < 4; ++r)
                    Y[(size_t)(mrow + mi * 16 + r) * N + ncol + ni * 16] =
                        (__bf16)(acc[mi][ni][r] + bvv);
        }
    }
}

// ---------------------------------------------------------------- 128x128 GEMM (Wo)
// writes bf16 y = acc + bias
__global__ __launch_bounds__(256, 2)
void gemm_kernel(const __bf16* __restrict__ A, const __bf16* __restrict__ Bt,
                 const float* __restrict__ bias, __bf16* __restrict__ Cb,
                 int M, int N, int K)
{
    __shared__ __bf16 As[128 * 64];
    __shared__ __bf16 Bs[128 * 64];
    const int tid = threadIdx.x;
    const int lane = tid & 63;
    const int w = tid >> 6, wr = w >> 1, wc = w & 1;
    const int nT = N >> 7;
    const int nwg = gridDim.x;
    const int bid = blockIdx.x;
    const int cpx = nwg >> 3;
    const int bswz = (bid & 7) * cpx + (bid >> 3);
    const int bm = bswz / nT, bn = bswz % nT;
    const int m0 = bm << 7, n0 = bn << 7;

    f32x4 acc[4][4] = {};

    const int chr = tid >> 3, chc = tid & 7;
    const __bf16* ga = A  + (size_t)(m0 + chr) * K + chc * 8;
    const __bf16* gb = Bt + (size_t)(n0 + chr) * K + chc * 8;
    char* la = (char*)As + (tid & ~63) * 16;
    char* lb = (char*)Bs + (tid & ~63) * 16;

    const __bf16* arow = As + (wr * 64 + (lane & 15)) * 64 + (lane >> 4) * 8;
    const __bf16* brow = Bs + (wc * 64 + (lane & 15)) * 64 + (lane >> 4) * 8;

    for (int k0 = 0; k0 < K; k0 += 64) {
#pragma unroll
        for (int i = 0; i < 4; ++i) {
            async16(ga + (size_t)(i * 32) * K + k0, la + i * 4096);
            async16(gb + (size_t)(i * 32) * K + k0, lb + i * 4096);
        }
        __syncthreads();
#pragma unroll
        for (int kk = 0; kk < 2; ++kk) {
            bf16x8 af[4], bf[4];
#pragma unroll
            for (int i = 0; i < 4; ++i) af[i] = *(const bf16x8*)(arow + i * 16 * 64 + kk * 32);
#pragma unroll
            for (int i = 0; i < 4; ++i) bf[i] = *(const bf16x8*)(brow + i * 16 * 64 + kk * 32);
#pragma unroll
            for (int mi = 0; mi < 4; ++mi)
#pragma unroll
                for (int ni = 0; ni < 4; ++ni)
                    acc[mi][ni] = mfma16(af[mi], bf[ni], acc[mi][ni]);
        }
        __syncthreads();
    }

    const int mb = m0 + wr * 64 + ((lane >> 4) * 4);
    const int nb = n0 + wc * 64 + (lane & 15);
#pragma unroll
    for (int ni = 0; ni < 4; ++ni) {
        const float bvv = bias[nb + ni * 16];
#pragma unroll
        for (int mi = 0; mi < 4; ++mi)
#pragma unroll
            for (int r = 0; r < 4; ++r)
                Cb[(size_t)(mb + mi * 16 + r) * N + nb + ni * 16] =
                    (__bf16)(acc[mi][ni][r] + bvv);
    }
}

// ---------------------------------------------------------------- attention v2
// Swapped QK^T (A=K, B=Q): S^T in regs, q = lane&15, key = (lane>>4)*4+r +16i.
// V pre-transposed in global (vT[b][h][64][512]); staged via global_load_lds.
// P packed b64 writes; PV: A=V^T-frag, B=P-frag -> O^T; packed ctx stores.
__global__ __launch_bounds__(256, 2)
void attn_kernel(const __bf16* __restrict__ q, const __bf16* __restrict__ k,
                 const __bf16* __restrict__ vT, const float* __restrict__ fmask,
                 __bf16* __restrict__ ctx)
{
    __shared__ __bf16 Ks[256 * 64];       // 32 KB; overlaid by P in PV phase
    __shared__ __bf16 Vt[64 * 256];       // 32 KB, swizzled content
    __shared__ float  negm[S_];
    const int bid = blockIdx.x;
    const int qt = bid & 7, h = (bid >> 3) & 15, b = bid >> 7;
    const int tid = threadIdx.x, lane = tid & 63, w = tid >> 6;
    const int g = lane >> 4, q15 = lane & 15, r7 = lane & 7;

    const __bf16* kbase  = k  + ((size_t)b * S_) * D_ + h * 64;
    const __bf16* vTbase = vT + ((size_t)((b * 16 + h) * 64) << 9);   // row d stride 512
    char* kl = (char*)Ks + (tid & ~63) * 16;
    char* vl = (char*)Vt + (tid & ~63) * 16;
    const int srow  = tid >> 3;
    const int sslot = (tid & 7) ^ (srow & 7);
    const int vrow  = tid >> 5;                       // d = i*8 + vrow
    // K-chunk stage (8 issues)
#define ST_K(c) do { _Pragma("unroll") for (int i_ = 0; i_ < 8; ++i_) {       \
        const int s_ = (c) * 256 + i_ * 32 + srow;                            \
        async16(kbase + (size_t)s_ * D_ + sslot * 8, kl + i_ * 4096); } } while (0)
    // V-chunk stage (8 issues): LDS[d][slot16] = vT[d][slot16 ^ (d&7)]
#define ST_V(c) do { _Pragma("unroll") for (int i_ = 0; i_ < 8; ++i_) {       \
        const int d_ = i_ * 8 + vrow;                                         \
        async16(vTbase + ((size_t)d_ << 9) + (c) * 256 +                      \
                (((tid & 31) ^ (d_ & 7)) << 3), vl + i_ * 4096); } } while (0)

    ST_K(0);
    for (int i = tid; i < S_; i += 256) negm[i] = (fmask[b * S_ + i] - 1.0f) * 1e30f;

    const __bf16* qbase = q + ((size_t)b * S_ + qt * 64 + w * 16) * D_ + h * 64;
    const bf16x8 qf0 = *(const bf16x8*)(qbase + (size_t)q15 * D_ + g * 8);
    const bf16x8 qf1 = *(const bf16x8*)(qbase + (size_t)q15 * D_ + 32 + g * 8);

    f32x4 sc[32];
#pragma unroll
    for (int i = 0; i < 32; ++i) { sc[i][0] = 0.f; sc[i][1] = 0.f; sc[i][2] = 0.f; sc[i][3] = 0.f; }

#define QKT(c) do { _Pragma("unroll") for (int nf = 0; nf < 16; ++nf) {       \
        const __bf16* kr = Ks + (nf * 16 + q15) * 64;                         \
        const bf16x8 kf0 = *(const bf16x8*)(kr + ((g ^ r7) << 3));            \
        const bf16x8 kf1 = *(const bf16x8*)(kr + (((g + 4) ^ r7) << 3));      \
        sc[(c)*16+nf] = mfma16(kf0, qf0, sc[(c)*16+nf]);                      \
        sc[(c)*16+nf] = mfma16(kf1, qf1, sc[(c)*16+nf]); } } while (0)

    __syncthreads();          // B1: K c0 ready
    ST_V(0);                  // V c0 flies under QK^T
    QKT(0);
    __syncthreads();          // B2: K c0 reads done
    ST_K(1);
    __syncthreads();          // B3: K c1 ready (V c0 also arrived)
    QKT(1);

    // ---- mask + softmax (per-lane: q fixed, keys across regs + groups)
    float mx = -3e38f;
#pragma unroll
    for (int i = 0; i < 32; ++i) {
        const float4 nm4 = *(const float4*)(negm + ((i >> 4) * 256 + (i & 15) * 16 + 4 * g));
        sc[i][0] += nm4.x; sc[i][1] += nm4.y; sc[i][2] += nm4.z; sc[i][3] += nm4.w;
        mx = fmaxf(mx, fmaxf(fmaxf(sc[i][0], sc[i][1]), fmaxf(sc[i][2], sc[i][3])));
    }
    mx = fmaxf(mx, __shfl_xor(mx, 16));
    mx = fmaxf(mx, __shfl_xor(mx, 32));
    float sum = 0.f;
#pragma unroll
    for (int i = 0; i < 32; ++i)
#pragma unroll
        for (int r = 0; r < 4; ++r) { float pp = __expf(sc[i][r] - mx); sc[i][r] = pp; sum += pp; }
    sum += __shfl_xor(sum, 16);
    sum += __shfl_xor(sum, 32);
    const float inv = 1.0f / sum;

    // ---- PV: P[q][key] per wave (8 KB), XOR-swizzled; A=V^T-frag, B=P-frag
    __bf16* P = Ks + w * 4096;
    f32x4 co[4] = {};
#define WR_P(c) do { _Pragma("unroll") for (int i_ = 0; i_ < 16; ++i_) {      \
        bf16x4 pk;                                                            \
        _Pragma("unroll") for (int r = 0; r < 4; ++r) pk[r] = (__bf16)sc[(c)*16+i_][r]; \
        *(bf16x4*)(P + q15 * 256 + ((i_ * 16 + 4 * g) ^ (8 * r7))) = pk; } } while (0)
#define PV() do { _Pragma("unroll") for (int kt = 0; kt < 8; ++kt) {          \
        const bf16x8 pf = *(const bf16x8*)(P + q15 * 256 + ((kt * 32 + 8 * g) ^ (8 * r7))); \
        _Pragma("unroll") for (int nf = 0; nf < 4; ++nf) {                    \
            const int d_ = nf * 16 + q15;                                     \
            const bf16x8 vf = *(const bf16x8*)(Vt + d_ * 256 + ((kt * 32 + 8 * g) ^ (8 * r7))); \
            co[nf] = mfma16(vf, pf, co[nf]); } } } while (0)

    __syncthreads();          // B4: K c1 reads done -> Ks free for P
    WR_P(0);
    __syncthreads();          // B5: P c0 visible (V c0 resident)
    PV();
    __syncthreads();          // B6: PV c0 reads done
    WR_P(1);
    ST_V(1);
    __syncthreads();          // B7: P c1 + V c1 ready
    PV();
#undef ST_K
#undef ST_V
#undef QKT
#undef WR_P
#undef PV

    // ---- output O[q][d]: q = lane&15, d = nf*16 + 4g + r (4 consecutive)
    __bf16* cb = ctx + ((size_t)b * S_ + qt * 64 + w * 16 + q15) * D_ + h * 64;
#pragma unroll
    for (int nf = 0; nf < 4; ++nf) {
        bf16x4 o4;
#pragma unroll
        for (int r = 0; r < 4; ++r) o4[r] = (__bf16)(co[nf][r] * inv);
        *(bf16x4*)(cb + nf * 16 + 4 * g) = o4;
    }
}

// ---------------------------------------------------------------- launcher
extern "C" void kernel_launch(void* const* d_in, const int* in_sizes, int n_in,
                              void* d_out, int out_size, void* d_ws, size_t ws_size,
                              hipStream_t stream)
{
    (void)in_sizes; (void)n_in; (void)out_size; (void)ws_size;
    const int*   ids   = (const int*)d_in[0];
    const int*   lgs   = (const int*)d_in[1];
    const float* amask = (const float*)d_in[2];
    const float* wemb  = (const float*)d_in[3];
    const float* pemb  = (const float*)d_in[4];
    const float* lemb  = (const float*)d_in[5];
    const float* lng   = (const float*)d_in[6];
    const float* lnbv  = (const float*)d_in[7];
    const float* Wq = (const float*)d_in[8];  const float* bq = (const float*)d_in[9];
    const float* Wk = (const float*)d_in[10]; const float* bk = (const float*)d_in[11];
    const float* Wv = (const float*)d_in[12]; const float* bv = (const float*)d_in[13];
    const float* Wo = (const float*)d_in[14]; const float* bo = (const float*)d_in[15];
    const float* g1 = (const float*)d_in[16]; const float* be1 = (const float*)d_in[17];
    const float* W1 = (const float*)d_in[18]; const float* b1 = (const float*)d_in[19];
    const float* W2 = (const float*)d_in[20]; const float* b2 = (const float*)d_in[21];
    const float* g2 = (const float*)d_in[22]; const float* be2 = (const float*)d_in[23];

    char* p = (char*)d_ws;
    auto take = [&](size_t n) { char* r = p; p += (n + 255) & ~(size_t)255; return r; };
    float*  xf    = (float*) take((size_t)ROWS * D_ * 4);
    __bf16* xb    = (__bf16*)take((size_t)ROWS * D_ * 2);
    __bf16* qb    = (__bf16*)take((size_t)ROWS * D_ * 2);
    __bf16* kb    = (__bf16*)take((size_t)ROWS * D_ * 2);
    __bf16* vT    = (__bf16*)take((size_t)ROWS * D_ * 2);   // [B][H][64][512]
    __bf16* cxb   = (__bf16*)take((size_t)ROWS * D_ * 2);
    __bf16* hb    = (__bf16*)take((size_t)ROWS * FF_ * 2);
    __bf16* ybp   = (__bf16*)take((size_t)4 * ROWS * D_ * 2);  // bf16 partials
    __bf16* wqkvT = (__bf16*)take((size_t)3 * D_ * D_ * 2);
    __bf16* woT   = (__bf16*)take((size_t)D_ * D_ * 2);
    __bf16* w1T   = (__bf16*)take((size_t)D_ * FF_ * 2);
    __bf16* w2T   = (__bf16*)take((size_t)FF_ * D_ * 2);

    const int gQKV = (ROWS / 256) * (3 * D_ / 256);   // 192
    const int gF1  = (ROWS / 256) * (FF_ / 256);      // 256
    const int gF2  = 4 * (ROWS / 256) * (D_ / 256);   // 256 (split-K=4)
    const int gWo  = (ROWS / 128) * (D_ / 128);       // 256

    embed_ln_kernel<<<ROWS, 256, 0, stream>>>(ids, lgs, amask, wemb, pemb, lemb, lng, lnbv, xf, xb);

    for (int l = 0; l < 12; ++l) {
        const size_t woff = (size_t)l * D_ * D_;
        const size_t foff = (size_t)l * D_ * FF_;
        conv_all_kernel<<<3072, 256, 0, stream>>>(Wq + woff, Wk + woff, Wv + woff, Wo + woff,
                                                  W1 + foff, W2 + foff,
                                                  wqkvT, woT, w1T, w2T);

        gemm256_kernel<0><<<gQKV, 512, 0, stream>>>(xb, wqkvT, bq + l * D_, bk + l * D_, bv + l * D_,
                                                    qb, kb, vT, nullptr,
                                                    ROWS, 3 * D_, D_, D_, 12, gQKV);

        attn_kernel<<<B_ * H_ * (S_ / 64), 256, 0, stream>>>(qb, kb, vT, amask, cxb);

        gemm_kernel<<<gWo, 256, 0, stream>>>(cxb, woT, bo + l * D_, ybp, ROWS, D_, D_);
        ln_resN_kernel<1><<<ROWS, 256, 0, stream>>>(xf, ybp, g1 + l * D_, be1 + l * D_,
                                                    nullptr, xf, xb);

        gemm256_kernel<2><<<gF1, 512, 0, stream>>>(xb, w1T, b1 + l * FF_, nullptr, nullptr,
                                                   hb, nullptr, nullptr, nullptr,
                                                   ROWS, FF_, D_, D_, 16, gF1);
        gemm256_kernel<3><<<gF2, 512, 0, stream>>>(hb, w2T, b2 + l * D_, nullptr, nullptr,
                                                   nullptr, nullptr, nullptr, ybp,
                                                   ROWS, D_, FF_, D_, 4, 64);

        float* dst = (l == 11) ? (float*)d_out : xf;
        ln_resN_kernel<4><<<ROWS, 256, 0, stream>>>(xf, ybp, g2 + l * D_, be2 + l * D_,
                                                    amask, dst, xb);
    }
}

// Round 7
// 2586.692 us; speedup vs baseline: 1.5734x; 1.0020x over previous
//
#include <hip/hip_runtime.h>
#include <math.h>

typedef float  f32x4  __attribute__((ext_vector_type(4)));
typedef __bf16 bf16x8 __attribute__((ext_vector_type(8)));
typedef __bf16 bf16x4 __attribute__((ext_vector_type(4)));

#define DEV __device__ __forceinline__

DEV f32x4 mfma16(bf16x8 a, bf16x8 b, f32x4 c) {
    return __builtin_amdgcn_mfma_f32_16x16x32_bf16(a, b, c, 0, 0, 0);
}

DEV void async16(const void* g, void* l) {
    __builtin_amdgcn_global_load_lds((const __attribute__((address_space(1))) void*)g,
                                     (__attribute__((address_space(3))) void*)l, 16, 0, 0);
}

// ---------------------------------------------------------------- constants
constexpr int B_  = 8;
constexpr int S_  = 512;
constexpr int D_  = 1024;
constexpr int H_  = 16;
constexpr int FF_ = 4096;
constexpr int ROWS = B_ * S_;   // 4096

// ---------------------------------------------------------------- embed + LN -> bf16
__global__ __launch_bounds__(256)
void embed_ln_kernel(const int* __restrict__ ids, const int* __restrict__ lgs,
                     const float* __restrict__ fmask,
                     const float* __restrict__ wemb, const float* __restrict__ pemb,
                     const float* __restrict__ lemb,
                     const float* __restrict__ g, const float* __restrict__ bb,
                     __bf16* __restrict__ xb)
{
    __shared__ float2 red[4];
    const int row = blockIdx.x;
    const int s   = row & (S_ - 1);
    const int t   = threadIdx.x;
    const int lane = t & 63, w = t >> 6;
    const int id = ids[row], lg = lgs[row];

    float4 wv = *(const float4*)(wemb + ((size_t)id << 10) + t * 4);
    float4 pv = *(const float4*)(pemb + ((size_t)s  << 10) + t * 4);
    float4 lv = *(const float4*)(lemb + ((size_t)lg << 10) + t * 4);
    float a[4] = { wv.x + pv.x + lv.x, wv.y + pv.y + lv.y,
                   wv.z + pv.z + lv.z, wv.w + pv.w + lv.w };

    float sm = a[0] + a[1] + a[2] + a[3];
    float sq = a[0]*a[0] + a[1]*a[1] + a[2]*a[2] + a[3]*a[3];
#pragma unroll
    for (int o = 32; o > 0; o >>= 1) { sm += __shfl_down(sm, o); sq += __shfl_down(sq, o); }
    if (lane == 0) red[w] = make_float2(sm, sq);
    __syncthreads();
    float ts = red[0].x + red[1].x + red[2].x + red[3].x;
    float tq = red[0].y + red[1].y + red[2].y + red[3].y;
    float mean = ts * (1.0f / D_);
    float var  = tq * (1.0f / D_) - mean * mean;
    float rs   = rsqrtf(var + 1e-12f);
    float fm   = fmask[row];

    float4 gv = *(const float4*)(g  + t * 4);
    float4 bv = *(const float4*)(bb + t * 4);
    bf16x4 ob;
    ob[0] = (__bf16)(((a[0]-mean)*rs*gv.x + bv.x) * fm);
    ob[1] = (__bf16)(((a[1]-mean)*rs*gv.y + bv.y) * fm);
    ob[2] = (__bf16)(((a[2]-mean)*rs*gv.z + bv.z) * fm);
    ob[3] = (__bf16)(((a[3]-mean)*rs*gv.w + bv.w) * fm);
    *(bf16x4*)(xb + ((size_t)row << 10) + t * 4) = ob;
}

// ---------------- bf16 residual + NP bf16 partials + LN (+mask) -> bf16 (+fp32 out)
template<int NP>
__global__ __launch_bounds__(256)
void ln_resN_kernel(const __bf16* __restrict__ xres, const __bf16* __restrict__ yp,
                    const float* __restrict__ g, const float* __restrict__ bb,
                    const float* __restrict__ fmask,
                    __bf16* __restrict__ xb_out, float* __restrict__ fout)
{
    constexpr size_t MN = (size_t)ROWS * D_;
    __shared__ float2 red[4];
    const int row = blockIdx.x;
    const int t   = threadIdx.x;
    const int lane = t & 63, w = t >> 6;
    const size_t base = ((size_t)row << 10) + t * 4;

    bf16x4 xv = *(const bf16x4*)(xres + base);
    float a[4] = { (float)xv[0], (float)xv[1], (float)xv[2], (float)xv[3] };
#pragma unroll
    for (int pslice = 0; pslice < NP; ++pslice) {
        bf16x4 yv = *(const bf16x4*)(yp + base + (size_t)pslice * MN);
#pragma unroll
        for (int j = 0; j < 4; ++j) a[j] += (float)yv[j];
    }

    float sm = a[0] + a[1] + a[2] + a[3];
    float sq = a[0]*a[0] + a[1]*a[1] + a[2]*a[2] + a[3]*a[3];
#pragma unroll
    for (int o = 32; o > 0; o >>= 1) { sm += __shfl_down(sm, o); sq += __shfl_down(sq, o); }
    if (lane == 0) red[w] = make_float2(sm, sq);
    __syncthreads();
    float ts = red[0].x + red[1].x + red[2].x + red[3].x;
    float tq = red[0].y + red[1].y + red[2].y + red[3].y;
    float mean = ts * (1.0f / D_);
    float var  = tq * (1.0f / D_) - mean * mean;
    float rs   = rsqrtf(var + 1e-12f);
    float fm   = fmask ? fmask[row] : 1.0f;

    float4 gv = *(const float4*)(g  + t * 4);
    float4 bv = *(const float4*)(bb + t * 4);
    float o0 = ((a[0]-mean)*rs*gv.x + bv.x) * fm;
    float o1 = ((a[1]-mean)*rs*gv.y + bv.y) * fm;
    float o2 = ((a[2]-mean)*rs*gv.z + bv.z) * fm;
    float o3 = ((a[3]-mean)*rs*gv.w + bv.w) * fm;
    bf16x4 ob; ob[0] = (__bf16)o0; ob[1] = (__bf16)o1; ob[2] = (__bf16)o2; ob[3] = (__bf16)o3;
    *(bf16x4*)(xb_out + base) = ob;
    if (fout) *(float4*)(fout + base) = make_float4(o0, o1, o2, o3);
}

// ----------- upfront ALL-LAYER weight convert fp32[K][N] -> bf16[N][K] (1 dispatch)
// grid 12*3072; per layer: [0,1024) Wq/Wk/Wv/Wo, [1024,2048) W1, [2048,3072) W2
__global__ __launch_bounds__(256)
void conv_all_kernel(const float* __restrict__ Wq, const float* __restrict__ Wk,
                     const float* __restrict__ Wv, const float* __restrict__ Wo,
                     const float* __restrict__ W1, const float* __restrict__ W2,
                     __bf16* __restrict__ qkvT, __bf16* __restrict__ woT,
                     __bf16* __restrict__ w1T, __bf16* __restrict__ w2T)
{
    __shared__ __bf16 tile[64][66];
    const int id = blockIdx.x;
    const int l  = id / 3072;
    int t = id - l * 3072;
    const size_t woff = (size_t)l * D_ * D_;
    const size_t foff = (size_t)l * D_ * FF_;
    const float* src; __bf16* dst; int K, N;
    if (t < 1024) {
        const int m = t >> 8; t &= 255; K = 1024; N = 1024;
        src = ((m == 0) ? Wq : (m == 1) ? Wk : (m == 2) ? Wv : Wo) + woff;
        dst = (m == 3) ? (woT + woff)
                       : (qkvT + (size_t)l * 3 * D_ * D_ + (size_t)m * D_ * D_);
    } else if (t < 2048) {
        t -= 1024; K = 1024; N = 4096; src = W1 + foff; dst = w1T + foff;
    } else {
        t -= 2048; K = 4096; N = 1024; src = W2 + foff; dst = w2T + foff;
    }
    const int ktiles = K >> 6;
    const int tk = t % ktiles, tn = t / ktiles;
    const int k0 = tk << 6, n0 = tn << 6;
    const int tt = threadIdx.x;
#pragma unroll
    for (int i = 0; i < 16; ++i) {
        int idx = i * 256 + tt;
        int r = idx >> 6, c = idx & 63;
        tile[c][r] = (__bf16)src[(size_t)(k0 + r) * N + n0 + c];
    }
    __syncthreads();
#pragma unroll
    for (int i = 0; i < 16; ++i) {
        int idx = i * 256 + tt;
        int r = idx >> 6, c = idx & 63;
        dst[(size_t)(n0 + r) * K + k0 + c] = tile[r][c];
    }
}

// ================================================================ 256x256 8-phase GEMM
// EPI 0: QKV (q*0.125 bf16 row-major; k bf16 row-major; V -> TRANSPOSED vT[b][h][64][512])
// EPI 2: GELU->bf16.  EPI 3: split-K bf16 partials at oP + slice*M*N.
template<int EPI>
__global__ __launch_bounds__(512, 2)
void gemm256_kernel(const __bf16* __restrict__ A, const __bf16* __restrict__ Bt,
                    const float* __restrict__ b0, const float* __restrict__ b1,
                    const float* __restrict__ b2,
                    __bf16* __restrict__ o0, __bf16* __restrict__ o1,
                    __bf16* __restrict__ o2, __bf16* __restrict__ oP,
                    int M, int N, int K, int Kloc, int nTn, int tiles)
{
    __shared__ __bf16 lds[65536];
    const int tid  = threadIdx.x;
    const int lane = tid & 63;
    const int w    = tid >> 6;
    const int wr   = w >> 2, wc = w & 3;

    const int nwg = gridDim.x, bid = blockIdx.x;
    const int cpx = nwg >> 3;
    const int bswz = (bid & 7) * cpx + (bid >> 3);
    const int slice = bswz / tiles;
    const int tile  = bswz % tiles;
    const int bm = tile / nTn, bn = tile % nTn;
    const int m0 = bm << 8, n0 = bn << 8;
    const int ks = slice * Kloc;

    const int rrT = tid >> 3;
    const size_t swzK  = (size_t)(((tid & 7) ^ (rrT & 7)) * 8);
    const size_t aoff0 = (size_t)rrT * K + swzK;
    const size_t boff0 = (size_t)((rrT >> 5) * 64 + (rrT & 31)) * K + swzK;
    const size_t boff1 = (size_t)(((rrT >> 5) + 2) * 64 + (rrT & 31)) * K + swzK;
    const int wub = w * 512;

    const int aread = (wr * 64 + (lane & 15)) * 64;
    const int bread = (wc * 32 + (lane & 15)) * 64;
    const int csw0 = ((      (lane >> 4) * 16) ^ ((lane & 7) << 4)) >> 1;
    const int csw1 = ((64 +  (lane >> 4) * 16) ^ ((lane & 7) << 4)) >> 1;

    f32x4 acc[8][4] = {};
    bf16x8 a_[4][2], b_[2][2];

#define ST_A(p,h,kt) do {                                                     \
    const size_t gb = (size_t)(m0 + (h) * 64) * K + (kt);                     \
    async16(A + gb + aoff0,                  lds + ((p)*2+(h))*8192 + wub);   \
    async16(A + gb + (size_t)128*K + aoff0,  lds + ((p)*2+(h))*8192 + 4096 + wub); \
} while (0)
#define ST_B(p,h,kt) do {                                                     \
    const size_t gb = (size_t)(n0 + (h) * 32) * K + (kt);                     \
    async16(Bt + gb + boff0, lds + 32768 + ((p)*2+(h))*8192 + wub);           \
    async16(Bt + gb + boff1, lds + 32768 + ((p)*2+(h))*8192 + 4096 + wub);    \
} while (0)
#define DS_A(p,h) do {                                                        \
    const __bf16* base_ = lds + ((p)*2+(h))*8192 + aread;                     \
    _Pragma("unroll") for (int m_ = 0; m_ < 4; ++m_) {                        \
        a_[m_][0] = *(const bf16x8*)(base_ + m_*1024 + csw0);                 \
        a_[m_][1] = *(const bf16x8*)(base_ + m_*1024 + csw1);                 \
    }                                                                         \
} while (0)
#define DS_B(p,h) do {                                                        \
    const __bf16* base_ = lds + 32768 + ((p)*2+(h))*8192 + bread;             \
    _Pragma("unroll") for (int n_ = 0; n_ < 2; ++n_) {                        \
        b_[n_][0] = *(const bf16x8*)(base_ + n_*1024 + csw0);                 \
        b_[n_][1] = *(const bf16x8*)(base_ + n_*1024 + csw1);                 \
    }                                                                         \
} while (0)
#define MM(mb,nb) do {                                                        \
    _Pragma("unroll") for (int m_ = 0; m_ < 4; ++m_)                          \
    _Pragma("unroll") for (int n_ = 0; n_ < 2; ++n_)                          \
    _Pragma("unroll") for (int k_ = 0; k_ < 2; ++k_)                          \
        acc[(mb)+m_][(nb)+n_] = mfma16(a_[m_][k_], b_[n_][k_], acc[(mb)+m_][(nb)+n_]); \
} while (0)
#define SYNC do { __builtin_amdgcn_s_barrier();                               \
    asm volatile("s_waitcnt lgkmcnt(0)" ::: "memory");                        \
    __builtin_amdgcn_s_setprio(1); } while (0)
#define PEND do { __builtin_amdgcn_s_setprio(0);                              \
    __builtin_amdgcn_s_barrier(); } while (0)

    ST_A(0,0, ks);      ST_B(0,1, ks);      ST_A(0,1, ks);      ST_B(0,0, ks);
    ST_A(1,0, ks + 64); ST_B(1,1, ks + 64); ST_A(1,1, ks + 64);
    asm volatile("s_waitcnt vmcnt(6)" ::: "memory");
    __builtin_amdgcn_s_barrier();

    const int nIter = Kloc >> 7;
    for (int i = 0; i < nIter; ++i) {
        const bool nl = (i != nIter - 1);
        const int kt1 = ks + (2*i+1) * 64;
        const int kt2 = ks + (2*i+2) * 64;
        const int kt3 = kt2 + 64;
        DS_A(0,0); DS_B(0,0); ST_B(1,0,kt1);
        SYNC; MM(0,0); PEND;
        DS_B(0,1); if (nl) ST_A(0,0,kt2);
        SYNC; MM(0,2); PEND;
        DS_A(0,1); if (nl) ST_B(0,1,kt2);
        SYNC; MM(4,2); PEND;
        DS_B(0,0); if (nl) ST_A(0,1,kt2);
        SYNC; MM(4,0);
        __builtin_amdgcn_s_setprio(0);
        if (nl) asm volatile("s_waitcnt vmcnt(6)" ::: "memory");
        else    asm volatile("s_waitcnt vmcnt(0)" ::: "memory");
        __builtin_amdgcn_s_barrier();
        DS_A(1,0); DS_B(1,0); if (nl) ST_B(0,0,kt2);
        SYNC; MM(0,0); PEND;
        DS_B(1,1); if (nl) ST_A(1,0,kt3);
        SYNC; MM(0,2); PEND;
        DS_A(1,1); if (nl) ST_B(1,1,kt3);
        SYNC; MM(4,2); PEND;
        DS_B(1,0); if (nl) ST_A(1,1,kt3);
        SYNC; MM(4,0);
        __builtin_amdgcn_s_setprio(0);
        if (nl) asm volatile("s_waitcnt vmcnt(6)" ::: "memory");
        __builtin_amdgcn_s_barrier();
    }
#undef ST_A
#undef ST_B
#undef DS_A
#undef DS_B
#undef MM
#undef SYNC
#undef PEND

    const int mrow = m0 + wr * 128 + (lane >> 4) * 4;
    const int ncol = n0 + wc * 64 + (lane & 15);
    if (EPI == 0) {
        const int sel = n0 >> 10;
        const int nc = ncol & 1023;
        if (sel < 2) {
            __bf16* out = (sel == 0) ? o0 : o1;
            const float* bp = (sel == 0) ? b0 : b1;
            const float scl = (sel == 0) ? 0.125f : 1.0f;
#pragma unroll
            for (int ni = 0; ni < 4; ++ni) {
                const float bvv = bp[nc + ni * 16];
#pragma unroll
                for (int mi = 0; mi < 8; ++mi)
#pragma unroll
                    for (int r = 0; r < 4; ++r)
                        out[(size_t)(mrow + mi * 16 + r) * D_ + nc + ni * 16] =
                            (__bf16)((acc[mi][ni][r] + bvv) * scl);
            }
        } else {
            // V -> vT[((b*16+h)*64 + dh)][s], packed 4 consecutive s per store
#pragma unroll
            for (int ni = 0; ni < 4; ++ni) {
                const int dhf = nc + ni * 16;
                const float bvv = b2[dhf];
                const int hh = dhf >> 6, dh = dhf & 63;
#pragma unroll
                for (int mi = 0; mi < 8; ++mi) {
                    const int gm0 = mrow + mi * 16;
                    const int bb_ = gm0 >> 9, s0 = gm0 & 511;
                    bf16x4 pk;
#pragma unroll
                    for (int r = 0; r < 4; ++r) pk[r] = (__bf16)(acc[mi][ni][r] + bvv);
                    *(bf16x4*)(o2 + ((size_t)((bb_ * 16 + hh) * 64 + dh) << 9) + s0) = pk;
                }
            }
        }
    } else if (EPI == 2) {
#pragma unroll
        for (int ni = 0; ni < 4; ++ni) {
            const float bvv = b0[ncol + ni * 16];
#pragma unroll
            for (int mi = 0; mi < 8; ++mi)
#pragma unroll
                for (int r = 0; r < 4; ++r) {
                    float v = acc[mi][ni][r] + bvv;
                    float ge = 0.5f * v * (1.0f + erff(v * 0.70710678118654752f));
                    o0[(size_t)(mrow + mi * 16 + r) * N + ncol + ni * 16] = (__bf16)ge;
                }
        }
    } else {
        __bf16* Y = oP + (size_t)slice * M * N;
#pragma unroll
        for (int ni = 0; ni < 4; ++ni) {
            const float bvv = (slice == 0) ? b0[ncol + ni * 16] : 0.0f;
#pragma unroll
            for (int mi = 0; mi < 8; ++mi)
#pragma unroll
                for (int r = 0; r < 4; ++r)
                    Y[(size_t)(mrow + mi * 16 + r) * N + ncol + ni * 16] =
                        (__bf16)(acc[mi][ni][r] + bvv);
        }
    }
}

// ---------------------------------------------------------------- attention v2
// (unchanged from round 6 — verified)
__global__ __launch_bounds__(256, 2)
void attn_kernel(const __bf16* __restrict__ q, const __bf16* __restrict__ k,
                 const __bf16* __restrict__ vT, const float* __restrict__ fmask,
                 __bf16* __restrict__ ctx)
{
    __shared__ __bf16 Ks[256 * 64];
    __shared__ __bf16 Vt[64 * 256];
    __shared__ float  negm[S_];
    const int bid = blockIdx.x;
    const int qt = bid & 7, h = (bid >> 3) & 15, b = bid >> 7;
    const int tid = threadIdx.x, lane = tid & 63, w = tid >> 6;
    const int g = lane >> 4, q15 = lane & 15, r7 = lane & 7;

    const __bf16* kbase  = k  + ((size_t)b * S_) * D_ + h * 64;
    const __bf16* vTbase = vT + ((size_t)((b * 16 + h) * 64) << 9);
    char* kl = (char*)Ks + (tid & ~63) * 16;
    char* vl = (char*)Vt + (tid & ~63) * 16;
    const int srow  = tid >> 3;
    const int sslot = (tid & 7) ^ (srow & 7);
    const int vrow  = tid >> 5;
#define ST_K(c) do { _Pragma("unroll") for (int i_ = 0; i_ < 8; ++i_) {       \
        const int s_ = (c) * 256 + i_ * 32 + srow;                            \
        async16(kbase + (size_t)s_ * D_ + sslot * 8, kl + i_ * 4096); } } while (0)
#define ST_V(c) do { _Pragma("unroll") for (int i_ = 0; i_ < 8; ++i_) {       \
        const int d_ = i_ * 8 + vrow;                                         \
        async16(vTbase + ((size_t)d_ << 9) + (c) * 256 +                      \
                (((tid & 31) ^ (d_ & 7)) << 3), vl + i_ * 4096); } } while (0)

    ST_K(0);
    for (int i = tid; i < S_; i += 256) negm[i] = (fmask[b * S_ + i] - 1.0f) * 1e30f;

    const __bf16* qbase = q + ((size_t)b * S_ + qt * 64 + w * 16) * D_ + h * 64;
    const bf16x8 qf0 = *(const bf16x8*)(qbase + (size_t)q15 * D_ + g * 8);
    const bf16x8 qf1 = *(const bf16x8*)(qbase + (size_t)q15 * D_ + 32 + g * 8);

    f32x4 sc[32];
#pragma unroll
    for (int i = 0; i < 32; ++i) { sc[i][0] = 0.f; sc[i][1] = 0.f; sc[i][2] = 0.f; sc[i][3] = 0.f; }

#define QKT(c) do { _Pragma("unroll") for (int nf = 0; nf < 16; ++nf) {       \
        const __bf16* kr = Ks + (nf * 16 + q15) * 64;                         \
        const bf16x8 kf0 = *(const bf16x8*)(kr + ((g ^ r7) << 3));            \
        const bf16x8 kf1 = *(const bf16x8*)(kr + (((g + 4) ^ r7) << 3));      \
        sc[(c)*16+nf] = mfma16(kf0, qf0, sc[(c)*16+nf]);                      \
        sc[(c)*16+nf] = mfma16(kf1, qf1, sc[(c)*16+nf]); } } while (0)

    __syncthreads();
    ST_V(0);
    QKT(0);
    __syncthreads();
    ST_K(1);
    __syncthreads();
    QKT(1);

    float mx = -3e38f;
#pragma unroll
    for (int i = 0; i < 32; ++i) {
        const float4 nm4 = *(const float4*)(negm + ((i >> 4) * 256 + (i & 15) * 16 + 4 * g));
        sc[i][0] += nm4.x; sc[i][1] += nm4.y; sc[i][2] += nm4.z; sc[i][3] += nm4.w;
        mx = fmaxf(mx, fmaxf(fmaxf(sc[i][0], sc[i][1]), fmaxf(sc[i][2], sc[i][3])));
    }
    mx = fmaxf(mx, __shfl_xor(mx, 16));
    mx = fmaxf(mx, __shfl_xor(mx, 32));
    float sum = 0.f;
#pragma unroll
    for (int i = 0; i < 32; ++i)
#pragma unroll
        for (int r = 0; r < 4; ++r) { float pp = __expf(sc[i][r] - mx); sc[i][r] = pp; sum += pp; }
    sum += __shfl_xor(sum, 16);
    sum += __shfl_xor(sum, 32);
    const float inv = 1.0f / sum;

    __bf16* P = Ks + w * 4096;
    f32x4 co[4] = {};
#define WR_P(c) do { _Pragma("unroll") for (int i_ = 0; i_ < 16; ++i_) {      \
        bf16x4 pk;                                                            \
        _Pragma("unroll") for (int r = 0; r < 4; ++r) pk[r] = (__bf16)sc[(c)*16+i_][r]; \
        *(bf16x4*)(P + q15 * 256 + ((i_ * 16 + 4 * g) ^ (8 * r7))) = pk; } } while (0)
#define PV() do { _Pragma("unroll") for (int kt = 0; kt < 8; ++kt) {          \
        const bf16x8 pf = *(const bf16x8*)(P + q15 * 256 + ((kt * 32 + 8 * g) ^ (8 * r7))); \
        _Pragma("unroll") for (int nf = 0; nf < 4; ++nf) {                    \
            const int d_ = nf * 16 + q15;                                     \
            const bf16x8 vf = *(const bf16x8*)(Vt + d_ * 256 + ((kt * 32 + 8 * g) ^ (8 * r7))); \
            co[nf] = mfma16(vf, pf, co[nf]); } } } while (0)

    __syncthreads();
    WR_P(0);
    __syncthreads();
    PV();
    __syncthreads();
    WR_P(1);
    ST_V(1);
    __syncthreads();
    PV();
#undef ST_K
#undef ST_V
#undef QKT
#undef WR_P
#undef PV

    __bf16* cb = ctx + ((size_t)b * S_ + qt * 64 + w * 16 + q15) * D_ + h * 64;
#pragma unroll
    for (int nf = 0; nf < 4; ++nf) {
        bf16x4 o4;
#pragma unroll
        for (int r = 0; r < 4; ++r) o4[r] = (__bf16)(co[nf][r] * inv);
        *(bf16x4*)(cb + nf * 16 + 4 * g) = o4;
    }
}

// ---------------------------------------------------------------- launcher
extern "C" void kernel_launch(void* const* d_in, const int* in_sizes, int n_in,
                              void* d_out, int out_size, void* d_ws, size_t ws_size,
                              hipStream_t stream)
{
    (void)in_sizes; (void)n_in; (void)out_size; (void)ws_size;
    const int*   ids   = (const int*)d_in[0];
    const int*   lgs   = (const int*)d_in[1];
    const float* amask = (const float*)d_in[2];
    const float* wemb  = (const float*)d_in[3];
    const float* pemb  = (const float*)d_in[4];
    const float* lemb  = (const float*)d_in[5];
    const float* lng   = (const float*)d_in[6];
    const float* lnbv  = (const float*)d_in[7];
    const float* Wq = (const float*)d_in[8];  const float* bq = (const float*)d_in[9];
    const float* Wk = (const float*)d_in[10]; const float* bk = (const float*)d_in[11];
    const float* Wv = (const float*)d_in[12]; const float* bv = (const float*)d_in[13];
    const float* Wo = (const float*)d_in[14]; const float* bo = (const float*)d_in[15];
    const float* g1 = (const float*)d_in[16]; const float* be1 = (const float*)d_in[17];
    const float* W1 = (const float*)d_in[18]; const float* b1 = (const float*)d_in[19];
    const float* W2 = (const float*)d_in[20]; const float* b2 = (const float*)d_in[21];
    const float* g2 = (const float*)d_in[22]; const float* be2 = (const float*)d_in[23];

    char* p = (char*)d_ws;
    auto take = [&](size_t n) { char* r = p; p += (n + 255) & ~(size_t)255; return r; };
    __bf16* xb    = (__bf16*)take((size_t)ROWS * D_ * 2);
    __bf16* qb    = (__bf16*)take((size_t)ROWS * D_ * 2);
    __bf16* kb    = (__bf16*)take((size_t)ROWS * D_ * 2);
    __bf16* vT    = (__bf16*)take((size_t)ROWS * D_ * 2);   // [B][H][64][512]
    __bf16* cxb   = (__bf16*)take((size_t)ROWS * D_ * 2);
    __bf16* hb    = (__bf16*)take((size_t)ROWS * FF_ * 2);
    __bf16* ybp   = (__bf16*)take((size_t)4 * ROWS * D_ * 2);  // bf16 partials (4 slices)
    __bf16* wqkvT = (__bf16*)take((size_t)12 * 3 * D_ * D_ * 2);  // 72 MB
    __bf16* woT   = (__bf16*)take((size_t)12 * D_ * D_ * 2);      // 24 MB
    __bf16* w1T   = (__bf16*)take((size_t)12 * D_ * FF_ * 2);     // 96 MB
    __bf16* w2T   = (__bf16*)take((size_t)12 * FF_ * D_ * 2);     // 96 MB

    const int gQKV = (ROWS / 256) * (3 * D_ / 256);   // 192
    const int gF1  = (ROWS / 256) * (FF_ / 256);      // 256
    const int gF2  = 4 * (ROWS / 256) * (D_ / 256);   // 256 (split-K=4, Kloc=1024)
    const int gWo  = 4 * (ROWS / 256) * (D_ / 256);   // 256 (split-K=4, Kloc=256)

    // all-layer weight conversion, one dispatch
    conv_all_kernel<<<12 * 3072, 256, 0, stream>>>(Wq, Wk, Wv, Wo, W1, W2,
                                                   wqkvT, woT, w1T, w2T);

    embed_ln_kernel<<<ROWS, 256, 0, stream>>>(ids, lgs, amask, wemb, pemb, lemb, lng, lnbv, xb);

    for (int l = 0; l < 12; ++l) {
        __bf16* wqkvL = wqkvT + (size_t)l * 3 * D_ * D_;
        __bf16* woL   = woT   + (size_t)l * D_ * D_;
        __bf16* w1L   = w1T   + (size_t)l * D_ * FF_;
        __bf16* w2L   = w2T   + (size_t)l * FF_ * D_;

        gemm256_kernel<0><<<gQKV, 512, 0, stream>>>(xb, wqkvL, bq + l * D_, bk + l * D_, bv + l * D_,
                                                    qb, kb, vT, nullptr,
                                                    ROWS, 3 * D_, D_, D_, 12, gQKV);

        attn_kernel<<<B_ * H_ * (S_ / 64), 256, 0, stream>>>(qb, kb, vT, amask, cxb);

        gemm256_kernel<3><<<gWo, 512, 0, stream>>>(cxb, woL, bo + l * D_, nullptr, nullptr,
                                                   nullptr, nullptr, nullptr, ybp,
                                                   ROWS, D_, D_, D_ / 4, 4, 64);
        ln_resN_kernel<4><<<ROWS, 256, 0, stream>>>(xb, ybp, g1 + l * D_, be1 + l * D_,
                                                    nullptr, xb, nullptr);

        gemm256_kernel<2><<<gF1, 512, 0, stream>>>(xb, w1L, b1 + l * FF_, nullptr, nullptr,
                                                   hb, nullptr, nullptr, nullptr,
                                                   ROWS, FF_, D_, D_, 16, gF1);
        gemm256_kernel<3><<<gF2, 512, 0, stream>>>(hb, w2L, b2 + l * D_, nullptr, nullptr,
                                                   nullptr, nullptr, nullptr, ybp,
                                                   ROWS, D_, FF_, D_, 4, 64);

        float* dst = (l == 11) ? (float*)d_out : nullptr;
        ln_resN_kernel<4><<<ROWS, 256, 0, stream>>>(xb, ybp, g2 + l * D_, be2 + l * D_,
                                                    amask, xb, dst);
    }
}

// Round 8
// 2578.076 us; speedup vs baseline: 1.5786x; 1.0033x over previous
//
#include <hip/hip_runtime.h>
#include <math.h>

typedef float  f32x4  __attribute__((ext_vector_type(4)));
typedef __bf16 bf16x8 __attribute__((ext_vector_type(8)));
typedef __bf16 bf16x4 __attribute__((ext_vector_type(4)));

#define DEV __device__ __forceinline__

DEV f32x4 mfma16(bf16x8 a, bf16x8 b, f32x4 c) {
    return __builtin_amdgcn_mfma_f32_16x16x32_bf16(a, b, c, 0, 0, 0);
}

DEV void async16(const void* g, void* l) {
    __builtin_amdgcn_global_load_lds((const __attribute__((address_space(1))) void*)g,
                                     (__attribute__((address_space(3))) void*)l, 16, 0, 0);
}

// ---------------------------------------------------------------- constants
constexpr int B_  = 8;
constexpr int S_  = 512;
constexpr int D_  = 1024;
constexpr int H_  = 16;
constexpr int FF_ = 4096;
constexpr int ROWS = B_ * S_;   // 4096

// ---------------------------------------------------------------- embed + LN -> bf16
__global__ __launch_bounds__(256)
void embed_ln_kernel(const int* __restrict__ ids, const int* __restrict__ lgs,
                     const float* __restrict__ fmask,
                     const float* __restrict__ wemb, const float* __restrict__ pemb,
                     const float* __restrict__ lemb,
                     const float* __restrict__ g, const float* __restrict__ bb,
                     __bf16* __restrict__ xb)
{
    __shared__ float2 red[4];
    const int row = blockIdx.x;
    const int s   = row & (S_ - 1);
    const int t   = threadIdx.x;
    const int lane = t & 63, w = t >> 6;
    const int id = ids[row], lg = lgs[row];

    float4 wv = *(const float4*)(wemb + ((size_t)id << 10) + t * 4);
    float4 pv = *(const float4*)(pemb + ((size_t)s  << 10) + t * 4);
    float4 lv = *(const float4*)(lemb + ((size_t)lg << 10) + t * 4);
    float a[4] = { wv.x + pv.x + lv.x, wv.y + pv.y + lv.y,
                   wv.z + pv.z + lv.z, wv.w + pv.w + lv.w };

    float sm = a[0] + a[1] + a[2] + a[3];
    float sq = a[0]*a[0] + a[1]*a[1] + a[2]*a[2] + a[3]*a[3];
#pragma unroll
    for (int o = 32; o > 0; o >>= 1) { sm += __shfl_down(sm, o); sq += __shfl_down(sq, o); }
    if (lane == 0) red[w] = make_float2(sm, sq);
    __syncthreads();
    float ts = red[0].x + red[1].x + red[2].x + red[3].x;
    float tq = red[0].y + red[1].y + red[2].y + red[3].y;
    float mean = ts * (1.0f / D_);
    float var  = tq * (1.0f / D_) - mean * mean;
    float rs   = rsqrtf(var + 1e-12f);
    float fm   = fmask[row];

    float4 gv = *(const float4*)(g  + t * 4);
    float4 bv = *(const float4*)(bb + t * 4);
    bf16x4 ob;
    ob[0] = (__bf16)(((a[0]-mean)*rs*gv.x + bv.x) * fm);
    ob[1] = (__bf16)(((a[1]-mean)*rs*gv.y + bv.y) * fm);
    ob[2] = (__bf16)(((a[2]-mean)*rs*gv.z + bv.z) * fm);
    ob[3] = (__bf16)(((a[3]-mean)*rs*gv.w + bv.w) * fm);
    *(bf16x4*)(xb + ((size_t)row << 10) + t * 4) = ob;
}

// ---------------- bf16 residual + NP bf16 partials + LN (+mask) -> bf16 (+fp32 out)
template<int NP>
__global__ __launch_bounds__(256)
void ln_resN_kernel(const __bf16* __restrict__ xres, const __bf16* __restrict__ yp,
                    const float* __restrict__ g, const float* __restrict__ bb,
                    const float* __restrict__ fmask,
                    __bf16* __restrict__ xb_out, float* __restrict__ fout)
{
    constexpr size_t MN = (size_t)ROWS * D_;
    __shared__ float2 red[4];
    const int row = blockIdx.x;
    const int t   = threadIdx.x;
    const int lane = t & 63, w = t >> 6;
    const size_t base = ((size_t)row << 10) + t * 4;

    bf16x4 xv = *(const bf16x4*)(xres + base);
    float a[4] = { (float)xv[0], (float)xv[1], (float)xv[2], (float)xv[3] };
#pragma unroll
    for (int pslice = 0; pslice < NP; ++pslice) {
        bf16x4 yv = *(const bf16x4*)(yp + base + (size_t)pslice * MN);
#pragma unroll
        for (int j = 0; j < 4; ++j) a[j] += (float)yv[j];
    }

    float sm = a[0] + a[1] + a[2] + a[3];
    float sq = a[0]*a[0] + a[1]*a[1] + a[2]*a[2] + a[3]*a[3];
#pragma unroll
    for (int o = 32; o > 0; o >>= 1) { sm += __shfl_down(sm, o); sq += __shfl_down(sq, o); }
    if (lane == 0) red[w] = make_float2(sm, sq);
    __syncthreads();
    float ts = red[0].x + red[1].x + red[2].x + red[3].x;
    float tq = red[0].y + red[1].y + red[2].y + red[3].y;
    float mean = ts * (1.0f / D_);
    float var  = tq * (1.0f / D_) - mean * mean;
    float rs   = rsqrtf(var + 1e-12f);
    float fm   = fmask ? fmask[row] : 1.0f;

    float4 gv = *(const float4*)(g  + t * 4);
    float4 bv = *(const float4*)(bb + t * 4);
    float o0 = ((a[0]-mean)*rs*gv.x + bv.x) * fm;
    float o1 = ((a[1]-mean)*rs*gv.y + bv.y) * fm;
    float o2 = ((a[2]-mean)*rs*gv.z + bv.z) * fm;
    float o3 = ((a[3]-mean)*rs*gv.w + bv.w) * fm;
    bf16x4 ob; ob[0] = (__bf16)o0; ob[1] = (__bf16)o1; ob[2] = (__bf16)o2; ob[3] = (__bf16)o3;
    *(bf16x4*)(xb_out + base) = ob;
    if (fout) *(float4*)(fout + base) = make_float4(o0, o1, o2, o3);
}

// ----------- upfront ALL-LAYER weight convert fp32[K][N] -> bf16[N][K] (1 dispatch)
// VECTORIZED: float4 reads, slot-XOR-swizzled LDS tile, bf16x8 writes.
__global__ __launch_bounds__(256)
void conv_all_kernel(const float* __restrict__ Wq, const float* __restrict__ Wk,
                     const float* __restrict__ Wv, const float* __restrict__ Wo,
                     const float* __restrict__ W1, const float* __restrict__ W2,
                     __bf16* __restrict__ qkvT, __bf16* __restrict__ woT,
                     __bf16* __restrict__ w1T, __bf16* __restrict__ w2T)
{
    __shared__ __bf16 tile[64 * 72];
    const int id = blockIdx.x;
    const int l  = id / 3072;
    int t = id - l * 3072;
    const size_t woff = (size_t)l * D_ * D_;
    const size_t foff = (size_t)l * D_ * FF_;
    const float* src; __bf16* dst; int K, N;
    if (t < 1024) {
        const int m = t >> 8; t &= 255; K = 1024; N = 1024;
        src = ((m == 0) ? Wq : (m == 1) ? Wk : (m == 2) ? Wv : Wo) + woff;
        dst = (m == 3) ? (woT + woff)
                       : (qkvT + (size_t)l * 3 * D_ * D_ + (size_t)m * D_ * D_);
    } else if (t < 2048) {
        t -= 1024; K = 1024; N = 4096; src = W1 + foff; dst = w1T + foff;
    } else {
        t -= 2048; K = 4096; N = 1024; src = W2 + foff; dst = w2T + foff;
    }
    const int ktiles = K >> 6;
    const int tk = t % ktiles, tn = t / ktiles;
    const int k0 = tk << 6, n0 = tn << 6;
    const int tt = threadIdx.x;

    const int kr = tt >> 4;           // 0..15
    const int tc = (tt & 15) * 4;     // n quad base
#pragma unroll
    for (int i = 0; i < 4; ++i) {
        const int k = i * 16 + kr;
        float4 v = *(const float4*)(src + (size_t)(k0 + k) * N + n0 + tc);
        const int sl = k >> 3, kb = k & 7;
        tile[(tc    ) * 72 + ((sl ^ ((tc    ) & 7)) << 3) + kb] = (__bf16)v.x;
        tile[(tc + 1) * 72 + ((sl ^ ((tc + 1) & 7)) << 3) + kb] = (__bf16)v.y;
        tile[(tc + 2) * 72 + ((sl ^ ((tc + 2) & 7)) << 3) + kb] = (__bf16)v.z;
        tile[(tc + 3) * 72 + ((sl ^ ((tc + 3) & 7)) << 3) + kb] = (__bf16)v.w;
    }
    __syncthreads();
    const int nr = tt >> 3;           // 0..31
    const int kc = tt & 7;
#pragma unroll
    for (int pp = 0; pp < 2; ++pp) {
        const int n = pp * 32 + nr;
        bf16x8 vv = *(const bf16x8*)(tile + n * 72 + ((kc ^ (n & 7)) << 3));
        *(bf16x8*)(dst + (size_t)(n0 + n) * K + k0 + kc * 8) = vv;
    }
}

// ================================================================ 256x256 8-phase GEMM
// (unchanged — verified schedule)
// EPI 0: QKV (q*0.125 bf16; k bf16; V -> TRANSPOSED vT[b][h][64][512])
// EPI 2: GELU->bf16.  EPI 3: split-K bf16 partials at oP + slice*M*N.
template<int EPI>
__global__ __launch_bounds__(512, 2)
void gemm256_kernel(const __bf16* __restrict__ A, const __bf16* __restrict__ Bt,
                    const float* __restrict__ b0, const float* __restrict__ b1,
                    const float* __restrict__ b2,
                    __bf16* __restrict__ o0, __bf16* __restrict__ o1,
                    __bf16* __restrict__ o2, __bf16* __restrict__ oP,
                    int M, int N, int K, int Kloc, int nTn, int tiles)
{
    __shared__ __bf16 lds[65536];
    const int tid  = threadIdx.x;
    const int lane = tid & 63;
    const int w    = tid >> 6;
    const int wr   = w >> 2, wc = w & 3;

    const int nwg = gridDim.x, bid = blockIdx.x;
    const int cpx = nwg >> 3;
    const int bswz = (bid & 7) * cpx + (bid >> 3);
    const int slice = bswz / tiles;
    const int tile  = bswz % tiles;
    const int bm = tile / nTn, bn = tile % nTn;
    const int m0 = bm << 8, n0 = bn << 8;
    const int ks = slice * Kloc;

    const int rrT = tid >> 3;
    const size_t swzK  = (size_t)(((tid & 7) ^ (rrT & 7)) * 8);
    const size_t aoff0 = (size_t)rrT * K + swzK;
    const size_t boff0 = (size_t)((rrT >> 5) * 64 + (rrT & 31)) * K + swzK;
    const size_t boff1 = (size_t)(((rrT >> 5) + 2) * 64 + (rrT & 31)) * K + swzK;
    const int wub = w * 512;

    const int aread = (wr * 64 + (lane & 15)) * 64;
    const int bread = (wc * 32 + (lane & 15)) * 64;
    const int csw0 = ((      (lane >> 4) * 16) ^ ((lane & 7) << 4)) >> 1;
    const int csw1 = ((64 +  (lane >> 4) * 16) ^ ((lane & 7) << 4)) >> 1;

    f32x4 acc[8][4] = {};
    bf16x8 a_[4][2], b_[2][2];

#define ST_A(p,h,kt) do {                                                     \
    const size_t gb = (size_t)(m0 + (h) * 64) * K + (kt);                     \
    async16(A + gb + aoff0,                  lds + ((p)*2+(h))*8192 + wub);   \
    async16(A + gb + (size_t)128*K + aoff0,  lds + ((p)*2+(h))*8192 + 4096 + wub); \
} while (0)
#define ST_B(p,h,kt) do {                                                     \
    const size_t gb = (size_t)(n0 + (h) * 32) * K + (kt);                     \
    async16(Bt + gb + boff0, lds + 32768 + ((p)*2+(h))*8192 + wub);           \
    async16(Bt + gb + boff1, lds + 32768 + ((p)*2+(h))*8192 + 4096 + wub);    \
} while (0)
#define DS_A(p,h) do {                                                        \
    const __bf16* base_ = lds + ((p)*2+(h))*8192 + aread;                     \
    _Pragma("unroll") for (int m_ = 0; m_ < 4; ++m_) {                        \
        a_[m_][0] = *(const bf16x8*)(base_ + m_*1024 + csw0);                 \
        a_[m_][1] = *(const bf16x8*)(base_ + m_*1024 + csw1);                 \
    }                                                                         \
} while (0)
#define DS_B(p,h) do {                                                        \
    const __bf16* base_ = lds + 32768 + ((p)*2+(h))*8192 + bread;             \
    _Pragma("unroll") for (int n_ = 0; n_ < 2; ++n_) {                        \
        b_[n_][0] = *(const bf16x8*)(base_ + n_*1024 + csw0);                 \
        b_[n_][1] = *(const bf16x8*)(base_ + n_*1024 + csw1);                 \
    }                                                                         \
} while (0)
#define MM(mb,nb) do {                                                        \
    _Pragma("unroll") for (int m_ = 0; m_ < 4; ++m_)                          \
    _Pragma("unroll") for (int n_ = 0; n_ < 2; ++n_)                          \
    _Pragma("unroll") for (int k_ = 0; k_ < 2; ++k_)                          \
        acc[(mb)+m_][(nb)+n_] = mfma16(a_[m_][k_], b_[n_][k_], acc[(mb)+m_][(nb)+n_]); \
} while (0)
#define SYNC do { __builtin_amdgcn_s_barrier();                               \
    asm volatile("s_waitcnt lgkmcnt(0)" ::: "memory");                        \
    __builtin_amdgcn_s_setprio(1); } while (0)
#define PEND do { __builtin_amdgcn_s_setprio(0);                              \
    __builtin_amdgcn_s_barrier(); } while (0)

    ST_A(0,0, ks);      ST_B(0,1, ks);      ST_A(0,1, ks);      ST_B(0,0, ks);
    ST_A(1,0, ks + 64); ST_B(1,1, ks + 64); ST_A(1,1, ks + 64);
    asm volatile("s_waitcnt vmcnt(6)" ::: "memory");
    __builtin_amdgcn_s_barrier();

    const int nIter = Kloc >> 7;
    for (int i = 0; i < nIter; ++i) {
        const bool nl = (i != nIter - 1);
        const int kt1 = ks + (2*i+1) * 64;
        const int kt2 = ks + (2*i+2) * 64;
        const int kt3 = kt2 + 64;
        DS_A(0,0); DS_B(0,0); ST_B(1,0,kt1);
        SYNC; MM(0,0); PEND;
        DS_B(0,1); if (nl) ST_A(0,0,kt2);
        SYNC; MM(0,2); PEND;
        DS_A(0,1); if (nl) ST_B(0,1,kt2);
        SYNC; MM(4,2); PEND;
        DS_B(0,0); if (nl) ST_A(0,1,kt2);
        SYNC; MM(4,0);
        __builtin_amdgcn_s_setprio(0);
        if (nl) asm volatile("s_waitcnt vmcnt(6)" ::: "memory");
        else    asm volatile("s_waitcnt vmcnt(0)" ::: "memory");
        __builtin_amdgcn_s_barrier();
        DS_A(1,0); DS_B(1,0); if (nl) ST_B(0,0,kt2);
        SYNC; MM(0,0); PEND;
        DS_B(1,1); if (nl) ST_A(1,0,kt3);
        SYNC; MM(0,2); PEND;
        DS_A(1,1); if (nl) ST_B(1,1,kt3);
        SYNC; MM(4,2); PEND;
        DS_B(1,0); if (nl) ST_A(1,1,kt3);
        SYNC; MM(4,0);
        __builtin_amdgcn_s_setprio(0);
        if (nl) asm volatile("s_waitcnt vmcnt(6)" ::: "memory");
        __builtin_amdgcn_s_barrier();
    }
#undef ST_A
#undef ST_B
#undef DS_A
#undef DS_B
#undef MM
#undef SYNC
#undef PEND

    const int mrow = m0 + wr * 128 + (lane >> 4) * 4;
    const int ncol = n0 + wc * 64 + (lane & 15);
    if (EPI == 0) {
        const int sel = n0 >> 10;
        const int nc = ncol & 1023;
        if (sel < 2) {
            __bf16* out = (sel == 0) ? o0 : o1;
            const float* bp = (sel == 0) ? b0 : b1;
            const float scl = (sel == 0) ? 0.125f : 1.0f;
#pragma unroll
            for (int ni = 0; ni < 4; ++ni) {
                const float bvv = bp[nc + ni * 16];
#pragma unroll
                for (int mi = 0; mi < 8; ++mi)
#pragma unroll
                    for (int r = 0; r < 4; ++r)
                        out[(size_t)(mrow + mi * 16 + r) * D_ + nc + ni * 16] =
                            (__bf16)((acc[mi][ni][r] + bvv) * scl);
            }
        } else {
#pragma unroll
            for (int ni = 0; ni < 4; ++ni) {
                const int dhf = nc + ni * 16;
                const float bvv = b2[dhf];
                const int hh = dhf >> 6, dh = dhf & 63;
#pragma unroll
                for (int mi = 0; mi < 8; ++mi) {
                    const int gm0 = mrow + mi * 16;
                    const int bb_ = gm0 >> 9, s0 = gm0 & 511;
                    bf16x4 pk;
#pragma unroll
                    for (int r = 0; r < 4; ++r) pk[r] = (__bf16)(acc[mi][ni][r] + bvv);
                    *(bf16x4*)(o2 + ((size_t)((bb_ * 16 + hh) * 64 + dh) << 9) + s0) = pk;
                }
            }
        }
    } else if (EPI == 2) {
#pragma unroll
        for (int ni = 0; ni < 4; ++ni) {
            const float bvv = b0[ncol + ni * 16];
#pragma unroll
            for (int mi = 0; mi < 8; ++mi)
#pragma unroll
                for (int r = 0; r < 4; ++r) {
                    float v = acc[mi][ni][r] + bvv;
                    float ge = 0.5f * v * (1.0f + erff(v * 0.70710678118654752f));
                    o0[(size_t)(mrow + mi * 16 + r) * N + ncol + ni * 16] = (__bf16)ge;
                }
        }
    } else {
        __bf16* Y = oP + (size_t)slice * M * N;
#pragma unroll
        for (int ni = 0; ni < 4; ++ni) {
            const float bvv = (slice == 0) ? b0[ncol + ni * 16] : 0.0f;
#pragma unroll
            for (int mi = 0; mi < 8; ++mi)
#pragma unroll
                for (int r = 0; r < 4; ++r)
                    Y[(size_t)(mrow + mi * 16 + r) * N + ncol + ni * 16] =
                        (__bf16)(acc[mi][ni][r] + bvv);
        }
    }
}

// ---------------------------------------------------------------- attention v3
// 128 q-rows/block, 8 waves; K (64KB) + V^T (64KB) staged ONCE; P chunked over Ks.
__global__ __launch_bounds__(512, 1)
void attn_kernel(const __bf16* __restrict__ q, const __bf16* __restrict__ k,
                 const __bf16* __restrict__ vT, const float* __restrict__ fmask,
                 __bf16* __restrict__ ctx)
{
    __shared__ __bf16 Ks[512 * 64];       // 64 KB; chunk-P overlays after QK^T
    __shared__ __bf16 Vt[64 * 512];       // 64 KB, slot-XOR-swizzled content
    __shared__ float  negm[S_];
    const int bid = blockIdx.x;
    const int qt = bid & 3, h = (bid >> 2) & 15, b = bid >> 6;
    const int tid = threadIdx.x, lane = tid & 63, w = tid >> 6;
    const int g = lane >> 4, q15 = lane & 15, r7 = lane & 7;

    const __bf16* kbase  = k  + ((size_t)b * S_) * D_ + h * 64;
    const __bf16* vTbase = vT + ((size_t)((b * 16 + h) * 64) << 9);   // row d stride 512
    char* kl = (char*)Ks + (tid & ~63) * 16;
    char* vl = (char*)Vt + (tid & ~63) * 16;
    const int srow  = tid >> 3;                    // 0..63
    const int sslot = (tid & 7) ^ (srow & 7);

    // ---- stage all of K (8 issues) and V^T (8 issues) once
#pragma unroll
    for (int i = 0; i < 8; ++i) {
        const int s = i * 64 + srow;
        async16(kbase + (size_t)s * D_ + sslot * 8, kl + i * 8192);
    }
#pragma unroll
    for (int i = 0; i < 8; ++i) {
        const int d = i * 8 + w;
        async16(vTbase + ((size_t)d << 9) + (((tid & 63) ^ (d & 7)) << 3), vl + i * 8192);
    }
    if (tid < S_) negm[tid] = (fmask[b * S_ + tid] - 1.0f) * 1e30f;

    const __bf16* qbase = q + ((size_t)b * S_ + qt * 128 + w * 16) * D_ + h * 64;
    const bf16x8 qf0 = *(const bf16x8*)(qbase + (size_t)q15 * D_ + g * 8);
    const bf16x8 qf1 = *(const bf16x8*)(qbase + (size_t)q15 * D_ + 32 + g * 8);

    f32x4 sc[32];
#pragma unroll
    for (int i = 0; i < 32; ++i) { sc[i][0] = 0.f; sc[i][1] = 0.f; sc[i][2] = 0.f; sc[i][3] = 0.f; }

    __syncthreads();          // B1: K + V resident
#pragma unroll
    for (int nf = 0; nf < 32; ++nf) {
        const __bf16* kr = Ks + (nf * 16 + q15) * 64;
        const bf16x8 kf0 = *(const bf16x8*)(kr + ((g ^ r7) << 3));
        const bf16x8 kf1 = *(const bf16x8*)(kr + (((g + 4) ^ r7) << 3));
        sc[nf] = mfma16(kf0, qf0, sc[nf]);
        sc[nf] = mfma16(kf1, qf1, sc[nf]);
    }

    // ---- mask + softmax (per-lane; q fixed = q15; key = nf*16 + 4g + r)
    float mx = -3e38f;
#pragma unroll
    for (int i = 0; i < 32; ++i) {
        const float4 nm4 = *(const float4*)(negm + i * 16 + 4 * g);
        sc[i][0] += nm4.x; sc[i][1] += nm4.y; sc[i][2] += nm4.z; sc[i][3] += nm4.w;
        mx = fmaxf(mx, fmaxf(fmaxf(sc[i][0], sc[i][1]), fmaxf(sc[i][2], sc[i][3])));
    }
    mx = fmaxf(mx, __shfl_xor(mx, 16));
    mx = fmaxf(mx, __shfl_xor(mx, 32));
    float sum = 0.f;
#pragma unroll
    for (int i = 0; i < 32; ++i)
#pragma unroll
        for (int r = 0; r < 4; ++r) { float pp = __expf(sc[i][r] - mx); sc[i][r] = pp; sum += pp; }
    sum += __shfl_xor(sum, 16);
    sum += __shfl_xor(sum, 32);
    const float inv = 1.0f / sum;

    // ---- PV in two 256-key chunks: per-wave P[16][256] overlays Ks
    __bf16* P = Ks + w * 4096;
    f32x4 co[4] = {};
#define WR_P(c) do { _Pragma("unroll") for (int i_ = 0; i_ < 16; ++i_) {      \
        bf16x4 pk;                                                            \
        _Pragma("unroll") for (int r = 0; r < 4; ++r) pk[r] = (__bf16)sc[(c)*16+i_][r]; \
        *(bf16x4*)(P + q15 * 256 + ((i_ * 16 + 4 * g) ^ (8 * r7))) = pk; } } while (0)
#define PV(c) do { _Pragma("unroll") for (int kt = 0; kt < 8; ++kt) {         \
        const bf16x8 pf = *(const bf16x8*)(P + q15 * 256 + ((kt * 32 + 8 * g) ^ (8 * r7))); \
        _Pragma("unroll") for (int nf = 0; nf < 4; ++nf) {                    \
            const int d_ = nf * 16 + q15;                                     \
            const bf16x8 vf = *(const bf16x8*)(Vt + d_ * 512 +                \
                (((c) * 256 + kt * 32 + 8 * g) ^ (8 * r7)));                  \
            co[nf] = mfma16(vf, pf, co[nf]); } } } while (0)

    __syncthreads();          // B2: all QK^T reads of Ks done
    WR_P(0);
    __syncthreads();          // B3: P c0 visible
    PV(0);
    __syncthreads();          // B4: PV c0 P-reads done
    WR_P(1);
    __syncthreads();          // B5: P c1 visible
    PV(1);
#undef WR_P
#undef PV

    __bf16* cb = ctx + ((size_t)b * S_ + qt * 128 + w * 16 + q15) * D_ + h * 64;
#pragma unroll
    for (int nf = 0; nf < 4; ++nf) {
        bf16x4 o4;
#pragma unroll
        for (int r = 0; r < 4; ++r) o4[r] = (__bf16)(co[nf][r] * inv);
        *(bf16x4*)(cb + nf * 16 + 4 * g) = o4;
    }
}

// ---------------------------------------------------------------- launcher
extern "C" void kernel_launch(void* const* d_in, const int* in_sizes, int n_in,
                              void* d_out, int out_size, void* d_ws, size_t ws_size,
                              hipStream_t stream)
{
    (void)in_sizes; (void)n_in; (void)out_size; (void)ws_size;
    const int*   ids   = (const int*)d_in[0];
    const int*   lgs   = (const int*)d_in[1];
    const float* amask = (const float*)d_in[2];
    const float* wemb  = (const float*)d_in[3];
    const float* pemb  = (const float*)d_in[4];
    const float* lemb  = (const float*)d_in[5];
    const float* lng   = (const float*)d_in[6];
    const float* lnbv  = (const float*)d_in[7];
    const float* Wq = (const float*)d_in[8];  const float* bq = (const float*)d_in[9];
    const float* Wk = (const float*)d_in[10]; const float* bk = (const float*)d_in[11];
    const float* Wv = (const float*)d_in[12]; const float* bv = (const float*)d_in[13];
    const float* Wo = (const float*)d_in[14]; const float* bo = (const float*)d_in[15];
    const float* g1 = (const float*)d_in[16]; const float* be1 = (const float*)d_in[17];
    const float* W1 = (const float*)d_in[18]; const float* b1 = (const float*)d_in[19];
    const float* W2 = (const float*)d_in[20]; const float* b2 = (const float*)d_in[21];
    const float* g2 = (const float*)d_in[22]; const float* be2 = (const float*)d_in[23];

    char* p = (char*)d_ws;
    auto take = [&](size_t n) { char* r = p; p += (n + 255) & ~(size_t)255; return r; };
    __bf16* xb    = (__bf16*)take((size_t)ROWS * D_ * 2);
    __bf16* qb    = (__bf16*)take((size_t)ROWS * D_ * 2);
    __bf16* kb    = (__bf16*)take((size_t)ROWS * D_ * 2);
    __bf16* vT    = (__bf16*)take((size_t)ROWS * D_ * 2);   // [B][H][64][512]
    __bf16* cxb   = (__bf16*)take((size_t)ROWS * D_ * 2);
    __bf16* hb    = (__bf16*)take((size_t)ROWS * FF_ * 2);
    __bf16* ybp   = (__bf16*)take((size_t)4 * ROWS * D_ * 2);  // bf16 partials (4 slices)
    __bf16* wqkvT = (__bf16*)take((size_t)12 * 3 * D_ * D_ * 2);
    __bf16* woT   = (__bf16*)take((size_t)12 * D_ * D_ * 2);
    __bf16* w1T   = (__bf16*)take((size_t)12 * D_ * FF_ * 2);
    __bf16* w2T   = (__bf16*)take((size_t)12 * FF_ * D_ * 2);

    const int gQKV = (ROWS / 256) * (3 * D_ / 256);   // 192
    const int gF1  = (ROWS / 256) * (FF_ / 256);      // 256
    const int gF2  = 4 * (ROWS / 256) * (D_ / 256);   // 256 (split-K=4, Kloc=1024)
    const int gWo  = 4 * (ROWS / 256) * (D_ / 256);   // 256 (split-K=4, Kloc=256)

    conv_all_kernel<<<12 * 3072, 256, 0, stream>>>(Wq, Wk, Wv, Wo, W1, W2,
                                                   wqkvT, woT, w1T, w2T);

    embed_ln_kernel<<<ROWS, 256, 0, stream>>>(ids, lgs, amask, wemb, pemb, lemb, lng, lnbv, xb);

    for (int l = 0; l < 12; ++l) {
        __bf16* wqkvL = wqkvT + (size_t)l * 3 * D_ * D_;
        __bf16* woL   = woT   + (size_t)l * D_ * D_;
        __bf16* w1L   = w1T   + (size_t)l * D_ * FF_;
        __bf16* w2L   = w2T   + (size_t)l * FF_ * D_;

        gemm256_kernel<0><<<gQKV, 512, 0, stream>>>(xb, wqkvL, bq + l * D_, bk + l * D_, bv + l * D_,
                                                    qb, kb, vT, nullptr,
                                                    ROWS, 3 * D_, D_, D_, 12, gQKV);

        attn_kernel<<<B_ * H_ * (S_ / 128), 512, 0, stream>>>(qb, kb, vT, amask, cxb);

        gemm256_kernel<3><<<gWo, 512, 0, stream>>>(cxb, woL, bo + l * D_, nullptr, nullptr,
                                                   nullptr, nullptr, nullptr, ybp,
                                                   ROWS, D_, D_, D_ / 4, 4, 64);
        ln_resN_kernel<4><<<ROWS, 256, 0, stream>>>(xb, ybp, g1 + l * D_, be1 + l * D_,
                                                    nullptr, xb, nullptr);

        gemm256_kernel<2><<<gF1, 512, 0, stream>>>(xb, w1L, b1 + l * FF_, nullptr, nullptr,
                                                   hb, nullptr, nullptr, nullptr,
                                                   ROWS, FF_, D_, D_, 16, gF1);
        gemm256_kernel<3><<<gF2, 512, 0, stream>>>(hb, w2L, b2 + l * D_, nullptr, nullptr,
                                                   nullptr, nullptr, nullptr, ybp,
                                                   ROWS, D_, FF_, D_, 4, 64);

        float* dst = (l == 11) ? (float*)d_out : nullptr;
        ln_resN_kernel<4><<<ROWS, 256, 0, stream>>>(xb, ybp, g2 + l * D_, be2 + l * D_,
                                                    amask, xb, dst);
    }
}

// Round 9
// 2461.554 us; speedup vs baseline: 1.6534x; 1.0473x over previous
//
#include <hip/hip_runtime.h>
#include <math.h>

typedef float  f32x4  __attribute__((ext_vector_type(4)));
typedef __bf16 bf16x8 __attribute__((ext_vector_type(8)));
typedef __bf16 bf16x4 __attribute__((ext_vector_type(4)));

#define DEV __device__ __forceinline__

DEV f32x4 mfma16(bf16x8 a, bf16x8 b, f32x4 c) {
    return __builtin_amdgcn_mfma_f32_16x16x32_bf16(a, b, c, 0, 0, 0);
}

DEV void async16(const void* g, void* l) {
    __builtin_amdgcn_global_load_lds((const __attribute__((address_space(1))) void*)g,
                                     (__attribute__((address_space(3))) void*)l, 16, 0, 0);
}

// ---------------------------------------------------------------- constants
constexpr int B_  = 8;
constexpr int S_  = 512;
constexpr int D_  = 1024;
constexpr int H_  = 16;
constexpr int FF_ = 4096;
constexpr int ROWS = B_ * S_;   // 4096

// ---------------------------------------------------------------- embed + LN -> bf16
__global__ __launch_bounds__(256)
void embed_ln_kernel(const int* __restrict__ ids, const int* __restrict__ lgs,
                     const float* __restrict__ fmask,
                     const float* __restrict__ wemb, const float* __restrict__ pemb,
                     const float* __restrict__ lemb,
                     const float* __restrict__ g, const float* __restrict__ bb,
                     __bf16* __restrict__ xb)
{
    __shared__ float2 red[4];
    const int row = blockIdx.x;
    const int s   = row & (S_ - 1);
    const int t   = threadIdx.x;
    const int lane = t & 63, w = t >> 6;
    const int id = ids[row], lg = lgs[row];

    float4 wv = *(const float4*)(wemb + ((size_t)id << 10) + t * 4);
    float4 pv = *(const float4*)(pemb + ((size_t)s  << 10) + t * 4);
    float4 lv = *(const float4*)(lemb + ((size_t)lg << 10) + t * 4);
    float a[4] = { wv.x + pv.x + lv.x, wv.y + pv.y + lv.y,
                   wv.z + pv.z + lv.z, wv.w + pv.w + lv.w };

    float sm = a[0] + a[1] + a[2] + a[3];
    float sq = a[0]*a[0] + a[1]*a[1] + a[2]*a[2] + a[3]*a[3];
#pragma unroll
    for (int o = 32; o > 0; o >>= 1) { sm += __shfl_down(sm, o); sq += __shfl_down(sq, o); }
    if (lane == 0) red[w] = make_float2(sm, sq);
    __syncthreads();
    float ts = red[0].x + red[1].x + red[2].x + red[3].x;
    float tq = red[0].y + red[1].y + red[2].y + red[3].y;
    float mean = ts * (1.0f / D_);
    float var  = tq * (1.0f / D_) - mean * mean;
    float rs   = rsqrtf(var + 1e-12f);
    float fm   = fmask[row];

    float4 gv = *(const float4*)(g  + t * 4);
    float4 bv = *(const float4*)(bb + t * 4);
    bf16x4 ob;
    ob[0] = (__bf16)(((a[0]-mean)*rs*gv.x + bv.x) * fm);
    ob[1] = (__bf16)(((a[1]-mean)*rs*gv.y + bv.y) * fm);
    ob[2] = (__bf16)(((a[2]-mean)*rs*gv.z + bv.z) * fm);
    ob[3] = (__bf16)(((a[3]-mean)*rs*gv.w + bv.w) * fm);
    *(bf16x4*)(xb + ((size_t)row << 10) + t * 4) = ob;
}

// ---------------- bf16 residual + NP bf16 partials + LN (+mask) -> bf16 (+fp32 out)
// 128 threads/row, 8 elems/thread (16B loads per tensor).
template<int NP>
__global__ __launch_bounds__(128)
void ln_resN_kernel(const __bf16* __restrict__ xres, const __bf16* __restrict__ yp,
                    const float* __restrict__ g, const float* __restrict__ bb,
                    const float* __restrict__ fmask,
                    __bf16* __restrict__ xb_out, float* __restrict__ fout)
{
    constexpr size_t MN = (size_t)ROWS * D_;
    __shared__ float2 red[2];
    const int row = blockIdx.x;
    const int t   = threadIdx.x;            // 0..127
    const int lane = t & 63, w = t >> 6;
    const size_t base = ((size_t)row << 10) + t * 8;

    bf16x8 xv = *(const bf16x8*)(xres + base);
    float a[8];
#pragma unroll
    for (int j = 0; j < 8; ++j) a[j] = (float)xv[j];
#pragma unroll
    for (int pslice = 0; pslice < NP; ++pslice) {
        bf16x8 yv = *(const bf16x8*)(yp + base + (size_t)pslice * MN);
#pragma unroll
        for (int j = 0; j < 8; ++j) a[j] += (float)yv[j];
    }

    float sm = 0.f, sq = 0.f;
#pragma unroll
    for (int j = 0; j < 8; ++j) { sm += a[j]; sq += a[j] * a[j]; }
#pragma unroll
    for (int o = 32; o > 0; o >>= 1) { sm += __shfl_down(sm, o); sq += __shfl_down(sq, o); }
    if (lane == 0) red[w] = make_float2(sm, sq);
    __syncthreads();
    float ts = red[0].x + red[1].x;
    float tq = red[0].y + red[1].y;
    float mean = ts * (1.0f / D_);
    float var  = tq * (1.0f / D_) - mean * mean;
    float rs   = rsqrtf(var + 1e-12f);
    float fm   = fmask ? fmask[row] : 1.0f;

    float4 gv0 = *(const float4*)(g  + t * 8);
    float4 gv1 = *(const float4*)(g  + t * 8 + 4);
    float4 bv0 = *(const float4*)(bb + t * 8);
    float4 bv1 = *(const float4*)(bb + t * 8 + 4);
    float gg[8] = { gv0.x, gv0.y, gv0.z, gv0.w, gv1.x, gv1.y, gv1.z, gv1.w };
    float bbv[8] = { bv0.x, bv0.y, bv0.z, bv0.w, bv1.x, bv1.y, bv1.z, bv1.w };

    float o[8];
    bf16x8 ob;
#pragma unroll
    for (int j = 0; j < 8; ++j) {
        o[j] = ((a[j] - mean) * rs * gg[j] + bbv[j]) * fm;
        ob[j] = (__bf16)o[j];
    }
    *(bf16x8*)(xb_out + base) = ob;
    if (fout) {
        *(float4*)(fout + base)     = make_float4(o[0], o[1], o[2], o[3]);
        *(float4*)(fout + base + 4) = make_float4(o[4], o[5], o[6], o[7]);
    }
}

// ----------- upfront ALL-LAYER weight convert fp32[K][N] -> bf16[N][K] (1 dispatch)
// v3: float4 reads (2 adjacent k-rows/thread), u32-packed LDS writes into padded
// [n][34]-u32 tile with lane-varying XOR (banks ~2-3 way), bf16x8 writes out.
__global__ __launch_bounds__(256)
void conv_all_kernel(const float* __restrict__ Wq, const float* __restrict__ Wk,
                     const float* __restrict__ Wv, const float* __restrict__ Wo,
                     const float* __restrict__ W1, const float* __restrict__ W2,
                     __bf16* __restrict__ qkvT, __bf16* __restrict__ woT,
                     __bf16* __restrict__ w1T, __bf16* __restrict__ w2T)
{
    __shared__ unsigned int tile32[64 * 34];   // [n][k/2], stride 34 words
    const int id = blockIdx.x;
    const int l  = id / 3072;
    int t = id - l * 3072;
    const size_t woff = (size_t)l * D_ * D_;
    const size_t foff = (size_t)l * D_ * FF_;
    const float* src; __bf16* dst; int K, N;
    if (t < 1024) {
        const int m = t >> 8; t &= 255; K = 1024; N = 1024;
        src = ((m == 0) ? Wq : (m == 1) ? Wk : (m == 2) ? Wv : Wo) + woff;
        dst = (m == 3) ? (woT + woff)
                       : (qkvT + (size_t)l * 3 * D_ * D_ + (size_t)m * D_ * D_);
    } else if (t < 2048) {
        t -= 1024; K = 1024; N = 4096; src = W1 + foff; dst = w1T + foff;
    } else {
        t -= 2048; K = 4096; N = 1024; src = W2 + foff; dst = w2T + foff;
    }
    const int ktiles = K >> 6;
    const int tk = t % ktiles, tn = t / ktiles;
    const int k0t = tk << 6, n0t = tn << 6;
    const int tt = threadIdx.x;

    const int kp = tt >> 4;          // 0..15 (k-pair index)
    const int nq = tt & 15;          // 0..15 (n quad)
    const int swzw = (nq >> 2) << 2; // write-side XOR key (lane-varying)
#pragma unroll
    for (int i = 0; i < 2; ++i) {
        const int k0 = i * 32 + kp * 2;
        const float4 r0 = *(const float4*)(src + (size_t)(k0t + k0)     * N + n0t + nq * 4);
        const float4 r1 = *(const float4*)(src + (size_t)(k0t + k0 + 1) * N + n0t + nq * 4);
        const int j = (i * 16 + kp) ^ swzw;
        const float lo[4] = { r0.x, r0.y, r0.z, r0.w };
        const float hi[4] = { r1.x, r1.y, r1.z, r1.w };
#pragma unroll
        for (int c = 0; c < 4; ++c) {
            const int n = nq * 4 + c;
            union { unsigned int u; __bf16 b[2]; } pk;
            pk.b[0] = (__bf16)lo[c];
            pk.b[1] = (__bf16)hi[c];
            tile32[n * 34 + j] = pk.u;
        }
    }
    __syncthreads();
    const int nr = tt >> 3;          // 0..31
    const int kc = tt & 7;           // 0..7
#pragma unroll
    for (int pp = 0; pp < 2; ++pp) {
        const int n = pp * 32 + nr;
        // writer key for row n: nq = n>>2 -> swz = ((n>>2)>>2)<<2 = (n>>4)<<2
        const int jb = (kc * 4) ^ ((n >> 4) << 2);   // 4 consecutive words (bits0-1 free)
        const unsigned int* tp = tile32 + n * 34 + jb;
        union { unsigned int u[4]; bf16x8 v; } out;
        out.u[0] = tp[0]; out.u[1] = tp[1]; out.u[2] = tp[2]; out.u[3] = tp[3];
        *(bf16x8*)(dst + (size_t)(n0t + n) * K + k0t + kc * 8) = out.v;
    }
}

// ================================================================ 256x256 8-phase GEMM
// (schedule unchanged — verified)
// EPI 0: QKV (q*0.125 bf16; k bf16; V -> TRANSPOSED vT[b][h][64][512])
// EPI 2: GELU(sigmoid form)->bf16.  EPI 3: split-K bf16 partials at oP + slice*M*N.
template<int EPI>
__global__ __launch_bounds__(512, 2)
void gemm256_kernel(const __bf16* __restrict__ A, const __bf16* __restrict__ Bt,
                    const float* __restrict__ b0, const float* __restrict__ b1,
                    const float* __restrict__ b2,
                    __bf16* __restrict__ o0, __bf16* __restrict__ o1,
                    __bf16* __restrict__ o2, __bf16* __restrict__ oP,
                    int M, int N, int K, int Kloc, int nTn, int tiles)
{
    __shared__ __bf16 lds[65536];
    const int tid  = threadIdx.x;
    const int lane = tid & 63;
    const int w    = tid >> 6;
    const int wr   = w >> 2, wc = w & 3;

    const int nwg = gridDim.x, bid = blockIdx.x;
    const int cpx = nwg >> 3;
    const int bswz = (bid & 7) * cpx + (bid >> 3);
    const int slice = bswz / tiles;
    const int tile  = bswz % tiles;
    const int bm = tile / nTn, bn = tile % nTn;
    const int m0 = bm << 8, n0 = bn << 8;
    const int ks = slice * Kloc;

    const int rrT = tid >> 3;
    const size_t swzK  = (size_t)(((tid & 7) ^ (rrT & 7)) * 8);
    const size_t aoff0 = (size_t)rrT * K + swzK;
    const size_t boff0 = (size_t)((rrT >> 5) * 64 + (rrT & 31)) * K + swzK;
    const size_t boff1 = (size_t)(((rrT >> 5) + 2) * 64 + (rrT & 31)) * K + swzK;
    const int wub = w * 512;

    const int aread = (wr * 64 + (lane & 15)) * 64;
    const int bread = (wc * 32 + (lane & 15)) * 64;
    const int csw0 = ((      (lane >> 4) * 16) ^ ((lane & 7) << 4)) >> 1;
    const int csw1 = ((64 +  (lane >> 4) * 16) ^ ((lane & 7) << 4)) >> 1;

    f32x4 acc[8][4] = {};
    bf16x8 a_[4][2], b_[2][2];

#define ST_A(p,h,kt) do {                                                     \
    const size_t gb = (size_t)(m0 + (h) * 64) * K + (kt);                     \
    async16(A + gb + aoff0,                  lds + ((p)*2+(h))*8192 + wub);   \
    async16(A + gb + (size_t)128*K + aoff0,  lds + ((p)*2+(h))*8192 + 4096 + wub); \
} while (0)
#define ST_B(p,h,kt) do {                                                     \
    const size_t gb = (size_t)(n0 + (h) * 32) * K + (kt);                     \
    async16(Bt + gb + boff0, lds + 32768 + ((p)*2+(h))*8192 + wub);           \
    async16(Bt + gb + boff1, lds + 32768 + ((p)*2+(h))*8192 + 4096 + wub);    \
} while (0)
#define DS_A(p,h) do {                                                        \
    const __bf16* base_ = lds + ((p)*2+(h))*8192 + aread;                     \
    _Pragma("unroll") for (int m_ = 0; m_ < 4; ++m_) {                        \
        a_[m_][0] = *(const bf16x8*)(base_ + m_*1024 + csw0);                 \
        a_[m_][1] = *(const bf16x8*)(base_ + m_*1024 + csw1);                 \
    }                                                                         \
} while (0)
#define DS_B(p,h) do {                                                        \
    const __bf16* base_ = lds + 32768 + ((p)*2+(h))*8192 + bread;             \
    _Pragma("unroll") for (int n_ = 0; n_ < 2; ++n_) {                        \
        b_[n_][0] = *(const bf16x8*)(base_ + n_*1024 + csw0);                 \
        b_[n_][1] = *(const bf16x8*)(base_ + n_*1024 + csw1);                 \
    }                                                                         \
} while (0)
#define MM(mb,nb) do {                                                        \
    _Pragma("unroll") for (int m_ = 0; m_ < 4; ++m_)                          \
    _Pragma("unroll") for (int n_ = 0; n_ < 2; ++n_)                          \
    _Pragma("unroll") for (int k_ = 0; k_ < 2; ++k_)                          \
        acc[(mb)+m_][(nb)+n_] = mfma16(a_[m_][k_], b_[n_][k_], acc[(mb)+m_][(nb)+n_]); \
} while (0)
#define SYNC do { __builtin_amdgcn_s_barrier();                               \
    asm volatile("s_waitcnt lgkmcnt(0)" ::: "memory");                        \
    __builtin_amdgcn_s_setprio(1); } while (0)
#define PEND do { __builtin_amdgcn_s_setprio(0);                              \
    __builtin_amdgcn_s_barrier(); } while (0)

    ST_A(0,0, ks);      ST_B(0,1, ks);      ST_A(0,1, ks);      ST_B(0,0, ks);
    ST_A(1,0, ks + 64); ST_B(1,1, ks + 64); ST_A(1,1, ks + 64);
    asm volatile("s_waitcnt vmcnt(6)" ::: "memory");
    __builtin_amdgcn_s_barrier();

    const int nIter = Kloc >> 7;
    for (int i = 0; i < nIter; ++i) {
        const bool nl = (i != nIter - 1);
        const int kt1 = ks + (2*i+1) * 64;
        const int kt2 = ks + (2*i+2) * 64;
        const int kt3 = kt2 + 64;
        DS_A(0,0); DS_B(0,0); ST_B(1,0,kt1);
        SYNC; MM(0,0); PEND;
        DS_B(0,1); if (nl) ST_A(0,0,kt2);
        SYNC; MM(0,2); PEND;
        DS_A(0,1); if (nl) ST_B(0,1,kt2);
        SYNC; MM(4,2); PEND;
        DS_B(0,0); if (nl) ST_A(0,1,kt2);
        SYNC; MM(4,0);
        __builtin_amdgcn_s_setprio(0);
        if (nl) asm volatile("s_waitcnt vmcnt(6)" ::: "memory");
        else    asm volatile("s_waitcnt vmcnt(0)" ::: "memory");
        __builtin_amdgcn_s_barrier();
        DS_A(1,0); DS_B(1,0); if (nl) ST_B(0,0,kt2);
        SYNC; MM(0,0); PEND;
        DS_B(1,1); if (nl) ST_A(1,0,kt3);
        SYNC; MM(0,2); PEND;
        DS_A(1,1); if (nl) ST_B(1,1,kt3);
        SYNC; MM(4,2); PEND;
        DS_B(1,0); if (nl) ST_A(1,1,kt3);
        SYNC; MM(4,0);
        __builtin_amdgcn_s_setprio(0);
        if (nl) asm volatile("s_waitcnt vmcnt(6)" ::: "memory");
        __builtin_amdgcn_s_barrier();
    }
#undef ST_A
#undef ST_B
#undef DS_A
#undef DS_B
#undef MM
#undef SYNC
#undef PEND

    const int mrow = m0 + wr * 128 + (lane >> 4) * 4;
    const int ncol = n0 + wc * 64 + (lane & 15);
    if (EPI == 0) {
        const int sel = n0 >> 10;
        const int nc = ncol & 1023;
        if (sel < 2) {
            __bf16* out = (sel == 0) ? o0 : o1;
            const float* bp = (sel == 0) ? b0 : b1;
            const float scl = (sel == 0) ? 0.125f : 1.0f;
#pragma unroll
            for (int ni = 0; ni < 4; ++ni) {
                const float bvv = bp[nc + ni * 16];
#pragma unroll
                for (int mi = 0; mi < 8; ++mi)
#pragma unroll
                    for (int r = 0; r < 4; ++r)
                        out[(size_t)(mrow + mi * 16 + r) * D_ + nc + ni * 16] =
                            (__bf16)((acc[mi][ni][r] + bvv) * scl);
            }
        } else {
#pragma unroll
            for (int ni = 0; ni < 4; ++ni) {
                const int dhf = nc + ni * 16;
                const float bvv = b2[dhf];
                const int hh = dhf >> 6, dh = dhf & 63;
#pragma unroll
                for (int mi = 0; mi < 8; ++mi) {
                    const int gm0 = mrow + mi * 16;
                    const int bb_ = gm0 >> 9, s0 = gm0 & 511;
                    bf16x4 pk;
#pragma unroll
                    for (int r = 0; r < 4; ++r) pk[r] = (__bf16)(acc[mi][ni][r] + bvv);
                    *(bf16x4*)(o2 + ((size_t)((bb_ * 16 + hh) * 64 + dh) << 9) + s0) = pk;
                }
            }
        }
    } else if (EPI == 2) {
#pragma unroll
        for (int ni = 0; ni < 4; ++ni) {
            const float bvv = b0[ncol + ni * 16];
#pragma unroll
            for (int mi = 0; mi < 8; ++mi)
#pragma unroll
                for (int r = 0; r < 4; ++r) {
                    float v = acc[mi][ni][r] + bvv;
                    // exact-erf gelu ~= sigmoid(tanh-form): max dev ~1e-3
                    float u2 = 1.5957691216f * v * (1.0f + 0.044715f * v * v);
                    float ge = v / (1.0f + __expf(-u2));
                    o0[(size_t)(mrow + mi * 16 + r) * N + ncol + ni * 16] = (__bf16)ge;
                }
        }
    } else {
        __bf16* Y = oP + (size_t)slice * M * N;
#pragma unroll
        for (int ni = 0; ni < 4; ++ni) {
            const float bvv = (slice == 0) ? b0[ncol + ni * 16] : 0.0f;
#pragma unroll
            for (int mi = 0; mi < 8; ++mi)
#pragma unroll
                for (int r = 0; r < 4; ++r)
                    Y[(size_t)(mrow + mi * 16 + r) * N + ncol + ni * 16] =
                        (__bf16)(acc[mi][ni][r] + bvv);
        }
    }
}

// ---------------------------------------------------------------- attention v3
// (unchanged — verified)
__global__ __launch_bounds__(512, 1)
void attn_kernel(const __bf16* __restrict__ q, const __bf16* __restrict__ k,
                 const __bf16* __restrict__ vT, const float* __restrict__ fmask,
                 __bf16* __restrict__ ctx)
{
    __shared__ __bf16 Ks[512 * 64];
    __shared__ __bf16 Vt[64 * 512];
    __shared__ float  negm[S_];
    const int bid = blockIdx.x;
    const int qt = bid & 3, h = (bid >> 2) & 15, b = bid >> 6;
    const int tid = threadIdx.x, lane = tid & 63, w = tid >> 6;
    const int g = lane >> 4, q15 = lane & 15, r7 = lane & 7;

    const __bf16* kbase  = k  + ((size_t)b * S_) * D_ + h * 64;
    const __bf16* vTbase = vT + ((size_t)((b * 16 + h) * 64) << 9);
    char* kl = (char*)Ks + (tid & ~63) * 16;
    char* vl = (char*)Vt + (tid & ~63) * 16;
    const int srow  = tid >> 3;
    const int sslot = (tid & 7) ^ (srow & 7);

#pragma unroll
    for (int i = 0; i < 8; ++i) {
        const int s = i * 64 + srow;
        async16(kbase + (size_t)s * D_ + sslot * 8, kl + i * 8192);
    }
#pragma unroll
    for (int i = 0; i < 8; ++i) {
        const int d = i * 8 + w;
        async16(vTbase + ((size_t)d << 9) + (((tid & 63) ^ (d & 7)) << 3), vl + i * 8192);
    }
    if (tid < S_) negm[tid] = (fmask[b * S_ + tid] - 1.0f) * 1e30f;

    const __bf16* qbase = q + ((size_t)b * S_ + qt * 128 + w * 16) * D_ + h * 64;
    const bf16x8 qf0 = *(const bf16x8*)(qbase + (size_t)q15 * D_ + g * 8);
    const bf16x8 qf1 = *(const bf16x8*)(qbase + (size_t)q15 * D_ + 32 + g * 8);

    f32x4 sc[32];
#pragma unroll
    for (int i = 0; i < 32; ++i) { sc[i][0] = 0.f; sc[i][1] = 0.f; sc[i][2] = 0.f; sc[i][3] = 0.f; }

    __syncthreads();
#pragma unroll
    for (int nf = 0; nf < 32; ++nf) {
        const __bf16* kr = Ks + (nf * 16 + q15) * 64;
        const bf16x8 kf0 = *(const bf16x8*)(kr + ((g ^ r7) << 3));
        const bf16x8 kf1 = *(const bf16x8*)(kr + (((g + 4) ^ r7) << 3));
        sc[nf] = mfma16(kf0, qf0, sc[nf]);
        sc[nf] = mfma16(kf1, qf1, sc[nf]);
    }

    float mx = -3e38f;
#pragma unroll
    for (int i = 0; i < 32; ++i) {
        const float4 nm4 = *(const float4*)(negm + i * 16 + 4 * g);
        sc[i][0] += nm4.x; sc[i][1] += nm4.y; sc[i][2] += nm4.z; sc[i][3] += nm4.w;
        mx = fmaxf(mx, fmaxf(fmaxf(sc[i][0], sc[i][1]), fmaxf(sc[i][2], sc[i][3])));
    }
    mx = fmaxf(mx, __shfl_xor(mx, 16));
    mx = fmaxf(mx, __shfl_xor(mx, 32));
    float sum = 0.f;
#pragma unroll
    for (int i = 0; i < 32; ++i)
#pragma unroll
        for (int r = 0; r < 4; ++r) { float pp = __expf(sc[i][r] - mx); sc[i][r] = pp; sum += pp; }
    sum += __shfl_xor(sum, 16);
    sum += __shfl_xor(sum, 32);
    const float inv = 1.0f / sum;

    __bf16* P = Ks + w * 4096;
    f32x4 co[4] = {};
#define WR_P(c) do { _Pragma("unroll") for (int i_ = 0; i_ < 16; ++i_) {      \
        bf16x4 pk;                                                            \
        _Pragma("unroll") for (int r = 0; r < 4; ++r) pk[r] = (__bf16)sc[(c)*16+i_][r]; \
        *(bf16x4*)(P + q15 * 256 + ((i_ * 16 + 4 * g) ^ (8 * r7))) = pk; } } while (0)
#define PV(c) do { _Pragma("unroll") for (int kt = 0; kt < 8; ++kt) {         \
        const bf16x8 pf = *(const bf16x8*)(P + q15 * 256 + ((kt * 32 + 8 * g) ^ (8 * r7))); \
        _Pragma("unroll") for (int nf = 0; nf < 4; ++nf) {                    \
            const int d_ = nf * 16 + q15;                                     \
            const bf16x8 vf = *(const bf16x8*)(Vt + d_ * 512 +                \
                (((c) * 256 + kt * 32 + 8 * g) ^ (8 * r7)));                  \
            co[nf] = mfma16(vf, pf, co[nf]); } } } while (0)

    __syncthreads();
    WR_P(0);
    __syncthreads();
    PV(0);
    __syncthreads();
    WR_P(1);
    __syncthreads();
    PV(1);
#undef WR_P
#undef PV

    __bf16* cb = ctx + ((size_t)b * S_ + qt * 128 + w * 16 + q15) * D_ + h * 64;
#pragma unroll
    for (int nf = 0; nf < 4; ++nf) {
        bf16x4 o4;
#pragma unroll
        for (int r = 0; r < 4; ++r) o4[r] = (__bf16)(co[nf][r] * inv);
        *(bf16x4*)(cb + nf * 16 + 4 * g) = o4;
    }
}

// ---------------------------------------------------------------- launcher
extern "C" void kernel_launch(void* const* d_in, const int* in_sizes, int n_in,
                              void* d_out, int out_size, void* d_ws, size_t ws_size,
                              hipStream_t stream)
{
    (void)in_sizes; (void)n_in; (void)out_size; (void)ws_size;
    const int*   ids   = (const int*)d_in[0];
    const int*   lgs   = (const int*)d_in[1];
    const float* amask = (const float*)d_in[2];
    const float* wemb  = (const float*)d_in[3];
    const float* pemb  = (const float*)d_in[4];
    const float* lemb  = (const float*)d_in[5];
    const float* lng   = (const float*)d_in[6];
    const float* lnbv  = (const float*)d_in[7];
    const float* Wq = (const float*)d_in[8];  const float* bq = (const float*)d_in[9];
    const float* Wk = (const float*)d_in[10]; const float* bk = (const float*)d_in[11];
    const float* Wv = (const float*)d_in[12]; const float* bv = (const float*)d_in[13];
    const float* Wo = (const float*)d_in[14]; const float* bo = (const float*)d_in[15];
    const float* g1 = (const float*)d_in[16]; const float* be1 = (const float*)d_in[17];
    const float* W1 = (const float*)d_in[18]; const float* b1 = (const float*)d_in[19];
    const float* W2 = (const float*)d_in[20]; const float* b2 = (const float*)d_in[21];
    const float* g2 = (const float*)d_in[22]; const float* be2 = (const float*)d_in[23];

    char* p = (char*)d_ws;
    auto take = [&](size_t n) { char* r = p; p += (n + 255) & ~(size_t)255; return r; };
    __bf16* xb    = (__bf16*)take((size_t)ROWS * D_ * 2);
    __bf16* qb    = (__bf16*)take((size_t)ROWS * D_ * 2);
    __bf16* kb    = (__bf16*)take((size_t)ROWS * D_ * 2);
    __bf16* vT    = (__bf16*)take((size_t)ROWS * D_ * 2);   // [B][H][64][512]
    __bf16* cxb   = (__bf16*)take((size_t)ROWS * D_ * 2);
    __bf16* hb    = (__bf16*)take((size_t)ROWS * FF_ * 2);
    __bf16* ybp   = (__bf16*)take((size_t)4 * ROWS * D_ * 2);  // bf16 partials (4 slices)
    __bf16* wqkvT = (__bf16*)take((size_t)12 * 3 * D_ * D_ * 2);
    __bf16* woT   = (__bf16*)take((size_t)12 * D_ * D_ * 2);
    __bf16* w1T   = (__bf16*)take((size_t)12 * D_ * FF_ * 2);
    __bf16* w2T   = (__bf16*)take((size_t)12 * FF_ * D_ * 2);

    const int gQKV = (ROWS / 256) * (3 * D_ / 256);   // 192
    const int gF1  = (ROWS / 256) * (FF_ / 256);      // 256
    const int gF2  = 4 * (ROWS / 256) * (D_ / 256);   // 256 (split-K=4, Kloc=1024)
    const int gWo  = 4 * (ROWS / 256) * (D_ / 256);   // 256 (split-K=4, Kloc=256)

    conv_all_kernel<<<12 * 3072, 256, 0, stream>>>(Wq, Wk, Wv, Wo, W1, W2,
                                                   wqkvT, woT, w1T, w2T);

    embed_ln_kernel<<<ROWS, 256, 0, stream>>>(ids, lgs, amask, wemb, pemb, lemb, lng, lnbv, xb);

    for (int l = 0; l < 12; ++l) {
        __bf16* wqkvL = wqkvT + (size_t)l * 3 * D_ * D_;
        __bf16* woL   = woT   + (size_t)l * D_ * D_;
        __bf16* w1L   = w1T   + (size_t)l * D_ * FF_;
        __bf16* w2L   = w2T   + (size_t)l * FF_ * D_;

        gemm256_kernel<0><<<gQKV, 512, 0, stream>>>(xb, wqkvL, bq + l * D_, bk + l * D_, bv + l * D_,
                                                    qb, kb, vT, nullptr,
                                                    ROWS, 3 * D_, D_, D_, 12, gQKV);

        attn_kernel<<<B_ * H_ * (S_ / 128), 512, 0, stream>>>(qb, kb, vT, amask, cxb);

        gemm256_kernel<3><<<gWo, 512, 0, stream>>>(cxb, woL, bo + l * D_, nullptr, nullptr,
                                                   nullptr, nullptr, nullptr, ybp,
                                                   ROWS, D_, D_, D_ / 4, 4, 64);
        ln_resN_kernel<4><<<ROWS, 128, 0, stream>>>(xb, ybp, g1 + l * D_, be1 + l * D_,
                                                    nullptr, xb, nullptr);

        gemm256_kernel<2><<<gF1, 512, 0, stream>>>(xb, w1L, b1 + l * FF_, nullptr, nullptr,
                                                   hb, nullptr, nullptr, nullptr,
                                                   ROWS, FF_, D_, D_, 16, gF1);
        gemm256_kernel<3><<<gF2, 512, 0, stream>>>(hb, w2L, b2 + l * D_, nullptr, nullptr,
                                                   nullptr, nullptr, nullptr, ybp,
                                                   ROWS, D_, FF_, D_, 4, 64);

        float* dst = (l == 11) ? (float*)d_out : nullptr;
        ln_resN_kernel<4><<<ROWS, 128, 0, stream>>>(xb, ybp, g2 + l * D_, be2 + l * D_,
                                                    amask, xb, dst);
    }
}